// Round 12
// baseline (3556.282 us; speedup 1.0000x reference)
//
#include <hip/hip_runtime.h>

// ViT-B/16 forward, B=32, S=197, E=768, H=12, HD=64, MLP=3072, DEPTH=12.
// Round 12: traffic-model round. All GEMMs converge to ~7-9 TB/s of L2/L3
// operand traffic (BW ceiling, not latency/MFMA) -> minimize
// traffic = M*K*(N/BN) + N*K*(M/BM) with grid >= ~300 blocks:
//   qkv/mlp1: 128x256  proj: 128x128  mlp2: split-K on 256x128.
// gemmU<EPI,BM,BN>: 8 waves, BK=64, 2-phase __syncthreads (R10-best loop),
// global_load_lds(16B), both-sides chunk-XOR swizzle, XCD block swizzle.

typedef __attribute__((ext_vector_type(8))) short short8;
typedef __attribute__((ext_vector_type(8))) unsigned short ushort8;
typedef __attribute__((ext_vector_type(4))) float f32x4;
typedef unsigned short u16;

#define DEV __device__ __forceinline__

DEV u16 f2bf(float f) {
  unsigned int u = __builtin_bit_cast(unsigned int, f);
  u += 0x7fffu + ((u >> 16) & 1u);
  return (u16)(u >> 16);
}
DEV float wred_sum(float v) {
  for (int o = 32; o; o >>= 1) v += __shfl_xor(v, o, 64);
  return v;
}
DEV void glds16(const void* gp, void* lp) {
  __builtin_amdgcn_global_load_lds(
      (const __attribute__((address_space(1))) void*)gp,
      (__attribute__((address_space(3))) void*)lp, 16, 0, 0);
}
// m204 bijective XCD swizzle: contiguous wg chunk per XCD
DEV int xcd_swz(int flat, int nwg) {
  int q = nwg >> 3, r = nwg & 7;
  int x = flat & 7, o = flat >> 3;
  return (x < r ? x * (q + 1) : r * (q + 1) + (x - r) * q) + o;
}

// ---------------- weight conversion ----------------
__global__ __launch_bounds__(256) void cvt4_k(const float* __restrict__ s,
                                              u16* __restrict__ d, long n4) {
  long i = (long)blockIdx.x * 256 + threadIdx.x;
  if (i >= n4) return;
  float4 v = ((const float4*)s)[i];
  ushort4 o;
  o.x = f2bf(v.x); o.y = f2bf(v.y); o.z = f2bf(v.z); o.w = f2bf(v.w);
  ((ushort4*)d)[i] = o;
}

// fp32 [K][N] (blockIdx.z selects layer) -> bf16 [N][K], tiled 32x32
__global__ __launch_bounds__(256) void tpose_k(const float* __restrict__ s,
                                               u16* __restrict__ d, int K,
                                               int N) {
  __shared__ float t[32][33];
  const int bx = blockIdx.x;  // n tile
  const int by = blockIdx.y;  // k tile
  const size_t base = (size_t)blockIdx.z * K * N;
  const int c = threadIdx.x & 31, r0 = threadIdx.x >> 5;
#pragma unroll
  for (int i = 0; i < 4; ++i) {
    int r = r0 + i * 8;
    t[r][c] = s[base + (size_t)(by * 32 + r) * N + bx * 32 + c];
  }
  __syncthreads();
#pragma unroll
  for (int i = 0; i < 4; ++i) {
    int r = r0 + i * 8;
    d[base + (size_t)(bx * 32 + r) * K + by * 32 + c] = f2bf(t[c][r]);
  }
}

// patches[b][p][d] <- x[b][c][gy*16+py][gx*16+px], bf16
__global__ __launch_bounds__(256) void patch_k(const float* __restrict__ x,
                                               u16* __restrict__ pt) {
  int i = blockIdx.x * 256 + threadIdx.x;  // 6272*768 exactly
  int d = i % 768;
  int bp = i / 768;
  int p = bp % 196, b = bp / 196;
  int c = d >> 8, pd = d & 255;
  int py = pd >> 4, px = pd & 15;
  int gy = p / 14, gx = p - gy * 14;
  size_t src = ((size_t)(b * 3 + c) * 224 + gy * 16 + py) * 224 + gx * 16 + px;
  pt[i] = f2bf(x[src]);
}

// h[b][0][:] = cls + pos[0]
__global__ __launch_bounds__(256) void clspos_k(const float* __restrict__ cls,
                                                const float* __restrict__ pos,
                                                float* __restrict__ h) {
  int i = blockIdx.x * 256 + threadIdx.x;  // 32*768
  int b = i / 768, e = i - b * 768;
  h[(size_t)b * 197 * 768 + e] = cls[e] + pos[e];
}

// ---------------- epilogue helper ----------------
template <int EPI>
DEV void epi_store(float v, int grow, int gcol, u16* outb, int ldo,
                   float* outf, const float* pos) {
  if constexpr (EPI == 0) {
    outb[(size_t)grow * ldo + gcol] = f2bf(v);
  } else if constexpr (EPI == 1) {
    // gelu(x) ~= x * sigmoid(1.5957691(x + 0.044715 x^3))
    float u = __expf(-1.5957691216f * (v + 0.044715f * v * v * v));
    outb[(size_t)grow * ldo + gcol] = f2bf(v / (1.f + u));
  } else if constexpr (EPI == 2) {
    outf[(size_t)grow * ldo + gcol] += v;
  } else if constexpr (EPI == 3) {
    int b = grow / 196, p = grow - b * 196;
    outf[(size_t)(grow + b + 1) * 768 + gcol] =
        v + pos[(size_t)(p + 1) * 768 + gcol];
  }
}

// -------- gemmU: C[M,N] = A[M,K](bf16) @ Bt[N,K](bf16), BMxBN, BK=64 ------
// 8 waves (512 thr), wave tile 64 x (BN/WN). 2-phase double-buffer,
// global_load_lds(16B), chunk-XOR swizzle (both sides), XCD block swizzle.
// EPI 4: split-K partial -> outf plane blockIdx.z (raw fp32, no bias);
//        K parameter is the per-chunk KC, sources offset by z*KC.
template <int EPI, int BM, int BN>
__global__ __launch_bounds__(512) void gemmU(
    const u16* __restrict__ A, int lda, const u16* __restrict__ Bt, int ldb,
    const float* __restrict__ bias, u16* __restrict__ outb, int ldo,
    float* __restrict__ outf, const float* __restrict__ pos, int M, int K) {
  constexpr int WM = BM / 64;      // waves along M (2 or 4)
  constexpr int WN = 8 / WM;       // waves along N (4 or 2)
  constexpr int WCOL = BN / WN;    // wave tile cols (64 or 32)
  constexpr int NI = WCOL / 16;    // B frags per wave (4 or 2)
  constexpr int RW = (BM + BN) / 8;  // rows staged per wave
  constexpr int NG = RW / 8;         // glds16 per wave per stage
  __shared__ __align__(16) u16 Ak[2][BM * 64];
  __shared__ __align__(16) u16 Bk[2][BN * 64];
  const int tid = threadIdx.x;
  const int lane = tid & 63, wid = tid >> 6;
  const int wm = wid / WN, wn = wid % WN;
  const int lg = lane >> 4, lr = lane & 15;
  const int nwg = gridDim.x * gridDim.y;
  const int wg = xcd_swz(blockIdx.y * gridDim.x + blockIdx.x, nwg);
  const int tn = wg % gridDim.x, tm = wg / gridDim.x;
  const size_t koff = (EPI == 4) ? (size_t)blockIdx.z * K : 0;

  const int r8 = lane >> 3, c8 = lane & 7;
  const int swc = (c8 ^ r8) << 3;  // source chunk pre-swizzled (rule #21)
  const u16* aRow = A + (size_t)(tm * BM + r8) * lda + koff + swc;
  const u16* bRow = Bt + (size_t)(tn * BN + r8) * ldb + koff + swc;

  auto stage = [&](int buf, int kt) {  // NG glds16/wave, 8 rows x 64 each
#pragma unroll
    for (int g = 0; g < NG; ++g) {
      const int cr0 = wid * RW + g * 8;  // wave-uniform
      if (cr0 < BM) {
        glds16(aRow + (size_t)cr0 * lda + kt * 64, &Ak[buf][cr0 * 64]);
      } else {
        glds16(bRow + (size_t)(cr0 - BM) * ldb + kt * 64,
               &Bk[buf][(cr0 - BM) * 64]);
      }
    }
  };

  f32x4 acc[4][NI] = {};
  auto compute = [&](int buf) {
#pragma unroll
    for (int ks = 0; ks < 2; ++ks) {
      const int pc = (ks << 2) | lg;
      const int po = ((pc ^ (lr & 7)) << 3);  // read-side un-swizzle
      short8 af[4], bf[NI];
#pragma unroll
      for (int i = 0; i < 4; ++i)
        af[i] = *(const short8*)(&Ak[buf][(wm * 64 + i * 16 + lr) * 64 + po]);
#pragma unroll
      for (int i = 0; i < NI; ++i)
        bf[i] =
            *(const short8*)(&Bk[buf][(wn * WCOL + i * 16 + lr) * 64 + po]);
#pragma unroll
      for (int mi = 0; mi < 4; ++mi)
#pragma unroll
        for (int ni = 0; ni < NI; ++ni)
          acc[mi][ni] = __builtin_amdgcn_mfma_f32_16x16x32_bf16(
              af[mi], bf[ni], acc[mi][ni], 0, 0, 0);
    }
  };

  const int nk = K >> 6;
  int cur = 0;
  stage(0, 0);
  __syncthreads();
  for (int kt = 0; kt < nk - 1; ++kt) {
    stage(cur ^ 1, kt + 1);  // next K-tile in flight under compute
    compute(cur);
    __syncthreads();
    cur ^= 1;
  }
  compute(cur);

#pragma unroll
  for (int mi = 0; mi < 4; ++mi)
#pragma unroll
    for (int ni = 0; ni < NI; ++ni)
#pragma unroll
      for (int r = 0; r < 4; ++r) {
        int grow = tm * BM + wm * 64 + mi * 16 + lg * 4 + r;
        int gcol = tn * BN + wn * WCOL + ni * 16 + lr;
        if (grow < M) {
          float v = acc[mi][ni][r];
          if constexpr (EPI == 4) {
            outf[(size_t)blockIdx.z * M * ldo + (size_t)grow * ldo + gcol] =
                v;
          } else {
            epi_store<EPI>(v + bias[gcol], grow, gcol, outb, ldo, outf, pos);
          }
        }
      }
}

// redK: h += bias + Cp[0] + Cp[1]  (mlp2 residual reduce, float4)
__global__ __launch_bounds__(256) void redK(const float* __restrict__ Cp,
                                            const float* __restrict__ bias,
                                            float* __restrict__ h) {
  size_t i = ((size_t)blockIdx.x * 256 + threadIdx.x) * 4;  // < 6304*768
  float4 p0 = *(const float4*)(Cp + i);
  float4 p1 = *(const float4*)(Cp + 6304ull * 768 + i);
  float4 hv = *(const float4*)(h + i);
  float4 bv = *(const float4*)(bias + (int)(i % 768));
  hv.x += p0.x + p1.x + bv.x;
  hv.y += p0.y + p1.y + bv.y;
  hv.z += p0.z + p1.z + bv.z;
  hv.w += p0.w + p1.w + bv.w;
  *(float4*)(h + i) = hv;
}

// -------- gemmP (patch embed): 64x128 tile, BK=32, 4 waves, 2-phase -------
template <int EPI, int BM>
__global__ __launch_bounds__(256) void gemmP(
    const u16* __restrict__ A, int lda, const u16* __restrict__ Bt, int ldb,
    const float* __restrict__ bias, u16* __restrict__ outb, int ldo,
    float* __restrict__ outf, const float* __restrict__ pos, int M, int N,
    int K) {
  constexpr int MI = BM / 32;  // acc rows per wave (2 or 4)
  __shared__ __align__(16) u16 Ak[2][BM * 32];
  __shared__ __align__(16) u16 Bk[2][128 * 32];
  const int tid = threadIdx.x;
  const int lane = tid & 63, wid = tid >> 6;
  const int wm = wid >> 1, wn = wid & 1;
  const int lg = lane >> 4, lr = lane & 15;
  const int nwg = gridDim.x * gridDim.y;
  const int wg = xcd_swz(blockIdx.y * gridDim.x + blockIdx.x, nwg);
  const int tn = wg % gridDim.x, tm = wg / gridDim.x;

  const int sr = lane >> 2;
  const int sc4 = (((lane & 3) ^ ((lane >> 3) & 3)) << 3);
  const u16* aSrc = A + (size_t)(tm * BM + wid * (BM / 4) + sr) * lda + sc4;
  const u16* bSrc = Bt + (size_t)(tn * 128 + wid * 32 + sr) * ldb + sc4;
  const size_t aRow16 = (size_t)16 * lda, bRow16 = (size_t)16 * ldb;

  auto stage = [&](int buf, int kt) {
    const u16* ak = aSrc + kt * 32;
    const u16* bk = bSrc + kt * 32;
    u16* ad = &Ak[buf][wid * (BM / 4) * 32];
    u16* bd = &Bk[buf][wid * 1024];
    glds16(ak, ad);
    if constexpr (BM == 128) glds16(ak + aRow16, ad + 512);
    glds16(bk, bd);
    glds16(bk + bRow16, bd + 512);
  };

  const int rp = (lg ^ ((lr >> 1) & 3)) << 3;
  f32x4 acc[MI][4] = {};
  auto compute = [&](int buf) {
    short8 af[MI], bfr[4];
#pragma unroll
    for (int i = 0; i < MI; ++i)
      af[i] =
          *(const short8*)(&Ak[buf][(wm * (BM / 2) + i * 16 + lr) * 32 + rp]);
#pragma unroll
    for (int i = 0; i < 4; ++i)
      bfr[i] = *(const short8*)(&Bk[buf][(wn * 64 + i * 16 + lr) * 32 + rp]);
#pragma unroll
    for (int mi = 0; mi < MI; ++mi)
#pragma unroll
      for (int ni = 0; ni < 4; ++ni)
        acc[mi][ni] = __builtin_amdgcn_mfma_f32_16x16x32_bf16(
            af[mi], bfr[ni], acc[mi][ni], 0, 0, 0);
  };

  const int nk = K >> 5;
  int cur = 0;
  stage(0, 0);
  __syncthreads();
  for (int kt = 0; kt < nk - 1; ++kt) {
    stage(cur ^ 1, kt + 1);
    compute(cur);
    __syncthreads();
    cur ^= 1;
  }
  compute(cur);

#pragma unroll
  for (int mi = 0; mi < MI; ++mi)
#pragma unroll
    for (int ni = 0; ni < 4; ++ni)
#pragma unroll
      for (int r = 0; r < 4; ++r) {
        int grow = tm * BM + wm * (BM / 2) + mi * 16 + lg * 4 + r;
        int gcol = tn * 128 + wn * 64 + ni * 16 + lr;
        if (grow < M)
          epi_store<EPI>(acc[mi][ni][r] + bias[gcol], grow, gcol, outb, ldo,
                         outf, pos);
      }
}

// ---------------- attention ----------------
// fused QK^T + softmax: P[bh][q][k] bf16, row stride 224, cols 197..223 = 0.
__global__ __launch_bounds__(64) void qksm_k(const u16* __restrict__ qkv,
                                             u16* __restrict__ P) {
  const int bh = blockIdx.x;  // b*12+h
  const int qt = blockIdx.y;  // 0..12
  const int lane = threadIdx.x;
  const int lg = lane >> 4, lr = lane & 15;
  const int b = bh / 12, hh = bh - b * 12;
  const u16* base = qkv + (size_t)b * 197 * 2304 + hh * 64;
  int qrow = qt * 16 + lr;
  if (qrow > 196) qrow = 196;
  const u16* qp = base + (size_t)qrow * 2304 + lg * 8;
  short8 a0 = *(const short8*)(qp);
  short8 a1 = *(const short8*)(qp + 32);
  f32x4 c[13];
  const bool kval[2] = {true, (12 * 16 + lr) <= 196};
#pragma unroll
  for (int kt = 0; kt < 13; ++kt) {
    int krow = kt * 16 + lr;
    if (krow > 196) krow = 196;
    const u16* kp = base + 768 + (size_t)krow * 2304 + lg * 8;
    short8 b0 = *(const short8*)(kp);
    short8 b1 = *(const short8*)(kp + 32);
    f32x4 t = {0.f, 0.f, 0.f, 0.f};
    t = __builtin_amdgcn_mfma_f32_16x16x32_bf16(a0, b0, t, 0, 0, 0);
    c[kt] = __builtin_amdgcn_mfma_f32_16x16x32_bf16(a1, b1, t, 0, 0, 0);
  }
  float mr[4], sr_[4];
#pragma unroll
  for (int r = 0; r < 4; ++r) {
    float mm = -3.4e38f;
#pragma unroll
    for (int kt = 0; kt < 13; ++kt)
      if (kval[kt == 12]) mm = fmaxf(mm, c[kt][r] * 0.125f);
#pragma unroll
    for (int o = 1; o < 16; o <<= 1) mm = fmaxf(mm, __shfl_xor(mm, o, 64));
    mr[r] = mm;
  }
#pragma unroll
  for (int r = 0; r < 4; ++r) {
    float s = 0.f;
#pragma unroll
    for (int kt = 0; kt < 13; ++kt) {
      float e = kval[kt == 12] ? __expf(c[kt][r] * 0.125f - mr[r]) : 0.f;
      c[kt][r] = e;
      s += e;
    }
#pragma unroll
    for (int o = 1; o < 16; o <<= 1) s += __shfl_xor(s, o, 64);
    sr_[r] = 1.0f / s;
  }
  u16* pb = P + (size_t)bh * 197 * 224;
#pragma unroll
  for (int r = 0; r < 4; ++r) {
    int q = qt * 16 + lg * 4 + r;
    if (q < 197) {
#pragma unroll
      for (int kt = 0; kt < 13; ++kt)
        pb[(size_t)q * 224 + kt * 16 + lr] = f2bf(c[kt][r] * sr_[r]);
      pb[(size_t)q * 224 + 208 + lr] = 0;  // pad cols 208..223
    }
  }
}

// o[b][q][h*64+d] = sum_k P[bh][q][k](bf16) * V[b][k][h][d]
__global__ __launch_bounds__(256) void pv_k(const u16* __restrict__ qkv,
                                            const u16* __restrict__ P,
                                            u16* __restrict__ o) {
  const int bh = blockIdx.x;
  const int b = bh / 12, hh = bh - b * 12;
  const int tid = threadIdx.x;
  const int lane = tid & 63, ct = tid >> 6;  // wave = 16-col tile of HD
  const int lg = lane >> 4, lr = lane & 15;
  const u16* vbase =
      qkv + (size_t)b * 197 * 2304 + 1536 + hh * 64 + ct * 16 + lr;
  short8 vf[7];
#pragma unroll
  for (int ks = 0; ks < 7; ++ks) {
    ushort8 t;
#pragma unroll
    for (int j = 0; j < 8; ++j) {
      int kk = ks * 32 + lg * 8 + j;
      if (kk > 196) kk = 196;  // P is 0 there, value irrelevant
      t[j] = vbase[(size_t)kk * 2304];
    }
    vf[ks] = __builtin_bit_cast(short8, t);
  }
  const u16* pbase = P + (size_t)bh * 197 * 224;
  u16* ob = o + (size_t)b * 197 * 768 + hh * 64 + ct * 16;
  for (int qt = 0; qt < 13; ++qt) {
    int q = qt * 16 + lr;
    if (q > 196) q = 196;
    const u16* pp = pbase + (size_t)q * 224 + lg * 8;
    f32x4 acc = {0.f, 0.f, 0.f, 0.f};
#pragma unroll
    for (int ks = 0; ks < 7; ++ks) {
      short8 af = *(const short8*)(pp + ks * 32);
      acc = __builtin_amdgcn_mfma_f32_16x16x32_bf16(af, vf[ks], acc, 0, 0, 0);
    }
#pragma unroll
    for (int r = 0; r < 4; ++r) {
      int qq = qt * 16 + lg * 4 + r;
      if (qq < 197) ob[(size_t)qq * 768 + lr] = f2bf(acc[r]);
    }
  }
}

// ---------------- layernorm: 4 rows/block, 64 lanes/row, float4 ----------
__global__ __launch_bounds__(256) void ln_k(const float* __restrict__ x,
                                            const float* __restrict__ w,
                                            const float* __restrict__ bb,
                                            u16* __restrict__ y) {
  const int lane = threadIdx.x & 63, wv = threadIdx.x >> 6;
  const int r = blockIdx.x * 4 + wv;
  const float* xr = x + (size_t)r * 768;
  float4 v[3];
  float s = 0.f, q = 0.f;
#pragma unroll
  for (int i = 0; i < 3; ++i) {
    v[i] = *(const float4*)(xr + i * 256 + lane * 4);
    s += v[i].x + v[i].y + v[i].z + v[i].w;
    q += v[i].x * v[i].x + v[i].y * v[i].y + v[i].z * v[i].z +
         v[i].w * v[i].w;
  }
  s = wred_sum(s);
  q = wred_sum(q);
  float mu = s * (1.f / 768.f);
  float var = q * (1.f / 768.f) - mu * mu;
  float rs = rsqrtf(var + 1e-5f);
  u16* yr = y + (size_t)r * 768;
#pragma unroll
  for (int i = 0; i < 3; ++i) {
    float4 wv4 = *(const float4*)(w + i * 256 + lane * 4);
    float4 bv4 = *(const float4*)(bb + i * 256 + lane * 4);
    ushort4 o;
    o.x = f2bf((v[i].x - mu) * rs * wv4.x + bv4.x);
    o.y = f2bf((v[i].y - mu) * rs * wv4.y + bv4.y);
    o.z = f2bf((v[i].z - mu) * rs * wv4.z + bv4.z);
    o.w = f2bf((v[i].w - mu) * rs * wv4.w + bv4.w);
    *(ushort4*)(yr + i * 256 + lane * 4) = o;
  }
}

// ---------------- final LN(cls row) + head ----------------
__global__ __launch_bounds__(256) void head_k(
    const float* __restrict__ h, const float* __restrict__ lnw,
    const float* __restrict__ lnb, const float* __restrict__ hw,
    const float* __restrict__ hb, float* __restrict__ out) {
  const int b = blockIdx.x, tid = threadIdx.x;
  const float* xr = h + (size_t)b * 197 * 768;
  float v0 = xr[tid], v1 = xr[tid + 256], v2 = xr[tid + 512];
  float s = v0 + v1 + v2;
  float q = v0 * v0 + v1 * v1 + v2 * v2;
  s = wred_sum(s);
  q = wred_sum(q);
  __shared__ float ss[4], qs[4];
  int lane = tid & 63, wid = tid >> 6;
  if (lane == 0) { ss[wid] = s; qs[wid] = q; }
  __syncthreads();
  float S = ss[0] + ss[1] + ss[2] + ss[3];
  float Q = qs[0] + qs[1] + qs[2] + qs[3];
  float mu = S * (1.f / 768.f);
  float var = Q * (1.f / 768.f) - mu * mu;
  float rs = rsqrtf(var + 1e-5f);
  __shared__ float yb[768];
  yb[tid] = (v0 - mu) * rs * lnw[tid] + lnb[tid];
  yb[tid + 256] = (v1 - mu) * rs * lnw[tid + 256] + lnb[tid + 256];
  yb[tid + 512] = (v2 - mu) * rs * lnw[tid + 512] + lnb[tid + 512];
  __syncthreads();
  float p[10] = {};
  for (int e = tid; e < 768; e += 256) {
    float yv = yb[e];
#pragma unroll
    for (int n = 0; n < 10; ++n) p[n] += yv * hw[(size_t)e * 10 + n];
  }
#pragma unroll
  for (int n = 0; n < 10; ++n) p[n] = wred_sum(p[n]);
  __shared__ float red[4][10];
  if (lane == 0)
#pragma unroll
    for (int n = 0; n < 10; ++n) red[wid][n] = p[n];
  __syncthreads();
  if (tid < 10)
    out[b * 10 + tid] =
        red[0][tid] + red[1][tid] + red[2][tid] + red[3][tid] + hb[tid];
}

// ---------------- host orchestration ----------------
extern "C" void kernel_launch(void* const* d_in, const int* in_sizes, int n_in,
                              void* d_out, int out_size, void* d_ws,
                              size_t ws_size, hipStream_t stream) {
  const float* x = (const float*)d_in[0];
  const float* conv_w = (const float*)d_in[1];
  const float* conv_b = (const float*)d_in[2];
  const float* cls = (const float*)d_in[3];
  const float* pos = (const float*)d_in[4];
  const float* ln1w = (const float*)d_in[5];
  const float* ln1b = (const float*)d_in[6];
  const float* qkvw = (const float*)d_in[7];
  const float* qkvbias = (const float*)d_in[8];
  const float* projw = (const float*)d_in[9];
  const float* projb = (const float*)d_in[10];
  const float* ln2w = (const float*)d_in[11];
  const float* ln2b = (const float*)d_in[12];
  const float* w1f = (const float*)d_in[13];
  const float* b1 = (const float*)d_in[14];
  const float* w2f = (const float*)d_in[15];
  const float* b2 = (const float*)d_in[16];
  const float* lnfw = (const float*)d_in[17];
  const float* lnfb = (const float*)d_in[18];
  const float* headw = (const float*)d_in[19];
  const float* headb = (const float*)d_in[20];
  float* out = (float*)d_out;

  // workspace layout; A-side buffers padded to 6400 rows (tiles read past
  // M=6304; garbage rows are finite, never reach guarded outputs)
  char* p = (char*)d_ws;
  auto take = [&](size_t bytes) {
    char* q = p;
    p += (bytes + 255) & ~(size_t)255;
    return q;
  };
  u16* wq = (u16*)take(12ull * 768 * 2304 * 2);   // [N=2304][K=768] per layer
  u16* wpj = (u16*)take(12ull * 768 * 768 * 2);   // [768][768]
  u16* w1 = (u16*)take(12ull * 768 * 3072 * 2);   // [3072][768]
  u16* w2 = (u16*)take(12ull * 3072 * 768 * 2);   // [768][3072]
  u16* wc = (u16*)take(768ull * 768 * 2);         // conv_w already [N][K]
  float* h = (float*)take(6304ull * 768 * 4);
  u16* y = (u16*)take(6400ull * 768 * 2);
  u16* qkv = (u16*)take(6400ull * 2304 * 2);
  u16* ob = (u16*)take(6400ull * 768 * 2);
  u16* mlpb = (u16*)take(6400ull * 3072 * 2);  // also holds patches at start
  u16* P = (u16*)take(384ull * 197 * 224 * 2);
  // split-K partial planes for mlp2: 2 x 6304x768 fp32 = 38.7MB, ALIASED
  // onto y+qkv+ob (free during mlp2; next writer of y is next ln1 after redK)
  float* skP = (float*)y;
  (void)ws_size; (void)in_sizes; (void)n_in; (void)out_size;

  // weight conversion fp32 -> bf16, transposed to [N][K]
  tpose_k<<<dim3(72, 24, 12), 256, 0, stream>>>(qkvw, wq, 768, 2304);
  tpose_k<<<dim3(24, 24, 12), 256, 0, stream>>>(projw, wpj, 768, 768);
  tpose_k<<<dim3(96, 24, 12), 256, 0, stream>>>(w1f, w1, 768, 3072);
  tpose_k<<<dim3(24, 96, 12), 256, 0, stream>>>(w2f, w2, 3072, 768);
  cvt4_k<<<576, 256, 0, stream>>>(conv_w, wc, 768 * 768 / 4);

  // patch embed
  patch_k<<<6272 * 768 / 256, 256, 0, stream>>>(x, mlpb);
  gemmP<3, 64><<<dim3(6, 98), 256, 0, stream>>>(mlpb, 768, wc, 768, conv_b,
                                                nullptr, 0, h, pos, 6272, 768,
                                                768);
  clspos_k<<<32 * 768 / 256, 256, 0, stream>>>(cls, pos, h);

  for (int i = 0; i < 12; ++i) {
    ln_k<<<1576, 256, 0, stream>>>(h, ln1w + i * 768, ln1b + i * 768, y);
    gemmU<0, 128, 256><<<dim3(9, 50), 512, 0, stream>>>(
        y, 768, wq + (size_t)i * 768 * 2304, 768, qkvbias + i * 2304, qkv,
        2304, nullptr, nullptr, 6304, 768);
    qksm_k<<<dim3(384, 13), 64, 0, stream>>>(qkv, P);
    pv_k<<<384, 256, 0, stream>>>(qkv, P, ob);
    gemmU<2, 128, 128><<<dim3(6, 50), 512, 0, stream>>>(
        ob, 768, wpj + (size_t)i * 768 * 768, 768, projb + i * 768, nullptr,
        768, h, nullptr, 6304, 768);
    ln_k<<<1576, 256, 0, stream>>>(h, ln2w + i * 768, ln2b + i * 768, y);
    gemmU<1, 128, 256><<<dim3(12, 50), 512, 0, stream>>>(
        y, 768, w1 + (size_t)i * 768 * 3072, 768, b1 + i * 3072, mlpb, 3072,
        nullptr, nullptr, 6304, 768);
    // mlp2: split-K x2 (KC=1536) on 256x128 tile -> 300 blocks
    gemmU<4, 256, 128><<<dim3(6, 25, 2), 512, 0, stream>>>(
        mlpb, 3072, w2 + (size_t)i * 3072 * 768, 3072, nullptr, nullptr, 768,
        skP, nullptr, 6304, 1536);
    redK<<<4728, 256, 0, stream>>>(skP, b2 + i * 768, h);
  }

  head_k<<<32, 256, 0, stream>>>(h, lnfw, lnfb, headw, headb, out);
}

// Round 13
// 3103.914 us; speedup vs baseline: 1.1457x; 1.1457x over previous
//
#include <hip/hip_runtime.h>

// ViT-B/16 forward, B=32, S=197, E=768, H=12, HD=64, MLP=3072, DEPTH=12.
// Round 13: revert GEMMs to R10 (best). New: (1) pv_k stages V in LDS via
// coalesced global_load_lds (old code: 56 scalar u16 gathers/thread at
// 4.6KB stride = a cache line per element); (2) redln_k fuses mlp2's
// split-K reduce with the NEXT layer's ln1 (saves one full h read+write
// pass per layer). skP gets dedicated ws (alias would race with y writes).

typedef __attribute__((ext_vector_type(8))) short short8;
typedef __attribute__((ext_vector_type(8))) unsigned short ushort8;
typedef __attribute__((ext_vector_type(4))) float f32x4;
typedef unsigned short u16;

#define DEV __device__ __forceinline__

DEV u16 f2bf(float f) {
  unsigned int u = __builtin_bit_cast(unsigned int, f);
  u += 0x7fffu + ((u >> 16) & 1u);
  return (u16)(u >> 16);
}
DEV float wred_sum(float v) {
  for (int o = 32; o; o >>= 1) v += __shfl_xor(v, o, 64);
  return v;
}
DEV void glds16(const void* gp, void* lp) {
  __builtin_amdgcn_global_load_lds(
      (const __attribute__((address_space(1))) void*)gp,
      (__attribute__((address_space(3))) void*)lp, 16, 0, 0);
}
// m204 bijective XCD swizzle: contiguous wg chunk per XCD
DEV int xcd_swz(int flat, int nwg) {
  int q = nwg >> 3, r = nwg & 7;
  int x = flat & 7, o = flat >> 3;
  return (x < r ? x * (q + 1) : r * (q + 1) + (x - r) * q) + o;
}

// ---------------- weight conversion ----------------
__global__ __launch_bounds__(256) void cvt4_k(const float* __restrict__ s,
                                              u16* __restrict__ d, long n4) {
  long i = (long)blockIdx.x * 256 + threadIdx.x;
  if (i >= n4) return;
  float4 v = ((const float4*)s)[i];
  ushort4 o;
  o.x = f2bf(v.x); o.y = f2bf(v.y); o.z = f2bf(v.z); o.w = f2bf(v.w);
  ((ushort4*)d)[i] = o;
}

// fp32 [K][N] (blockIdx.z selects layer) -> bf16 [N][K], tiled 32x32
__global__ __launch_bounds__(256) void tpose_k(const float* __restrict__ s,
                                               u16* __restrict__ d, int K,
                                               int N) {
  __shared__ float t[32][33];
  const int bx = blockIdx.x;  // n tile
  const int by = blockIdx.y;  // k tile
  const size_t base = (size_t)blockIdx.z * K * N;
  const int c = threadIdx.x & 31, r0 = threadIdx.x >> 5;
#pragma unroll
  for (int i = 0; i < 4; ++i) {
    int r = r0 + i * 8;
    t[r][c] = s[base + (size_t)(by * 32 + r) * N + bx * 32 + c];
  }
  __syncthreads();
#pragma unroll
  for (int i = 0; i < 4; ++i) {
    int r = r0 + i * 8;
    d[base + (size_t)(bx * 32 + r) * K + by * 32 + c] = f2bf(t[c][r]);
  }
}

// patches[b][p][d] <- x[b][c][gy*16+py][gx*16+px], bf16
__global__ __launch_bounds__(256) void patch_k(const float* __restrict__ x,
                                               u16* __restrict__ pt) {
  int i = blockIdx.x * 256 + threadIdx.x;  // 6272*768 exactly
  int d = i % 768;
  int bp = i / 768;
  int p = bp % 196, b = bp / 196;
  int c = d >> 8, pd = d & 255;
  int py = pd >> 4, px = pd & 15;
  int gy = p / 14, gx = p - gy * 14;
  size_t src = ((size_t)(b * 3 + c) * 224 + gy * 16 + py) * 224 + gx * 16 + px;
  pt[i] = f2bf(x[src]);
}

// h[b][0][:] = cls + pos[0]
__global__ __launch_bounds__(256) void clspos_k(const float* __restrict__ cls,
                                                const float* __restrict__ pos,
                                                float* __restrict__ h) {
  int i = blockIdx.x * 256 + threadIdx.x;  // 32*768
  int b = i / 768, e = i - b * 768;
  h[(size_t)b * 197 * 768 + e] = cls[e] + pos[e];
}

// ---------------- epilogue helper ----------------
template <int EPI>
DEV void epi_store(float v, int grow, int gcol, u16* outb, int ldo,
                   float* outf, const float* pos) {
  if constexpr (EPI == 0) {
    outb[(size_t)grow * ldo + gcol] = f2bf(v);
  } else if constexpr (EPI == 1) {
    // gelu(x) ~= x * sigmoid(1.5957691(x + 0.044715 x^3))
    float u = __expf(-1.5957691216f * (v + 0.044715f * v * v * v));
    outb[(size_t)grow * ldo + gcol] = f2bf(v / (1.f + u));
  } else if constexpr (EPI == 2) {
    outf[(size_t)grow * ldo + gcol] += v;
  } else {
    int b = grow / 196, p = grow - b * 196;
    outf[(size_t)(grow + b + 1) * 768 + gcol] =
        v + pos[(size_t)(p + 1) * 768 + gcol];
  }
}

// -------- gemmK64: C[M,N] = A[M,K] @ Bt[N,K], 128x128 tile, BK=64 ---------
// 8 waves (2m x 4n), 2-phase double-buffer, global_load_lds(16B), both-sides
// chunk-XOR swizzle, tm-major flat + XCD block swizzle (R10 exact).
template <int EPI>
__global__ __launch_bounds__(512) void gemmK64(
    const u16* __restrict__ A, int lda, const u16* __restrict__ Bt, int ldb,
    const float* __restrict__ bias, u16* __restrict__ outb, int ldo,
    float* __restrict__ outf, const float* __restrict__ pos, int M, int N,
    int K) {
  __shared__ __align__(16) u16 Ak[2][128 * 64];
  __shared__ __align__(16) u16 Bk[2][128 * 64];
  const int tid = threadIdx.x;
  const int lane = tid & 63, wid = tid >> 6;
  const int wm = wid >> 2, wn = wid & 3;
  const int lg = lane >> 4, lr = lane & 15;
  const int nwg = gridDim.x * gridDim.y;
  const int wg = xcd_swz(blockIdx.y * gridDim.x + blockIdx.x, nwg);
  const int tn = wg % gridDim.x, tm = wg / gridDim.x;

  const int r8 = lane >> 3, c8 = lane & 7;
  const int swc = (c8 ^ r8) << 3;  // source chunk pre-swizzled (rule #21)
  const u16* aS = A + (size_t)(tm * 128 + wid * 16 + r8) * lda + swc;
  const u16* bS = Bt + (size_t)(tn * 128 + wid * 16 + r8) * ldb + swc;

  auto stage = [&](int buf, int kt) {  // 4 glds16/wave
    const u16* ak = aS + kt * 64;
    const u16* bk = bS + kt * 64;
    u16* ad = &Ak[buf][wid * 1024];
    u16* bd = &Bk[buf][wid * 1024];
    glds16(ak, ad);
    glds16(ak + (size_t)8 * lda, ad + 512);
    glds16(bk, bd);
    glds16(bk + (size_t)8 * ldb, bd + 512);
  };

  f32x4 acc[4][2] = {};
  auto compute = [&](int buf) {
#pragma unroll
    for (int ks = 0; ks < 2; ++ks) {
      const int pc = (ks << 2) | lg;
      const int po = ((pc ^ (lr & 7)) << 3);  // read-side un-swizzle
      short8 af[4], bf2[2];
#pragma unroll
      for (int i = 0; i < 4; ++i)
        af[i] = *(const short8*)(&Ak[buf][(wm * 64 + i * 16 + lr) * 64 + po]);
#pragma unroll
      for (int i = 0; i < 2; ++i)
        bf2[i] = *(const short8*)(&Bk[buf][(wn * 32 + i * 16 + lr) * 64 + po]);
#pragma unroll
      for (int mi = 0; mi < 4; ++mi)
#pragma unroll
        for (int ni = 0; ni < 2; ++ni)
          acc[mi][ni] = __builtin_amdgcn_mfma_f32_16x16x32_bf16(
              af[mi], bf2[ni], acc[mi][ni], 0, 0, 0);
    }
  };

  const int nk = K >> 6;
  int cur = 0;
  stage(0, 0);
  __syncthreads();
  for (int kt = 0; kt < nk - 1; ++kt) {
    stage(cur ^ 1, kt + 1);  // next K-tile in flight under compute
    compute(cur);
    __syncthreads();
    cur ^= 1;
  }
  compute(cur);

#pragma unroll
  for (int mi = 0; mi < 4; ++mi)
#pragma unroll
    for (int ni = 0; ni < 2; ++ni)
#pragma unroll
      for (int r = 0; r < 4; ++r) {
        int grow = tm * 128 + wm * 64 + mi * 16 + lg * 4 + r;
        int gcol = tn * 128 + wn * 32 + ni * 16 + lr;
        if (grow < M)
          epi_store<EPI>(acc[mi][ni][r] + bias[gcol], grow, gcol, outb, ldo,
                         outf, pos);
      }
}

// -------- gemmSK: split-K partial GEMM, 128x128 tile, BK=64 ----------------
__global__ __launch_bounds__(512) void gemmSK(const u16* __restrict__ A,
                                              int lda,
                                              const u16* __restrict__ Bt,
                                              int ldb, float* __restrict__ Cp,
                                              int M, int KC) {
  __shared__ __align__(16) u16 Ak[2][128 * 64];
  __shared__ __align__(16) u16 Bk[2][128 * 64];
  const int tid = threadIdx.x;
  const int lane = tid & 63, wid = tid >> 6;
  const int wm = wid >> 2, wn = wid & 3;
  const int lg = lane >> 4, lr = lane & 15;
  const int z = blockIdx.z;
  const int nwg = gridDim.x * gridDim.y;
  const int wg = xcd_swz(blockIdx.y * gridDim.x + blockIdx.x, nwg);
  const int tn = wg % gridDim.x, tm = wg / gridDim.x;

  const int r8 = lane >> 3, c8 = lane & 7;
  const int swc = (c8 ^ r8) << 3;
  const u16* aS = A + (size_t)(tm * 128 + wid * 16 + r8) * lda + z * KC + swc;
  const u16* bS = Bt + (size_t)(tn * 128 + wid * 16 + r8) * ldb + z * KC + swc;

  auto stage = [&](int buf, int kt) {
    const u16* ak = aS + kt * 64;
    const u16* bk = bS + kt * 64;
    u16* ad = &Ak[buf][wid * 1024];
    u16* bd = &Bk[buf][wid * 1024];
    glds16(ak, ad);
    glds16(ak + (size_t)8 * lda, ad + 512);
    glds16(bk, bd);
    glds16(bk + (size_t)8 * ldb, bd + 512);
  };

  f32x4 acc[4][2] = {};
  auto compute = [&](int buf) {
#pragma unroll
    for (int ks = 0; ks < 2; ++ks) {
      const int pc = (ks << 2) | lg;
      const int po = ((pc ^ (lr & 7)) << 3);
      short8 af[4], bf2[2];
#pragma unroll
      for (int i = 0; i < 4; ++i)
        af[i] = *(const short8*)(&Ak[buf][(wm * 64 + i * 16 + lr) * 64 + po]);
#pragma unroll
      for (int i = 0; i < 2; ++i)
        bf2[i] = *(const short8*)(&Bk[buf][(wn * 32 + i * 16 + lr) * 64 + po]);
#pragma unroll
      for (int mi = 0; mi < 4; ++mi)
#pragma unroll
        for (int ni = 0; ni < 2; ++ni)
          acc[mi][ni] = __builtin_amdgcn_mfma_f32_16x16x32_bf16(
              af[mi], bf2[ni], acc[mi][ni], 0, 0, 0);
    }
  };

  const int nk = KC >> 6;
  int cur = 0;
  stage(0, 0);
  __syncthreads();
  for (int kt = 0; kt < nk - 1; ++kt) {
    stage(cur ^ 1, kt + 1);
    compute(cur);
    __syncthreads();
    cur ^= 1;
  }
  compute(cur);

  float* outp = Cp + (size_t)z * M * 768;
#pragma unroll
  for (int mi = 0; mi < 4; ++mi)
#pragma unroll
    for (int ni = 0; ni < 2; ++ni)
#pragma unroll
      for (int r = 0; r < 4; ++r) {
        int grow = tm * 128 + wm * 64 + mi * 16 + lg * 4 + r;
        int gcol = tn * 128 + wn * 32 + ni * 16 + lr;
        if (grow < M) outp[(size_t)grow * 768 + gcol] = acc[mi][ni][r];
      }
}

// redK: h += bias + Cp[0] + Cp[1]  (last-layer reduce, float4)
__global__ __launch_bounds__(256) void redK(const float* __restrict__ Cp,
                                            const float* __restrict__ bias,
                                            float* __restrict__ h) {
  size_t i = ((size_t)blockIdx.x * 256 + threadIdx.x) * 4;  // < 6304*768
  float4 p0 = *(const float4*)(Cp + i);
  float4 p1 = *(const float4*)(Cp + 6304ull * 768 + i);
  float4 hv = *(const float4*)(h + i);
  float4 bv = *(const float4*)(bias + (int)(i % 768));
  hv.x += p0.x + p1.x + bv.x;
  hv.y += p0.y + p1.y + bv.y;
  hv.z += p0.z + p1.z + bv.z;
  hv.w += p0.w + p1.w + bv.w;
  *(float4*)(h + i) = hv;
}

// redln: h' = h + bias + Cp[0] + Cp[1]; h = h'; y = ln(h', w, b) bf16.
// Fuses mlp2's split-K reduce with the NEXT layer's ln1 (one h pass saved).
__global__ __launch_bounds__(256) void redln_k(
    const float* __restrict__ Cp, const float* __restrict__ bias,
    float* __restrict__ h, const float* __restrict__ lnw,
    const float* __restrict__ lnb, u16* __restrict__ y) {
  const int lane = threadIdx.x & 63, wv = threadIdx.x >> 6;
  const int r = blockIdx.x * 4 + wv;
  const size_t base = (size_t)r * 768;
  float4 a[3];
  float s = 0.f, q = 0.f;
#pragma unroll
  for (int i = 0; i < 3; ++i) {
    const int off = i * 256 + lane * 4;
    float4 hv = *(const float4*)(h + base + off);
    float4 p0 = *(const float4*)(Cp + base + off);
    float4 p1 = *(const float4*)(Cp + 6304ull * 768 + base + off);
    float4 bv = *(const float4*)(bias + off);
    a[i].x = hv.x + p0.x + p1.x + bv.x;
    a[i].y = hv.y + p0.y + p1.y + bv.y;
    a[i].z = hv.z + p0.z + p1.z + bv.z;
    a[i].w = hv.w + p0.w + p1.w + bv.w;
    s += a[i].x + a[i].y + a[i].z + a[i].w;
    q += a[i].x * a[i].x + a[i].y * a[i].y + a[i].z * a[i].z +
         a[i].w * a[i].w;
  }
  s = wred_sum(s);
  q = wred_sum(q);
  float mu = s * (1.f / 768.f);
  float var = q * (1.f / 768.f) - mu * mu;
  float rs = rsqrtf(var + 1e-5f);
#pragma unroll
  for (int i = 0; i < 3; ++i) {
    const int off = i * 256 + lane * 4;
    *(float4*)(h + base + off) = a[i];
    float4 wv4 = *(const float4*)(lnw + off);
    float4 bv4 = *(const float4*)(lnb + off);
    ushort4 o;
    o.x = f2bf((a[i].x - mu) * rs * wv4.x + bv4.x);
    o.y = f2bf((a[i].y - mu) * rs * wv4.y + bv4.y);
    o.z = f2bf((a[i].z - mu) * rs * wv4.z + bv4.z);
    o.w = f2bf((a[i].w - mu) * rs * wv4.w + bv4.w);
    *(ushort4*)(y + base + off) = o;
  }
}

// -------- gemmP: BMx128 tile, BK=32, 4 waves, 2-phase (R10 exact) ---------
template <int EPI, int BM>
__global__ __launch_bounds__(256) void gemmP(
    const u16* __restrict__ A, int lda, const u16* __restrict__ Bt, int ldb,
    const float* __restrict__ bias, u16* __restrict__ outb, int ldo,
    float* __restrict__ outf, const float* __restrict__ pos, int M, int N,
    int K) {
  constexpr int MI = BM / 32;  // acc rows per wave (2 or 4)
  __shared__ __align__(16) u16 Ak[2][BM * 32];
  __shared__ __align__(16) u16 Bk[2][128 * 32];
  const int tid = threadIdx.x;
  const int lane = tid & 63, wid = tid >> 6;
  const int wm = wid >> 1, wn = wid & 1;
  const int lg = lane >> 4, lr = lane & 15;
  const int nwg = gridDim.x * gridDim.y;
  const int wg = xcd_swz(blockIdx.y * gridDim.x + blockIdx.x, nwg);
  const int tn = wg % gridDim.x, tm = wg / gridDim.x;

  const int sr = lane >> 2;
  const int sc4 = (((lane & 3) ^ ((lane >> 3) & 3)) << 3);
  const u16* aSrc = A + (size_t)(tm * BM + wid * (BM / 4) + sr) * lda + sc4;
  const u16* bSrc = Bt + (size_t)(tn * 128 + wid * 32 + sr) * ldb + sc4;
  const size_t aRow16 = (size_t)16 * lda, bRow16 = (size_t)16 * ldb;

  auto stage = [&](int buf, int kt) {
    const u16* ak = aSrc + kt * 32;
    const u16* bk = bSrc + kt * 32;
    u16* ad = &Ak[buf][wid * (BM / 4) * 32];
    u16* bd = &Bk[buf][wid * 1024];
    glds16(ak, ad);
    if constexpr (BM == 128) glds16(ak + aRow16, ad + 512);
    glds16(bk, bd);
    glds16(bk + bRow16, bd + 512);
  };

  const int rp = (lg ^ ((lr >> 1) & 3)) << 3;
  f32x4 acc[MI][4] = {};
  auto compute = [&](int buf) {
    short8 af[MI], bfr[4];
#pragma unroll
    for (int i = 0; i < MI; ++i)
      af[i] =
          *(const short8*)(&Ak[buf][(wm * (BM / 2) + i * 16 + lr) * 32 + rp]);
#pragma unroll
    for (int i = 0; i < 4; ++i)
      bfr[i] = *(const short8*)(&Bk[buf][(wn * 64 + i * 16 + lr) * 32 + rp]);
#pragma unroll
    for (int mi = 0; mi < MI; ++mi)
#pragma unroll
      for (int ni = 0; ni < 4; ++ni)
        acc[mi][ni] = __builtin_amdgcn_mfma_f32_16x16x32_bf16(
            af[mi], bfr[ni], acc[mi][ni], 0, 0, 0);
  };

  const int nk = K >> 5;
  int cur = 0;
  stage(0, 0);
  __syncthreads();
  for (int kt = 0; kt < nk - 1; ++kt) {
    stage(cur ^ 1, kt + 1);
    compute(cur);
    __syncthreads();
    cur ^= 1;
  }
  compute(cur);

#pragma unroll
  for (int mi = 0; mi < MI; ++mi)
#pragma unroll
    for (int ni = 0; ni < 4; ++ni)
#pragma unroll
      for (int r = 0; r < 4; ++r) {
        int grow = tm * BM + wm * (BM / 2) + mi * 16 + lg * 4 + r;
        int gcol = tn * 128 + wn * 64 + ni * 16 + lr;
        if (grow < M)
          epi_store<EPI>(acc[mi][ni][r] + bias[gcol], grow, gcol, outb, ldo,
                         outf, pos);
      }
}

// ---------------- attention ----------------
// fused QK^T + softmax: P[bh][q][k] bf16, row stride 224, cols 197..223 = 0.
__global__ __launch_bounds__(64) void qksm_k(const u16* __restrict__ qkv,
                                             u16* __restrict__ P) {
  const int bh = blockIdx.x;  // b*12+h
  const int qt = blockIdx.y;  // 0..12
  const int lane = threadIdx.x;
  const int lg = lane >> 4, lr = lane & 15;
  const int b = bh / 12, hh = bh - b * 12;
  const u16* base = qkv + (size_t)b * 197 * 2304 + hh * 64;
  int qrow = qt * 16 + lr;
  if (qrow > 196) qrow = 196;
  const u16* qp = base + (size_t)qrow * 2304 + lg * 8;
  short8 a0 = *(const short8*)(qp);
  short8 a1 = *(const short8*)(qp + 32);
  f32x4 c[13];
  const bool kval[2] = {true, (12 * 16 + lr) <= 196};
#pragma unroll
  for (int kt = 0; kt < 13; ++kt) {
    int krow = kt * 16 + lr;
    if (krow > 196) krow = 196;
    const u16* kp = base + 768 + (size_t)krow * 2304 + lg * 8;
    short8 b0 = *(const short8*)(kp);
    short8 b1 = *(const short8*)(kp + 32);
    f32x4 t = {0.f, 0.f, 0.f, 0.f};
    t = __builtin_amdgcn_mfma_f32_16x16x32_bf16(a0, b0, t, 0, 0, 0);
    c[kt] = __builtin_amdgcn_mfma_f32_16x16x32_bf16(a1, b1, t, 0, 0, 0);
  }
  float mr[4], sr_[4];
#pragma unroll
  for (int r = 0; r < 4; ++r) {
    float mm = -3.4e38f;
#pragma unroll
    for (int kt = 0; kt < 13; ++kt)
      if (kval[kt == 12]) mm = fmaxf(mm, c[kt][r] * 0.125f);
#pragma unroll
    for (int o = 1; o < 16; o <<= 1) mm = fmaxf(mm, __shfl_xor(mm, o, 64));
    mr[r] = mm;
  }
#pragma unroll
  for (int r = 0; r < 4; ++r) {
    float s = 0.f;
#pragma unroll
    for (int kt = 0; kt < 13; ++kt) {
      float e = kval[kt == 12] ? __expf(c[kt][r] * 0.125f - mr[r]) : 0.f;
      c[kt][r] = e;
      s += e;
    }
#pragma unroll
    for (int o = 1; o < 16; o <<= 1) s += __shfl_xor(s, o, 64);
    sr_[r] = 1.0f / s;
  }
  u16* pb = P + (size_t)bh * 197 * 224;
#pragma unroll
  for (int r = 0; r < 4; ++r) {
    int q = qt * 16 + lg * 4 + r;
    if (q < 197) {
#pragma unroll
      for (int kt = 0; kt < 13; ++kt)
        pb[(size_t)q * 224 + kt * 16 + lr] = f2bf(c[kt][r] * sr_[r]);
      pb[(size_t)q * 224 + 208 + lr] = 0;  // pad cols 208..223
    }
  }
}

// o[b][q][h*64+d] = sum_k P[bh][q][k](bf16) * V[b][k][h][d]
// V staged in LDS via coalesced global_load_lds (rows >=197 clamped to 196;
// their P is 0, values finite). Old version: 56 scalar u16 gathers/thread
// at 4.6KB stride = one cache line touched per element.
__global__ __launch_bounds__(256) void pv_k(const u16* __restrict__ qkv,
                                            const u16* __restrict__ P,
                                            u16* __restrict__ o) {
  __shared__ __align__(16) u16 Vs[224 * 64];  // 28 KB
  const int bh = blockIdx.x;
  const int b = bh / 12, hh = bh - b * 12;
  const int tid = threadIdx.x;
  const int lane = tid & 63, ct = tid >> 6;  // wave = 16-col tile of HD
  const int lg = lane >> 4, lr = lane & 15;
  const u16* vhead = qkv + (size_t)b * 197 * 2304 + 1536 + hh * 64;
  // stage V rows 0..223 (16B chunks; chunk c -> row c>>3, col-chunk c&7)
#pragma unroll
  for (int it = 0; it < 7; ++it) {
    const int c0 = it * 256 + ct * 64;  // wave-uniform chunk base
    const int c = c0 + lane;
    int row = c >> 3;
    if (row > 196) row = 196;
    glds16(vhead + (size_t)row * 2304 + (c & 7) * 8, &Vs[c0 * 8]);
  }
  __syncthreads();
  short8 vf[7];
#pragma unroll
  for (int ks = 0; ks < 7; ++ks) {
    ushort8 t;
#pragma unroll
    for (int j = 0; j < 8; ++j) {
      int kk = ks * 32 + lg * 8 + j;
      t[j] = Vs[kk * 64 + ct * 16 + lr];
    }
    vf[ks] = __builtin_bit_cast(short8, t);
  }
  const u16* pbase = P + (size_t)bh * 197 * 224;
  u16* ob = o + (size_t)b * 197 * 768 + hh * 64 + ct * 16;
  for (int qt = 0; qt < 13; ++qt) {
    int q = qt * 16 + lr;
    if (q > 196) q = 196;
    const u16* pp = pbase + (size_t)q * 224 + lg * 8;
    f32x4 acc = {0.f, 0.f, 0.f, 0.f};
#pragma unroll
    for (int ks = 0; ks < 7; ++ks) {
      short8 af = *(const short8*)(pp + ks * 32);
      acc = __builtin_amdgcn_mfma_f32_16x16x32_bf16(af, vf[ks], acc, 0, 0, 0);
    }
#pragma unroll
    for (int r = 0; r < 4; ++r) {
      int qq = qt * 16 + lg * 4 + r;
      if (qq < 197) ob[(size_t)qq * 768 + lr] = f2bf(acc[r]);
    }
  }
}

// ---------------- layernorm: 4 rows/block, 64 lanes/row, float4 ----------
__global__ __launch_bounds__(256) void ln_k(const float* __restrict__ x,
                                            const float* __restrict__ w,
                                            const float* __restrict__ bb,
                                            u16* __restrict__ y) {
  const int lane = threadIdx.x & 63, wv = threadIdx.x >> 6;
  const int r = blockIdx.x * 4 + wv;
  const float* xr = x + (size_t)r * 768;
  float4 v[3];
  float s = 0.f, q = 0.f;
#pragma unroll
  for (int i = 0; i < 3; ++i) {
    v[i] = *(const float4*)(xr + i * 256 + lane * 4);
    s += v[i].x + v[i].y + v[i].z + v[i].w;
    q += v[i].x * v[i].x + v[i].y * v[i].y + v[i].z * v[i].z +
         v[i].w * v[i].w;
  }
  s = wred_sum(s);
  q = wred_sum(q);
  float mu = s * (1.f / 768.f);
  float var = q * (1.f / 768.f) - mu * mu;
  float rs = rsqrtf(var + 1e-5f);
  u16* yr = y + (size_t)r * 768;
#pragma unroll
  for (int i = 0; i < 3; ++i) {
    float4 wv4 = *(const float4*)(w + i * 256 + lane * 4);
    float4 bv4 = *(const float4*)(bb + i * 256 + lane * 4);
    ushort4 o;
    o.x = f2bf((v[i].x - mu) * rs * wv4.x + bv4.x);
    o.y = f2bf((v[i].y - mu) * rs * wv4.y + bv4.y);
    o.z = f2bf((v[i].z - mu) * rs * wv4.z + bv4.z);
    o.w = f2bf((v[i].w - mu) * rs * wv4.w + bv4.w);
    *(ushort4*)(yr + i * 256 + lane * 4) = o;
  }
}

// ---------------- final LN(cls row) + head ----------------
__global__ __launch_bounds__(256) void head_k(
    const float* __restrict__ h, const float* __restrict__ lnw,
    const float* __restrict__ lnb, const float* __restrict__ hw,
    const float* __restrict__ hb, float* __restrict__ out) {
  const int b = blockIdx.x, tid = threadIdx.x;
  const float* xr = h + (size_t)b * 197 * 768;
  float v0 = xr[tid], v1 = xr[tid + 256], v2 = xr[tid + 512];
  float s = v0 + v1 + v2;
  float q = v0 * v0 + v1 * v1 + v2 * v2;
  s = wred_sum(s);
  q = wred_sum(q);
  __shared__ float ss[4], qs[4];
  int lane = tid & 63, wid = tid >> 6;
  if (lane == 0) { ss[wid] = s; qs[wid] = q; }
  __syncthreads();
  float S = ss[0] + ss[1] + ss[2] + ss[3];
  float Q = qs[0] + qs[1] + qs[2] + qs[3];
  float mu = S * (1.f / 768.f);
  float var = Q * (1.f / 768.f) - mu * mu;
  float rs = rsqrtf(var + 1e-5f);
  __shared__ float yb[768];
  yb[tid] = (v0 - mu) * rs * lnw[tid] + lnb[tid];
  yb[tid + 256] = (v1 - mu) * rs * lnw[tid + 256] + lnb[tid + 256];
  yb[tid + 512] = (v2 - mu) * rs * lnw[tid + 512] + lnb[tid + 512];
  __syncthreads();
  float p[10] = {};
  for (int e = tid; e < 768; e += 256) {
    float yv = yb[e];
#pragma unroll
    for (int n = 0; n < 10; ++n) p[n] += yv * hw[(size_t)e * 10 + n];
  }
#pragma unroll
  for (int n = 0; n < 10; ++n) p[n] = wred_sum(p[n]);
  __shared__ float red[4][10];
  if (lane == 0)
#pragma unroll
    for (int n = 0; n < 10; ++n) red[wid][n] = p[n];
  __syncthreads();
  if (tid < 10)
    out[b * 10 + tid] =
        red[0][tid] + red[1][tid] + red[2][tid] + red[3][tid] + hb[tid];
}

// ---------------- host orchestration ----------------
extern "C" void kernel_launch(void* const* d_in, const int* in_sizes, int n_in,
                              void* d_out, int out_size, void* d_ws,
                              size_t ws_size, hipStream_t stream) {
  const float* x = (const float*)d_in[0];
  const float* conv_w = (const float*)d_in[1];
  const float* conv_b = (const float*)d_in[2];
  const float* cls = (const float*)d_in[3];
  const float* pos = (const float*)d_in[4];
  const float* ln1w = (const float*)d_in[5];
  const float* ln1b = (const float*)d_in[6];
  const float* qkvw = (const float*)d_in[7];
  const float* qkvbias = (const float*)d_in[8];
  const float* projw = (const float*)d_in[9];
  const float* projb = (const float*)d_in[10];
  const float* ln2w = (const float*)d_in[11];
  const float* ln2b = (const float*)d_in[12];
  const float* w1f = (const float*)d_in[13];
  const float* b1 = (const float*)d_in[14];
  const float* w2f = (const float*)d_in[15];
  const float* b2 = (const float*)d_in[16];
  const float* lnfw = (const float*)d_in[17];
  const float* lnfb = (const float*)d_in[18];
  const float* headw = (const float*)d_in[19];
  const float* headb = (const float*)d_in[20];
  float* out = (float*)d_out;

  // workspace layout; A-side buffers padded to 6400 rows (tiles read past
  // M=6304; garbage rows are finite, never reach guarded outputs)
  char* p = (char*)d_ws;
  auto take = [&](size_t bytes) {
    char* q = p;
    p += (bytes + 255) & ~(size_t)255;
    return q;
  };
  u16* wq = (u16*)take(12ull * 768 * 2304 * 2);   // [N=2304][K=768] per layer
  u16* wpj = (u16*)take(12ull * 768 * 768 * 2);   // [768][768]
  u16* w1 = (u16*)take(12ull * 768 * 3072 * 2);   // [3072][768]
  u16* w2 = (u16*)take(12ull * 3072 * 768 * 2);   // [768][3072]
  u16* wc = (u16*)take(768ull * 768 * 2);         // conv_w already [N][K]
  float* h = (float*)take(6304ull * 768 * 4);
  u16* y = (u16*)take(6400ull * 768 * 2);
  u16* qkv = (u16*)take(6400ull * 2304 * 2);
  u16* ob = (u16*)take(6400ull * 768 * 2);
  u16* mlpb = (u16*)take(6400ull * 3072 * 2);  // also holds patches at start
  u16* P = (u16*)take(384ull * 197 * 224 * 2);
  float* skP = (float*)take(2ull * 6304 * 768 * 4);  // dedicated (no alias:
  // redln writes y while reading skP; aliasing them would race cross-block)
  (void)ws_size; (void)in_sizes; (void)n_in; (void)out_size;

  // weight conversion fp32 -> bf16, transposed to [N][K]
  tpose_k<<<dim3(72, 24, 12), 256, 0, stream>>>(qkvw, wq, 768, 2304);
  tpose_k<<<dim3(24, 24, 12), 256, 0, stream>>>(projw, wpj, 768, 768);
  tpose_k<<<dim3(96, 24, 12), 256, 0, stream>>>(w1f, w1, 768, 3072);
  tpose_k<<<dim3(24, 96, 12), 256, 0, stream>>>(w2f, w2, 3072, 768);
  cvt4_k<<<576, 256, 0, stream>>>(conv_w, wc, 768 * 768 / 4);

  // patch embed
  patch_k<<<6272 * 768 / 256, 256, 0, stream>>>(x, mlpb);
  gemmP<3, 64><<<dim3(6, 98), 256, 0, stream>>>(mlpb, 768, wc, 768, conv_b,
                                                nullptr, 0, h, pos, 6272, 768,
                                                768);
  clspos_k<<<32 * 768 / 256, 256, 0, stream>>>(cls, pos, h);

  // layer 0's ln1 standalone; thereafter fused into redln
  ln_k<<<1576, 256, 0, stream>>>(h, ln1w, ln1b, y);
  for (int i = 0; i < 12; ++i) {
    gemmK64<0><<<dim3(18, 50), 512, 0, stream>>>(
        y, 768, wq + (size_t)i * 768 * 2304, 768, qkvbias + i * 2304, qkv,
        2304, nullptr, nullptr, 6304, 2304, 768);
    qksm_k<<<dim3(384, 13), 64, 0, stream>>>(qkv, P);
    pv_k<<<384, 256, 0, stream>>>(qkv, P, ob);
    gemmP<2, 64><<<dim3(6, 99), 256, 0, stream>>>(
        ob, 768, wpj + (size_t)i * 768 * 768, 768, projb + i * 768, nullptr,
        768, h, nullptr, 6304, 768, 768);
    ln_k<<<1576, 256, 0, stream>>>(h, ln2w + i * 768, ln2b + i * 768, y);
    gemmK64<1><<<dim3(24, 50), 512, 0, stream>>>(
        y, 768, w1 + (size_t)i * 768 * 3072, 768, b1 + i * 3072, mlpb, 3072,
        nullptr, nullptr, 6304, 3072, 768);
    gemmSK<<<dim3(6, 50, 2), 512, 0, stream>>>(
        mlpb, 3072, w2 + (size_t)i * 3072 * 768, 3072, skP, 6304, 1536);
    if (i < 11) {
      redln_k<<<1576, 256, 0, stream>>>(skP, b2 + i * 768, h,
                                        ln1w + (i + 1) * 768,
                                        ln1b + (i + 1) * 768, y);
    } else {
      redK<<<4728, 256, 0, stream>>>(skP, b2 + i * 768, h);
    }
  }

  head_k<<<32, 256, 0, stream>>>(h, lnfw, lnfb, headw, headb, out);
}

// Round 14
// 3088.592 us; speedup vs baseline: 1.1514x; 1.0050x over previous
//
#include <hip/hip_runtime.h>

// ViT-B/16 forward, B=32, S=197, E=768, H=12, HD=64, MLP=3072, DEPTH=12.
// Round 14: GEMMs are staging-traffic-bound at ~7 TB/s (461MB/68us for
// gemmSK; sum over GEMMs reproduces per-layer time). Cut traffic with
// BN=256 tiles at BK=32 (48KB LDS -> 3 blocks/CU, unlike R12's 96KB):
// gemmW2 = 128x256, BK=32, 8 waves, 2-phase loop. qkv/mlp1 direct; mlp2
// split-K x3 (KC=1024, 450 blocks, 3 fp32 planes). proj/patch keep gemmP.

typedef __attribute__((ext_vector_type(8))) short short8;
typedef __attribute__((ext_vector_type(8))) unsigned short ushort8;
typedef __attribute__((ext_vector_type(4))) float f32x4;
typedef unsigned short u16;

#define DEV __device__ __forceinline__

DEV u16 f2bf(float f) {
  unsigned int u = __builtin_bit_cast(unsigned int, f);
  u += 0x7fffu + ((u >> 16) & 1u);
  return (u16)(u >> 16);
}
DEV float wred_sum(float v) {
  for (int o = 32; o; o >>= 1) v += __shfl_xor(v, o, 64);
  return v;
}
DEV void glds16(const void* gp, void* lp) {
  __builtin_amdgcn_global_load_lds(
      (const __attribute__((address_space(1))) void*)gp,
      (__attribute__((address_space(3))) void*)lp, 16, 0, 0);
}
// m204 bijective XCD swizzle: contiguous wg chunk per XCD
DEV int xcd_swz(int flat, int nwg) {
  int q = nwg >> 3, r = nwg & 7;
  int x = flat & 7, o = flat >> 3;
  return (x < r ? x * (q + 1) : r * (q + 1) + (x - r) * q) + o;
}

// ---------------- weight conversion ----------------
__global__ __launch_bounds__(256) void cvt4_k(const float* __restrict__ s,
                                              u16* __restrict__ d, long n4) {
  long i = (long)blockIdx.x * 256 + threadIdx.x;
  if (i >= n4) return;
  float4 v = ((const float4*)s)[i];
  ushort4 o;
  o.x = f2bf(v.x); o.y = f2bf(v.y); o.z = f2bf(v.z); o.w = f2bf(v.w);
  ((ushort4*)d)[i] = o;
}

// fp32 [K][N] (blockIdx.z selects layer) -> bf16 [N][K], tiled 32x32
__global__ __launch_bounds__(256) void tpose_k(const float* __restrict__ s,
                                               u16* __restrict__ d, int K,
                                               int N) {
  __shared__ float t[32][33];
  const int bx = blockIdx.x;  // n tile
  const int by = blockIdx.y;  // k tile
  const size_t base = (size_t)blockIdx.z * K * N;
  const int c = threadIdx.x & 31, r0 = threadIdx.x >> 5;
#pragma unroll
  for (int i = 0; i < 4; ++i) {
    int r = r0 + i * 8;
    t[r][c] = s[base + (size_t)(by * 32 + r) * N + bx * 32 + c];
  }
  __syncthreads();
#pragma unroll
  for (int i = 0; i < 4; ++i) {
    int r = r0 + i * 8;
    d[base + (size_t)(bx * 32 + r) * K + by * 32 + c] = f2bf(t[c][r]);
  }
}

// patches[b][p][d] <- x[b][c][gy*16+py][gx*16+px], bf16
__global__ __launch_bounds__(256) void patch_k(const float* __restrict__ x,
                                               u16* __restrict__ pt) {
  int i = blockIdx.x * 256 + threadIdx.x;  // 6272*768 exactly
  int d = i % 768;
  int bp = i / 768;
  int p = bp % 196, b = bp / 196;
  int c = d >> 8, pd = d & 255;
  int py = pd >> 4, px = pd & 15;
  int gy = p / 14, gx = p - gy * 14;
  size_t src = ((size_t)(b * 3 + c) * 224 + gy * 16 + py) * 224 + gx * 16 + px;
  pt[i] = f2bf(x[src]);
}

// h[b][0][:] = cls + pos[0]
__global__ __launch_bounds__(256) void clspos_k(const float* __restrict__ cls,
                                                const float* __restrict__ pos,
                                                float* __restrict__ h) {
  int i = blockIdx.x * 256 + threadIdx.x;  // 32*768
  int b = i / 768, e = i - b * 768;
  h[(size_t)b * 197 * 768 + e] = cls[e] + pos[e];
}

// ---------------- epilogue helper ----------------
template <int EPI>
DEV void epi_store(float v, int grow, int gcol, u16* outb, int ldo,
                   float* outf, const float* pos) {
  if constexpr (EPI == 0) {
    outb[(size_t)grow * ldo + gcol] = f2bf(v);
  } else if constexpr (EPI == 1) {
    // gelu(x) ~= x * sigmoid(1.5957691(x + 0.044715 x^3))
    float u = __expf(-1.5957691216f * (v + 0.044715f * v * v * v));
    outb[(size_t)grow * ldo + gcol] = f2bf(v / (1.f + u));
  } else if constexpr (EPI == 2) {
    outf[(size_t)grow * ldo + gcol] += v;
  } else {
    int b = grow / 196, p = grow - b * 196;
    outf[(size_t)(grow + b + 1) * 768 + gcol] =
        v + pos[(size_t)(p + 1) * 768 + gcol];
  }
}

// -------- gemmW2: C[M,N] = A[M,K] @ Bt[N,K], 128(M) x 256(N), BK=32 -------
// 8 waves (2m x 4n, wave tile 64x64), 2-phase double-buffer, 48KB LDS ->
// 3 blocks/CU. Staging/read swizzle identical math to gemmP (verified).
// EPI 4: split-K raw fp32 partial -> outf plane blockIdx.z; K = per-chunk KC.
template <int EPI>
__global__ __launch_bounds__(512) void gemmW2(
    const u16* __restrict__ A, int lda, const u16* __restrict__ Bt, int ldb,
    const float* __restrict__ bias, u16* __restrict__ outb, int ldo,
    float* __restrict__ outf, int M, int K) {
  __shared__ __align__(16) u16 Ak[2][128 * 32];  // 16 KB
  __shared__ __align__(16) u16 Bk[2][256 * 32];  // 32 KB
  const int tid = threadIdx.x;
  const int lane = tid & 63, wid = tid >> 6;
  const int wm = wid >> 2, wn = wid & 3;
  const int lg = lane >> 4, lr = lane & 15;
  const int nwg = gridDim.x * gridDim.y;
  const int wg = xcd_swz(blockIdx.y * gridDim.x + blockIdx.x, nwg);
  const int tn = wg % gridDim.x, tm = wg / gridDim.x;
  const size_t koff = (EPI == 4) ? (size_t)blockIdx.z * K : 0;

  // staging: lane covers row sr (16 rows/glds16), chunk (lane&3)^((lane>>3)&3)
  const int sr = lane >> 2;
  const int sc4 = (((lane & 3) ^ ((lane >> 3) & 3)) << 3);
  const u16* aSrc = A + (size_t)(tm * 128 + wid * 16 + sr) * lda + koff + sc4;
  const u16* bSrc = Bt + (size_t)(tn * 256 + wid * 32 + sr) * ldb + koff + sc4;
  const size_t bRow16 = (size_t)16 * ldb;

  auto stage = [&](int buf, int kt) {  // 3 glds16/wave
    const u16* ak = aSrc + kt * 32;
    const u16* bk = bSrc + kt * 32;
    glds16(ak, &Ak[buf][wid * 16 * 32]);
    u16* bd = &Bk[buf][wid * 32 * 32];
    glds16(bk, bd);
    glds16(bk + bRow16, bd + 512);
  };

  const int rp = (lg ^ ((lr >> 1) & 3)) << 3;  // read-side un-swizzle
  f32x4 acc[4][4] = {};
  auto compute = [&](int buf) {
    short8 af[4], bf[4];
#pragma unroll
    for (int i = 0; i < 4; ++i)
      af[i] = *(const short8*)(&Ak[buf][(wm * 64 + i * 16 + lr) * 32 + rp]);
#pragma unroll
    for (int i = 0; i < 4; ++i)
      bf[i] = *(const short8*)(&Bk[buf][(wn * 64 + i * 16 + lr) * 32 + rp]);
#pragma unroll
    for (int mi = 0; mi < 4; ++mi)
#pragma unroll
      for (int ni = 0; ni < 4; ++ni)
        acc[mi][ni] = __builtin_amdgcn_mfma_f32_16x16x32_bf16(
            af[mi], bf[ni], acc[mi][ni], 0, 0, 0);
  };

  const int nk = K >> 5;
  int cur = 0;
  stage(0, 0);
  __syncthreads();
  for (int kt = 0; kt < nk - 1; ++kt) {
    stage(cur ^ 1, kt + 1);  // next K-tile in flight under compute
    compute(cur);
    __syncthreads();
    cur ^= 1;
  }
  compute(cur);

#pragma unroll
  for (int mi = 0; mi < 4; ++mi)
#pragma unroll
    for (int ni = 0; ni < 4; ++ni)
#pragma unroll
      for (int r = 0; r < 4; ++r) {
        int grow = tm * 128 + wm * 64 + mi * 16 + lg * 4 + r;
        int gcol = tn * 256 + wn * 64 + ni * 16 + lr;
        if (grow < M) {
          if constexpr (EPI == 4) {
            outf[(size_t)blockIdx.z * M * ldo + (size_t)grow * ldo + gcol] =
                acc[mi][ni][r];
          } else {
            epi_store<EPI>(acc[mi][ni][r] + bias[gcol], grow, gcol, outb, ldo,
                           outf, nullptr);
          }
        }
      }
}

// redK: h += bias + Cp[0..2]  (last-layer reduce, float4)
__global__ __launch_bounds__(256) void redK(const float* __restrict__ Cp,
                                            const float* __restrict__ bias,
                                            float* __restrict__ h) {
  size_t i = ((size_t)blockIdx.x * 256 + threadIdx.x) * 4;  // < 6304*768
  float4 p0 = *(const float4*)(Cp + i);
  float4 p1 = *(const float4*)(Cp + 6304ull * 768 + i);
  float4 p2 = *(const float4*)(Cp + 2ull * 6304 * 768 + i);
  float4 hv = *(const float4*)(h + i);
  float4 bv = *(const float4*)(bias + (int)(i % 768));
  hv.x += p0.x + p1.x + p2.x + bv.x;
  hv.y += p0.y + p1.y + p2.y + bv.y;
  hv.z += p0.z + p1.z + p2.z + bv.z;
  hv.w += p0.w + p1.w + p2.w + bv.w;
  *(float4*)(h + i) = hv;
}

// redln: h' = h + bias + Cp[0..2]; h = h'; y = ln(h', w, b) bf16.
__global__ __launch_bounds__(256) void redln_k(
    const float* __restrict__ Cp, const float* __restrict__ bias,
    float* __restrict__ h, const float* __restrict__ lnw,
    const float* __restrict__ lnb, u16* __restrict__ y) {
  const int lane = threadIdx.x & 63, wv = threadIdx.x >> 6;
  const int r = blockIdx.x * 4 + wv;
  const size_t base = (size_t)r * 768;
  float4 a[3];
  float s = 0.f, q = 0.f;
#pragma unroll
  for (int i = 0; i < 3; ++i) {
    const int off = i * 256 + lane * 4;
    float4 hv = *(const float4*)(h + base + off);
    float4 p0 = *(const float4*)(Cp + base + off);
    float4 p1 = *(const float4*)(Cp + 6304ull * 768 + base + off);
    float4 p2 = *(const float4*)(Cp + 2ull * 6304 * 768 + base + off);
    float4 bv = *(const float4*)(bias + off);
    a[i].x = hv.x + p0.x + p1.x + p2.x + bv.x;
    a[i].y = hv.y + p0.y + p1.y + p2.y + bv.y;
    a[i].z = hv.z + p0.z + p1.z + p2.z + bv.z;
    a[i].w = hv.w + p0.w + p1.w + p2.w + bv.w;
    s += a[i].x + a[i].y + a[i].z + a[i].w;
    q += a[i].x * a[i].x + a[i].y * a[i].y + a[i].z * a[i].z +
         a[i].w * a[i].w;
  }
  s = wred_sum(s);
  q = wred_sum(q);
  float mu = s * (1.f / 768.f);
  float var = q * (1.f / 768.f) - mu * mu;
  float rs = rsqrtf(var + 1e-5f);
#pragma unroll
  for (int i = 0; i < 3; ++i) {
    const int off = i * 256 + lane * 4;
    *(float4*)(h + base + off) = a[i];
    float4 wv4 = *(const float4*)(lnw + off);
    float4 bv4 = *(const float4*)(lnb + off);
    ushort4 o;
    o.x = f2bf((a[i].x - mu) * rs * wv4.x + bv4.x);
    o.y = f2bf((a[i].y - mu) * rs * wv4.y + bv4.y);
    o.z = f2bf((a[i].z - mu) * rs * wv4.z + bv4.z);
    o.w = f2bf((a[i].w - mu) * rs * wv4.w + bv4.w);
    *(ushort4*)(y + base + off) = o;
  }
}

// -------- gemmP: BMx128 tile, BK=32, 4 waves, 2-phase (patch + proj) ------
template <int EPI, int BM>
__global__ __launch_bounds__(256) void gemmP(
    const u16* __restrict__ A, int lda, const u16* __restrict__ Bt, int ldb,
    const float* __restrict__ bias, u16* __restrict__ outb, int ldo,
    float* __restrict__ outf, const float* __restrict__ pos, int M, int N,
    int K) {
  constexpr int MI = BM / 32;  // acc rows per wave (2 or 4)
  __shared__ __align__(16) u16 Ak[2][BM * 32];
  __shared__ __align__(16) u16 Bk[2][128 * 32];
  const int tid = threadIdx.x;
  const int lane = tid & 63, wid = tid >> 6;
  const int wm = wid >> 1, wn = wid & 1;
  const int lg = lane >> 4, lr = lane & 15;
  const int nwg = gridDim.x * gridDim.y;
  const int wg = xcd_swz(blockIdx.y * gridDim.x + blockIdx.x, nwg);
  const int tn = wg % gridDim.x, tm = wg / gridDim.x;

  const int sr = lane >> 2;
  const int sc4 = (((lane & 3) ^ ((lane >> 3) & 3)) << 3);
  const u16* aSrc = A + (size_t)(tm * BM + wid * (BM / 4) + sr) * lda + sc4;
  const u16* bSrc = Bt + (size_t)(tn * 128 + wid * 32 + sr) * ldb + sc4;
  const size_t aRow16 = (size_t)16 * lda, bRow16 = (size_t)16 * ldb;

  auto stage = [&](int buf, int kt) {
    const u16* ak = aSrc + kt * 32;
    const u16* bk = bSrc + kt * 32;
    u16* ad = &Ak[buf][wid * (BM / 4) * 32];
    u16* bd = &Bk[buf][wid * 1024];
    glds16(ak, ad);
    if constexpr (BM == 128) glds16(ak + aRow16, ad + 512);
    glds16(bk, bd);
    glds16(bk + bRow16, bd + 512);
  };

  const int rp = (lg ^ ((lr >> 1) & 3)) << 3;
  f32x4 acc[MI][4] = {};
  auto compute = [&](int buf) {
    short8 af[MI], bfr[4];
#pragma unroll
    for (int i = 0; i < MI; ++i)
      af[i] =
          *(const short8*)(&Ak[buf][(wm * (BM / 2) + i * 16 + lr) * 32 + rp]);
#pragma unroll
    for (int i = 0; i < 4; ++i)
      bfr[i] = *(const short8*)(&Bk[buf][(wn * 64 + i * 16 + lr) * 32 + rp]);
#pragma unroll
    for (int mi = 0; mi < MI; ++mi)
#pragma unroll
      for (int ni = 0; ni < 4; ++ni)
        acc[mi][ni] = __builtin_amdgcn_mfma_f32_16x16x32_bf16(
            af[mi], bfr[ni], acc[mi][ni], 0, 0, 0);
  };

  const int nk = K >> 5;
  int cur = 0;
  stage(0, 0);
  __syncthreads();
  for (int kt = 0; kt < nk - 1; ++kt) {
    stage(cur ^ 1, kt + 1);
    compute(cur);
    __syncthreads();
    cur ^= 1;
  }
  compute(cur);

#pragma unroll
  for (int mi = 0; mi < MI; ++mi)
#pragma unroll
    for (int ni = 0; ni < 4; ++ni)
#pragma unroll
      for (int r = 0; r < 4; ++r) {
        int grow = tm * BM + wm * (BM / 2) + mi * 16 + lg * 4 + r;
        int gcol = tn * 128 + wn * 64 + ni * 16 + lr;
        if (grow < M)
          epi_store<EPI>(acc[mi][ni][r] + bias[gcol], grow, gcol, outb, ldo,
                         outf, pos);
      }
}

// ---------------- attention ----------------
// fused QK^T + softmax: P[bh][q][k] bf16, row stride 224, cols 197..223 = 0.
__global__ __launch_bounds__(64) void qksm_k(const u16* __restrict__ qkv,
                                             u16* __restrict__ P) {
  const int bh = blockIdx.x;  // b*12+h
  const int qt = blockIdx.y;  // 0..12
  const int lane = threadIdx.x;
  const int lg = lane >> 4, lr = lane & 15;
  const int b = bh / 12, hh = bh - b * 12;
  const u16* base = qkv + (size_t)b * 197 * 2304 + hh * 64;
  int qrow = qt * 16 + lr;
  if (qrow > 196) qrow = 196;
  const u16* qp = base + (size_t)qrow * 2304 + lg * 8;
  short8 a0 = *(const short8*)(qp);
  short8 a1 = *(const short8*)(qp + 32);
  f32x4 c[13];
  const bool kval[2] = {true, (12 * 16 + lr) <= 196};
#pragma unroll
  for (int kt = 0; kt < 13; ++kt) {
    int krow = kt * 16 + lr;
    if (krow > 196) krow = 196;
    const u16* kp = base + 768 + (size_t)krow * 2304 + lg * 8;
    short8 b0 = *(const short8*)(kp);
    short8 b1 = *(const short8*)(kp + 32);
    f32x4 t = {0.f, 0.f, 0.f, 0.f};
    t = __builtin_amdgcn_mfma_f32_16x16x32_bf16(a0, b0, t, 0, 0, 0);
    c[kt] = __builtin_amdgcn_mfma_f32_16x16x32_bf16(a1, b1, t, 0, 0, 0);
  }
  float mr[4], sr_[4];
#pragma unroll
  for (int r = 0; r < 4; ++r) {
    float mm = -3.4e38f;
#pragma unroll
    for (int kt = 0; kt < 13; ++kt)
      if (kval[kt == 12]) mm = fmaxf(mm, c[kt][r] * 0.125f);
#pragma unroll
    for (int o = 1; o < 16; o <<= 1) mm = fmaxf(mm, __shfl_xor(mm, o, 64));
    mr[r] = mm;
  }
#pragma unroll
  for (int r = 0; r < 4; ++r) {
    float s = 0.f;
#pragma unroll
    for (int kt = 0; kt < 13; ++kt) {
      float e = kval[kt == 12] ? __expf(c[kt][r] * 0.125f - mr[r]) : 0.f;
      c[kt][r] = e;
      s += e;
    }
#pragma unroll
    for (int o = 1; o < 16; o <<= 1) s += __shfl_xor(s, o, 64);
    sr_[r] = 1.0f / s;
  }
  u16* pb = P + (size_t)bh * 197 * 224;
#pragma unroll
  for (int r = 0; r < 4; ++r) {
    int q = qt * 16 + lg * 4 + r;
    if (q < 197) {
#pragma unroll
      for (int kt = 0; kt < 13; ++kt)
        pb[(size_t)q * 224 + kt * 16 + lr] = f2bf(c[kt][r] * sr_[r]);
      pb[(size_t)q * 224 + 208 + lr] = 0;  // pad cols 208..223
    }
  }
}

// o[b][q][h*64+d] = sum_k P[bh][q][k](bf16) * V[b][k][h][d]; V via LDS
__global__ __launch_bounds__(256) void pv_k(const u16* __restrict__ qkv,
                                            const u16* __restrict__ P,
                                            u16* __restrict__ o) {
  __shared__ __align__(16) u16 Vs[224 * 64];  // 28 KB
  const int bh = blockIdx.x;
  const int b = bh / 12, hh = bh - b * 12;
  const int tid = threadIdx.x;
  const int lane = tid & 63, ct = tid >> 6;  // wave = 16-col tile of HD
  const int lg = lane >> 4, lr = lane & 15;
  const u16* vhead = qkv + (size_t)b * 197 * 2304 + 1536 + hh * 64;
#pragma unroll
  for (int it = 0; it < 7; ++it) {
    const int c0 = it * 256 + ct * 64;  // wave-uniform chunk base
    const int c = c0 + lane;
    int row = c >> 3;
    if (row > 196) row = 196;
    glds16(vhead + (size_t)row * 2304 + (c & 7) * 8, &Vs[c0 * 8]);
  }
  __syncthreads();
  short8 vf[7];
#pragma unroll
  for (int ks = 0; ks < 7; ++ks) {
    ushort8 t;
#pragma unroll
    for (int j = 0; j < 8; ++j) {
      int kk = ks * 32 + lg * 8 + j;
      t[j] = Vs[kk * 64 + ct * 16 + lr];
    }
    vf[ks] = __builtin_bit_cast(short8, t);
  }
  const u16* pbase = P + (size_t)bh * 197 * 224;
  u16* ob = o + (size_t)b * 197 * 768 + hh * 64 + ct * 16;
  for (int qt = 0; qt < 13; ++qt) {
    int q = qt * 16 + lr;
    if (q > 196) q = 196;
    const u16* pp = pbase + (size_t)q * 224 + lg * 8;
    f32x4 acc = {0.f, 0.f, 0.f, 0.f};
#pragma unroll
    for (int ks = 0; ks < 7; ++ks) {
      short8 af = *(const short8*)(pp + ks * 32);
      acc = __builtin_amdgcn_mfma_f32_16x16x32_bf16(af, vf[ks], acc, 0, 0, 0);
    }
#pragma unroll
    for (int r = 0; r < 4; ++r) {
      int qq = qt * 16 + lg * 4 + r;
      if (qq < 197) ob[(size_t)qq * 768 + lr] = f2bf(acc[r]);
    }
  }
}

// ---------------- layernorm: 4 rows/block, 64 lanes/row, float4 ----------
__global__ __launch_bounds__(256) void ln_k(const float* __restrict__ x,
                                            const float* __restrict__ w,
                                            const float* __restrict__ bb,
                                            u16* __restrict__ y) {
  const int lane = threadIdx.x & 63, wv = threadIdx.x >> 6;
  const int r = blockIdx.x * 4 + wv;
  const float* xr = x + (size_t)r * 768;
  float4 v[3];
  float s = 0.f, q = 0.f;
#pragma unroll
  for (int i = 0; i < 3; ++i) {
    v[i] = *(const float4*)(xr + i * 256 + lane * 4);
    s += v[i].x + v[i].y + v[i].z + v[i].w;
    q += v[i].x * v[i].x + v[i].y * v[i].y + v[i].z * v[i].z +
         v[i].w * v[i].w;
  }
  s = wred_sum(s);
  q = wred_sum(q);
  float mu = s * (1.f / 768.f);
  float var = q * (1.f / 768.f) - mu * mu;
  float rs = rsqrtf(var + 1e-5f);
  u16* yr = y + (size_t)r * 768;
#pragma unroll
  for (int i = 0; i < 3; ++i) {
    float4 wv4 = *(const float4*)(w + i * 256 + lane * 4);
    float4 bv4 = *(const float4*)(bb + i * 256 + lane * 4);
    ushort4 o;
    o.x = f2bf((v[i].x - mu) * rs * wv4.x + bv4.x);
    o.y = f2bf((v[i].y - mu) * rs * wv4.y + bv4.y);
    o.z = f2bf((v[i].z - mu) * rs * wv4.z + bv4.z);
    o.w = f2bf((v[i].w - mu) * rs * wv4.w + bv4.w);
    *(ushort4*)(yr + i * 256 + lane * 4) = o;
  }
}

// ---------------- final LN(cls row) + head ----------------
__global__ __launch_bounds__(256) void head_k(
    const float* __restrict__ h, const float* __restrict__ lnw,
    const float* __restrict__ lnb, const float* __restrict__ hw,
    const float* __restrict__ hb, float* __restrict__ out) {
  const int b = blockIdx.x, tid = threadIdx.x;
  const float* xr = h + (size_t)b * 197 * 768;
  float v0 = xr[tid], v1 = xr[tid + 256], v2 = xr[tid + 512];
  float s = v0 + v1 + v2;
  float q = v0 * v0 + v1 * v1 + v2 * v2;
  s = wred_sum(s);
  q = wred_sum(q);
  __shared__ float ss[4], qs[4];
  int lane = tid & 63, wid = tid >> 6;
  if (lane == 0) { ss[wid] = s; qs[wid] = q; }
  __syncthreads();
  float S = ss[0] + ss[1] + ss[2] + ss[3];
  float Q = qs[0] + qs[1] + qs[2] + qs[3];
  float mu = S * (1.f / 768.f);
  float var = Q * (1.f / 768.f) - mu * mu;
  float rs = rsqrtf(var + 1e-5f);
  __shared__ float yb[768];
  yb[tid] = (v0 - mu) * rs * lnw[tid] + lnb[tid];
  yb[tid + 256] = (v1 - mu) * rs * lnw[tid + 256] + lnb[tid + 256];
  yb[tid + 512] = (v2 - mu) * rs * lnw[tid + 512] + lnb[tid + 512];
  __syncthreads();
  float p[10] = {};
  for (int e = tid; e < 768; e += 256) {
    float yv = yb[e];
#pragma unroll
    for (int n = 0; n < 10; ++n) p[n] += yv * hw[(size_t)e * 10 + n];
  }
#pragma unroll
  for (int n = 0; n < 10; ++n) p[n] = wred_sum(p[n]);
  __shared__ float red[4][10];
  if (lane == 0)
#pragma unroll
    for (int n = 0; n < 10; ++n) red[wid][n] = p[n];
  __syncthreads();
  if (tid < 10)
    out[b * 10 + tid] =
        red[0][tid] + red[1][tid] + red[2][tid] + red[3][tid] + hb[tid];
}

// ---------------- host orchestration ----------------
extern "C" void kernel_launch(void* const* d_in, const int* in_sizes, int n_in,
                              void* d_out, int out_size, void* d_ws,
                              size_t ws_size, hipStream_t stream) {
  const float* x = (const float*)d_in[0];
  const float* conv_w = (const float*)d_in[1];
  const float* conv_b = (const float*)d_in[2];
  const float* cls = (const float*)d_in[3];
  const float* pos = (const float*)d_in[4];
  const float* ln1w = (const float*)d_in[5];
  const float* ln1b = (const float*)d_in[6];
  const float* qkvw = (const float*)d_in[7];
  const float* qkvbias = (const float*)d_in[8];
  const float* projw = (const float*)d_in[9];
  const float* projb = (const float*)d_in[10];
  const float* ln2w = (const float*)d_in[11];
  const float* ln2b = (const float*)d_in[12];
  const float* w1f = (const float*)d_in[13];
  const float* b1 = (const float*)d_in[14];
  const float* w2f = (const float*)d_in[15];
  const float* b2 = (const float*)d_in[16];
  const float* lnfw = (const float*)d_in[17];
  const float* lnfb = (const float*)d_in[18];
  const float* headw = (const float*)d_in[19];
  const float* headb = (const float*)d_in[20];
  float* out = (float*)d_out;

  // workspace layout; A-side buffers padded to 6400 rows (tiles read past
  // M=6304; garbage rows are finite, never reach guarded outputs)
  char* p = (char*)d_ws;
  auto take = [&](size_t bytes) {
    char* q = p;
    p += (bytes + 255) & ~(size_t)255;
    return q;
  };
  u16* wq = (u16*)take(12ull * 768 * 2304 * 2);   // [N=2304][K=768] per layer
  u16* wpj = (u16*)take(12ull * 768 * 768 * 2);   // [768][768]
  u16* w1 = (u16*)take(12ull * 768 * 3072 * 2);   // [3072][768]
  u16* w2 = (u16*)take(12ull * 3072 * 768 * 2);   // [768][3072]
  u16* wc = (u16*)take(768ull * 768 * 2);         // conv_w already [N][K]
  float* h = (float*)take(6304ull * 768 * 4);
  u16* y = (u16*)take(6400ull * 768 * 2);
  u16* qkv = (u16*)take(6400ull * 2304 * 2);
  u16* ob = (u16*)take(6400ull * 768 * 2);
  u16* mlpb = (u16*)take(6400ull * 3072 * 2);  // also holds patches at start
  u16* P = (u16*)take(384ull * 197 * 224 * 2);
  float* skP = (float*)take(3ull * 6304 * 768 * 4);  // 3 split-K planes
  (void)ws_size; (void)in_sizes; (void)n_in; (void)out_size;

  // weight conversion fp32 -> bf16, transposed to [N][K]
  tpose_k<<<dim3(72, 24, 12), 256, 0, stream>>>(qkvw, wq, 768, 2304);
  tpose_k<<<dim3(24, 24, 12), 256, 0, stream>>>(projw, wpj, 768, 768);
  tpose_k<<<dim3(96, 24, 12), 256, 0, stream>>>(w1f, w1, 768, 3072);
  tpose_k<<<dim3(24, 96, 12), 256, 0, stream>>>(w2f, w2, 3072, 768);
  cvt4_k<<<576, 256, 0, stream>>>(conv_w, wc, 768 * 768 / 4);

  // patch embed
  patch_k<<<6272 * 768 / 256, 256, 0, stream>>>(x, mlpb);
  gemmP<3, 64><<<dim3(6, 98), 256, 0, stream>>>(mlpb, 768, wc, 768, conv_b,
                                                nullptr, 0, h, pos, 6272, 768,
                                                768);
  clspos_k<<<32 * 768 / 256, 256, 0, stream>>>(cls, pos, h);

  // layer 0's ln1 standalone; thereafter fused into redln
  ln_k<<<1576, 256, 0, stream>>>(h, ln1w, ln1b, y);
  for (int i = 0; i < 12; ++i) {
    gemmW2<0><<<dim3(9, 50), 512, 0, stream>>>(
        y, 768, wq + (size_t)i * 768 * 2304, 768, qkvbias + i * 2304, qkv,
        2304, nullptr, 6304, 768);
    qksm_k<<<dim3(384, 13), 64, 0, stream>>>(qkv, P);
    pv_k<<<384, 256, 0, stream>>>(qkv, P, ob);
    gemmP<2, 64><<<dim3(6, 99), 256, 0, stream>>>(
        ob, 768, wpj + (size_t)i * 768 * 768, 768, projb + i * 768, nullptr,
        768, h, nullptr, 6304, 768, 768);
    ln_k<<<1576, 256, 0, stream>>>(h, ln2w + i * 768, ln2b + i * 768, y);
    gemmW2<1><<<dim3(12, 50), 512, 0, stream>>>(
        y, 768, w1 + (size_t)i * 768 * 3072, 768, b1 + i * 3072, mlpb, 3072,
        nullptr, 6304, 768);
    // mlp2: split-K x3 (KC=1024) on 128x256 tile -> 450 blocks
    gemmW2<4><<<dim3(3, 50, 3), 512, 0, stream>>>(
        mlpb, 3072, w2 + (size_t)i * 3072 * 768, 3072, nullptr, nullptr, 768,
        skP, 6304, 1024);
    if (i < 11) {
      redln_k<<<1576, 256, 0, stream>>>(skP, b2 + i * 768, h,
                                        ln1w + (i + 1) * 768,
                                        ln1b + (i + 1) * 768, y);
    } else {
      redK<<<4728, 256, 0, stream>>>(skP, b2 + i * 768, h);
    }
  }

  head_k<<<32, 256, 0, stream>>>(h, lnfw, lnfb, headw, headb, out);
}

// Round 15
// 2951.204 us; speedup vs baseline: 1.2050x; 1.0466x over previous
//
#include <hip/hip_runtime.h>

// ViT-B/16 forward, B=32, S=197, E=768, H=12, HD=64, MLP=3072, DEPTH=12.
// Round 15: per-GEMM best-shape composition. R14 showed each GEMM has its
// own optimum: qkv/mlp2 prefer 128x256/BK=32 (traffic-bound), mlp1 prefers
// 128x128/BK=64 (step/drain-bound; BK=32 doubled its barriers, 65->77us).
// qkv: gemmW2. mlp1: gemmK64 (reverted). mlp2: gemmW2 split-K x3.
// proj/patch: gemmP. Attention/LN/redln unchanged from R14.

typedef __attribute__((ext_vector_type(8))) short short8;
typedef __attribute__((ext_vector_type(8))) unsigned short ushort8;
typedef __attribute__((ext_vector_type(4))) float f32x4;
typedef unsigned short u16;

#define DEV __device__ __forceinline__

DEV u16 f2bf(float f) {
  unsigned int u = __builtin_bit_cast(unsigned int, f);
  u += 0x7fffu + ((u >> 16) & 1u);
  return (u16)(u >> 16);
}
DEV float wred_sum(float v) {
  for (int o = 32; o; o >>= 1) v += __shfl_xor(v, o, 64);
  return v;
}
DEV void glds16(const void* gp, void* lp) {
  __builtin_amdgcn_global_load_lds(
      (const __attribute__((address_space(1))) void*)gp,
      (__attribute__((address_space(3))) void*)lp, 16, 0, 0);
}
// m204 bijective XCD swizzle: contiguous wg chunk per XCD
DEV int xcd_swz(int flat, int nwg) {
  int q = nwg >> 3, r = nwg & 7;
  int x = flat & 7, o = flat >> 3;
  return (x < r ? x * (q + 1) : r * (q + 1) + (x - r) * q) + o;
}

// ---------------- weight conversion ----------------
__global__ __launch_bounds__(256) void cvt4_k(const float* __restrict__ s,
                                              u16* __restrict__ d, long n4) {
  long i = (long)blockIdx.x * 256 + threadIdx.x;
  if (i >= n4) return;
  float4 v = ((const float4*)s)[i];
  ushort4 o;
  o.x = f2bf(v.x); o.y = f2bf(v.y); o.z = f2bf(v.z); o.w = f2bf(v.w);
  ((ushort4*)d)[i] = o;
}

// fp32 [K][N] (blockIdx.z selects layer) -> bf16 [N][K], tiled 32x32
__global__ __launch_bounds__(256) void tpose_k(const float* __restrict__ s,
                                               u16* __restrict__ d, int K,
                                               int N) {
  __shared__ float t[32][33];
  const int bx = blockIdx.x;  // n tile
  const int by = blockIdx.y;  // k tile
  const size_t base = (size_t)blockIdx.z * K * N;
  const int c = threadIdx.x & 31, r0 = threadIdx.x >> 5;
#pragma unroll
  for (int i = 0; i < 4; ++i) {
    int r = r0 + i * 8;
    t[r][c] = s[base + (size_t)(by * 32 + r) * N + bx * 32 + c];
  }
  __syncthreads();
#pragma unroll
  for (int i = 0; i < 4; ++i) {
    int r = r0 + i * 8;
    d[base + (size_t)(bx * 32 + r) * K + by * 32 + c] = f2bf(t[c][r]);
  }
}

// patches[b][p][d] <- x[b][c][gy*16+py][gx*16+px], bf16
__global__ __launch_bounds__(256) void patch_k(const float* __restrict__ x,
                                               u16* __restrict__ pt) {
  int i = blockIdx.x * 256 + threadIdx.x;  // 6272*768 exactly
  int d = i % 768;
  int bp = i / 768;
  int p = bp % 196, b = bp / 196;
  int c = d >> 8, pd = d & 255;
  int py = pd >> 4, px = pd & 15;
  int gy = p / 14, gx = p - gy * 14;
  size_t src = ((size_t)(b * 3 + c) * 224 + gy * 16 + py) * 224 + gx * 16 + px;
  pt[i] = f2bf(x[src]);
}

// h[b][0][:] = cls + pos[0]
__global__ __launch_bounds__(256) void clspos_k(const float* __restrict__ cls,
                                                const float* __restrict__ pos,
                                                float* __restrict__ h) {
  int i = blockIdx.x * 256 + threadIdx.x;  // 32*768
  int b = i / 768, e = i - b * 768;
  h[(size_t)b * 197 * 768 + e] = cls[e] + pos[e];
}

// ---------------- epilogue helper ----------------
template <int EPI>
DEV void epi_store(float v, int grow, int gcol, u16* outb, int ldo,
                   float* outf, const float* pos) {
  if constexpr (EPI == 0) {
    outb[(size_t)grow * ldo + gcol] = f2bf(v);
  } else if constexpr (EPI == 1) {
    // gelu(x) ~= x * sigmoid(1.5957691(x + 0.044715 x^3))
    float u = __expf(-1.5957691216f * (v + 0.044715f * v * v * v));
    outb[(size_t)grow * ldo + gcol] = f2bf(v / (1.f + u));
  } else if constexpr (EPI == 2) {
    outf[(size_t)grow * ldo + gcol] += v;
  } else {
    int b = grow / 196, p = grow - b * 196;
    outf[(size_t)(grow + b + 1) * 768 + gcol] =
        v + pos[(size_t)(p + 1) * 768 + gcol];
  }
}

// -------- gemmK64: C[M,N] = A[M,K] @ Bt[N,K], 128x128 tile, BK=64 ---------
// 8 waves (2m x 4n), 2-phase double-buffer, global_load_lds(16B), both-sides
// chunk-XOR swizzle, tm-major flat + XCD block swizzle. (mlp1)
template <int EPI>
__global__ __launch_bounds__(512) void gemmK64(
    const u16* __restrict__ A, int lda, const u16* __restrict__ Bt, int ldb,
    const float* __restrict__ bias, u16* __restrict__ outb, int ldo,
    float* __restrict__ outf, const float* __restrict__ pos, int M, int N,
    int K) {
  __shared__ __align__(16) u16 Ak[2][128 * 64];
  __shared__ __align__(16) u16 Bk[2][128 * 64];
  const int tid = threadIdx.x;
  const int lane = tid & 63, wid = tid >> 6;
  const int wm = wid >> 2, wn = wid & 3;
  const int lg = lane >> 4, lr = lane & 15;
  const int nwg = gridDim.x * gridDim.y;
  const int wg = xcd_swz(blockIdx.y * gridDim.x + blockIdx.x, nwg);
  const int tn = wg % gridDim.x, tm = wg / gridDim.x;

  const int r8 = lane >> 3, c8 = lane & 7;
  const int swc = (c8 ^ r8) << 3;  // source chunk pre-swizzled (rule #21)
  const u16* aS = A + (size_t)(tm * 128 + wid * 16 + r8) * lda + swc;
  const u16* bS = Bt + (size_t)(tn * 128 + wid * 16 + r8) * ldb + swc;

  auto stage = [&](int buf, int kt) {  // 4 glds16/wave
    const u16* ak = aS + kt * 64;
    const u16* bk = bS + kt * 64;
    u16* ad = &Ak[buf][wid * 1024];
    u16* bd = &Bk[buf][wid * 1024];
    glds16(ak, ad);
    glds16(ak + (size_t)8 * lda, ad + 512);
    glds16(bk, bd);
    glds16(bk + (size_t)8 * ldb, bd + 512);
  };

  f32x4 acc[4][2] = {};
  auto compute = [&](int buf) {
#pragma unroll
    for (int ks = 0; ks < 2; ++ks) {
      const int pc = (ks << 2) | lg;
      const int po = ((pc ^ (lr & 7)) << 3);  // read-side un-swizzle
      short8 af[4], bf2[2];
#pragma unroll
      for (int i = 0; i < 4; ++i)
        af[i] = *(const short8*)(&Ak[buf][(wm * 64 + i * 16 + lr) * 64 + po]);
#pragma unroll
      for (int i = 0; i < 2; ++i)
        bf2[i] = *(const short8*)(&Bk[buf][(wn * 32 + i * 16 + lr) * 64 + po]);
#pragma unroll
      for (int mi = 0; mi < 4; ++mi)
#pragma unroll
        for (int ni = 0; ni < 2; ++ni)
          acc[mi][ni] = __builtin_amdgcn_mfma_f32_16x16x32_bf16(
              af[mi], bf2[ni], acc[mi][ni], 0, 0, 0);
    }
  };

  const int nk = K >> 6;
  int cur = 0;
  stage(0, 0);
  __syncthreads();
  for (int kt = 0; kt < nk - 1; ++kt) {
    stage(cur ^ 1, kt + 1);  // next K-tile in flight under compute
    compute(cur);
    __syncthreads();
    cur ^= 1;
  }
  compute(cur);

#pragma unroll
  for (int mi = 0; mi < 4; ++mi)
#pragma unroll
    for (int ni = 0; ni < 2; ++ni)
#pragma unroll
      for (int r = 0; r < 4; ++r) {
        int grow = tm * 128 + wm * 64 + mi * 16 + lg * 4 + r;
        int gcol = tn * 128 + wn * 32 + ni * 16 + lr;
        if (grow < M)
          epi_store<EPI>(acc[mi][ni][r] + bias[gcol], grow, gcol, outb, ldo,
                         outf, pos);
      }
}

// -------- gemmW2: C[M,N] = A[M,K] @ Bt[N,K], 128(M) x 256(N), BK=32 -------
// 8 waves (2m x 4n, wave tile 64x64), 2-phase double-buffer, 48KB LDS ->
// 3 blocks/CU. (qkv direct; mlp2 split-K via EPI 4.)
template <int EPI>
__global__ __launch_bounds__(512) void gemmW2(
    const u16* __restrict__ A, int lda, const u16* __restrict__ Bt, int ldb,
    const float* __restrict__ bias, u16* __restrict__ outb, int ldo,
    float* __restrict__ outf, int M, int K) {
  __shared__ __align__(16) u16 Ak[2][128 * 32];  // 16 KB
  __shared__ __align__(16) u16 Bk[2][256 * 32];  // 32 KB
  const int tid = threadIdx.x;
  const int lane = tid & 63, wid = tid >> 6;
  const int wm = wid >> 2, wn = wid & 3;
  const int lg = lane >> 4, lr = lane & 15;
  const int nwg = gridDim.x * gridDim.y;
  const int wg = xcd_swz(blockIdx.y * gridDim.x + blockIdx.x, nwg);
  const int tn = wg % gridDim.x, tm = wg / gridDim.x;
  const size_t koff = (EPI == 4) ? (size_t)blockIdx.z * K : 0;

  const int sr = lane >> 2;
  const int sc4 = (((lane & 3) ^ ((lane >> 3) & 3)) << 3);
  const u16* aSrc = A + (size_t)(tm * 128 + wid * 16 + sr) * lda + koff + sc4;
  const u16* bSrc = Bt + (size_t)(tn * 256 + wid * 32 + sr) * ldb + koff + sc4;
  const size_t bRow16 = (size_t)16 * ldb;

  auto stage = [&](int buf, int kt) {  // 3 glds16/wave
    const u16* ak = aSrc + kt * 32;
    const u16* bk = bSrc + kt * 32;
    glds16(ak, &Ak[buf][wid * 16 * 32]);
    u16* bd = &Bk[buf][wid * 32 * 32];
    glds16(bk, bd);
    glds16(bk + bRow16, bd + 512);
  };

  const int rp = (lg ^ ((lr >> 1) & 3)) << 3;  // read-side un-swizzle
  f32x4 acc[4][4] = {};
  auto compute = [&](int buf) {
    short8 af[4], bf[4];
#pragma unroll
    for (int i = 0; i < 4; ++i)
      af[i] = *(const short8*)(&Ak[buf][(wm * 64 + i * 16 + lr) * 32 + rp]);
#pragma unroll
    for (int i = 0; i < 4; ++i)
      bf[i] = *(const short8*)(&Bk[buf][(wn * 64 + i * 16 + lr) * 32 + rp]);
#pragma unroll
    for (int mi = 0; mi < 4; ++mi)
#pragma unroll
      for (int ni = 0; ni < 4; ++ni)
        acc[mi][ni] = __builtin_amdgcn_mfma_f32_16x16x32_bf16(
            af[mi], bf[ni], acc[mi][ni], 0, 0, 0);
  };

  const int nk = K >> 5;
  int cur = 0;
  stage(0, 0);
  __syncthreads();
  for (int kt = 0; kt < nk - 1; ++kt) {
    stage(cur ^ 1, kt + 1);  // next K-tile in flight under compute
    compute(cur);
    __syncthreads();
    cur ^= 1;
  }
  compute(cur);

#pragma unroll
  for (int mi = 0; mi < 4; ++mi)
#pragma unroll
    for (int ni = 0; ni < 4; ++ni)
#pragma unroll
      for (int r = 0; r < 4; ++r) {
        int grow = tm * 128 + wm * 64 + mi * 16 + lg * 4 + r;
        int gcol = tn * 256 + wn * 64 + ni * 16 + lr;
        if (grow < M) {
          if constexpr (EPI == 4) {
            outf[(size_t)blockIdx.z * M * ldo + (size_t)grow * ldo + gcol] =
                acc[mi][ni][r];
          } else {
            epi_store<EPI>(acc[mi][ni][r] + bias[gcol], grow, gcol, outb, ldo,
                           outf, nullptr);
          }
        }
      }
}

// redK: h += bias + Cp[0..2]  (last-layer reduce, float4)
__global__ __launch_bounds__(256) void redK(const float* __restrict__ Cp,
                                            const float* __restrict__ bias,
                                            float* __restrict__ h) {
  size_t i = ((size_t)blockIdx.x * 256 + threadIdx.x) * 4;  // < 6304*768
  float4 p0 = *(const float4*)(Cp + i);
  float4 p1 = *(const float4*)(Cp + 6304ull * 768 + i);
  float4 p2 = *(const float4*)(Cp + 2ull * 6304 * 768 + i);
  float4 hv = *(const float4*)(h + i);
  float4 bv = *(const float4*)(bias + (int)(i % 768));
  hv.x += p0.x + p1.x + p2.x + bv.x;
  hv.y += p0.y + p1.y + p2.y + bv.y;
  hv.z += p0.z + p1.z + p2.z + bv.z;
  hv.w += p0.w + p1.w + p2.w + bv.w;
  *(float4*)(h + i) = hv;
}

// redln: h' = h + bias + Cp[0..2]; h = h'; y = ln(h', w, b) bf16.
__global__ __launch_bounds__(256) void redln_k(
    const float* __restrict__ Cp, const float* __restrict__ bias,
    float* __restrict__ h, const float* __restrict__ lnw,
    const float* __restrict__ lnb, u16* __restrict__ y) {
  const int lane = threadIdx.x & 63, wv = threadIdx.x >> 6;
  const int r = blockIdx.x * 4 + wv;
  const size_t base = (size_t)r * 768;
  float4 a[3];
  float s = 0.f, q = 0.f;
#pragma unroll
  for (int i = 0; i < 3; ++i) {
    const int off = i * 256 + lane * 4;
    float4 hv = *(const float4*)(h + base + off);
    float4 p0 = *(const float4*)(Cp + base + off);
    float4 p1 = *(const float4*)(Cp + 6304ull * 768 + base + off);
    float4 p2 = *(const float4*)(Cp + 2ull * 6304 * 768 + base + off);
    float4 bv = *(const float4*)(bias + off);
    a[i].x = hv.x + p0.x + p1.x + p2.x + bv.x;
    a[i].y = hv.y + p0.y + p1.y + p2.y + bv.y;
    a[i].z = hv.z + p0.z + p1.z + p2.z + bv.z;
    a[i].w = hv.w + p0.w + p1.w + p2.w + bv.w;
    s += a[i].x + a[i].y + a[i].z + a[i].w;
    q += a[i].x * a[i].x + a[i].y * a[i].y + a[i].z * a[i].z +
         a[i].w * a[i].w;
  }
  s = wred_sum(s);
  q = wred_sum(q);
  float mu = s * (1.f / 768.f);
  float var = q * (1.f / 768.f) - mu * mu;
  float rs = rsqrtf(var + 1e-5f);
#pragma unroll
  for (int i = 0; i < 3; ++i) {
    const int off = i * 256 + lane * 4;
    *(float4*)(h + base + off) = a[i];
    float4 wv4 = *(const float4*)(lnw + off);
    float4 bv4 = *(const float4*)(lnb + off);
    ushort4 o;
    o.x = f2bf((a[i].x - mu) * rs * wv4.x + bv4.x);
    o.y = f2bf((a[i].y - mu) * rs * wv4.y + bv4.y);
    o.z = f2bf((a[i].z - mu) * rs * wv4.z + bv4.z);
    o.w = f2bf((a[i].w - mu) * rs * wv4.w + bv4.w);
    *(ushort4*)(y + base + off) = o;
  }
}

// -------- gemmP: BMx128 tile, BK=32, 4 waves, 2-phase (patch + proj) ------
template <int EPI, int BM>
__global__ __launch_bounds__(256) void gemmP(
    const u16* __restrict__ A, int lda, const u16* __restrict__ Bt, int ldb,
    const float* __restrict__ bias, u16* __restrict__ outb, int ldo,
    float* __restrict__ outf, const float* __restrict__ pos, int M, int N,
    int K) {
  constexpr int MI = BM / 32;  // acc rows per wave (2 or 4)
  __shared__ __align__(16) u16 Ak[2][BM * 32];
  __shared__ __align__(16) u16 Bk[2][128 * 32];
  const int tid = threadIdx.x;
  const int lane = tid & 63, wid = tid >> 6;
  const int wm = wid >> 1, wn = wid & 1;
  const int lg = lane >> 4, lr = lane & 15;
  const int nwg = gridDim.x * gridDim.y;
  const int wg = xcd_swz(blockIdx.y * gridDim.x + blockIdx.x, nwg);
  const int tn = wg % gridDim.x, tm = wg / gridDim.x;

  const int sr = lane >> 2;
  const int sc4 = (((lane & 3) ^ ((lane >> 3) & 3)) << 3);
  const u16* aSrc = A + (size_t)(tm * BM + wid * (BM / 4) + sr) * lda + sc4;
  const u16* bSrc = Bt + (size_t)(tn * 128 + wid * 32 + sr) * ldb + sc4;
  const size_t aRow16 = (size_t)16 * lda, bRow16 = (size_t)16 * ldb;

  auto stage = [&](int buf, int kt) {
    const u16* ak = aSrc + kt * 32;
    const u16* bk = bSrc + kt * 32;
    u16* ad = &Ak[buf][wid * (BM / 4) * 32];
    u16* bd = &Bk[buf][wid * 1024];
    glds16(ak, ad);
    if constexpr (BM == 128) glds16(ak + aRow16, ad + 512);
    glds16(bk, bd);
    glds16(bk + bRow16, bd + 512);
  };

  const int rp = (lg ^ ((lr >> 1) & 3)) << 3;
  f32x4 acc[MI][4] = {};
  auto compute = [&](int buf) {
    short8 af[MI], bfr[4];
#pragma unroll
    for (int i = 0; i < MI; ++i)
      af[i] =
          *(const short8*)(&Ak[buf][(wm * (BM / 2) + i * 16 + lr) * 32 + rp]);
#pragma unroll
    for (int i = 0; i < 4; ++i)
      bfr[i] = *(const short8*)(&Bk[buf][(wn * 64 + i * 16 + lr) * 32 + rp]);
#pragma unroll
    for (int mi = 0; mi < MI; ++mi)
#pragma unroll
      for (int ni = 0; ni < 4; ++ni)
        acc[mi][ni] = __builtin_amdgcn_mfma_f32_16x16x32_bf16(
            af[mi], bfr[ni], acc[mi][ni], 0, 0, 0);
  };

  const int nk = K >> 5;
  int cur = 0;
  stage(0, 0);
  __syncthreads();
  for (int kt = 0; kt < nk - 1; ++kt) {
    stage(cur ^ 1, kt + 1);
    compute(cur);
    __syncthreads();
    cur ^= 1;
  }
  compute(cur);

#pragma unroll
  for (int mi = 0; mi < MI; ++mi)
#pragma unroll
    for (int ni = 0; ni < 4; ++ni)
#pragma unroll
      for (int r = 0; r < 4; ++r) {
        int grow = tm * BM + wm * (BM / 2) + mi * 16 + lg * 4 + r;
        int gcol = tn * 128 + wn * 64 + ni * 16 + lr;
        if (grow < M)
          epi_store<EPI>(acc[mi][ni][r] + bias[gcol], grow, gcol, outb, ldo,
                         outf, pos);
      }
}

// ---------------- attention ----------------
// fused QK^T + softmax: P[bh][q][k] bf16, row stride 224, cols 197..223 = 0.
__global__ __launch_bounds__(64) void qksm_k(const u16* __restrict__ qkv,
                                             u16* __restrict__ P) {
  const int bh = blockIdx.x;  // b*12+h
  const int qt = blockIdx.y;  // 0..12
  const int lane = threadIdx.x;
  const int lg = lane >> 4, lr = lane & 15;
  const int b = bh / 12, hh = bh - b * 12;
  const u16* base = qkv + (size_t)b * 197 * 2304 + hh * 64;
  int qrow = qt * 16 + lr;
  if (qrow > 196) qrow = 196;
  const u16* qp = base + (size_t)qrow * 2304 + lg * 8;
  short8 a0 = *(const short8*)(qp);
  short8 a1 = *(const short8*)(qp + 32);
  f32x4 c[13];
  const bool kval[2] = {true, (12 * 16 + lr) <= 196};
#pragma unroll
  for (int kt = 0; kt < 13; ++kt) {
    int krow = kt * 16 + lr;
    if (krow > 196) krow = 196;
    const u16* kp = base + 768 + (size_t)krow * 2304 + lg * 8;
    short8 b0 = *(const short8*)(kp);
    short8 b1 = *(const short8*)(kp + 32);
    f32x4 t = {0.f, 0.f, 0.f, 0.f};
    t = __builtin_amdgcn_mfma_f32_16x16x32_bf16(a0, b0, t, 0, 0, 0);
    c[kt] = __builtin_amdgcn_mfma_f32_16x16x32_bf16(a1, b1, t, 0, 0, 0);
  }
  float mr[4], sr_[4];
#pragma unroll
  for (int r = 0; r < 4; ++r) {
    float mm = -3.4e38f;
#pragma unroll
    for (int kt = 0; kt < 13; ++kt)
      if (kval[kt == 12]) mm = fmaxf(mm, c[kt][r] * 0.125f);
#pragma unroll
    for (int o = 1; o < 16; o <<= 1) mm = fmaxf(mm, __shfl_xor(mm, o, 64));
    mr[r] = mm;
  }
#pragma unroll
  for (int r = 0; r < 4; ++r) {
    float s = 0.f;
#pragma unroll
    for (int kt = 0; kt < 13; ++kt) {
      float e = kval[kt == 12] ? __expf(c[kt][r] * 0.125f - mr[r]) : 0.f;
      c[kt][r] = e;
      s += e;
    }
#pragma unroll
    for (int o = 1; o < 16; o <<= 1) s += __shfl_xor(s, o, 64);
    sr_[r] = 1.0f / s;
  }
  u16* pb = P + (size_t)bh * 197 * 224;
#pragma unroll
  for (int r = 0; r < 4; ++r) {
    int q = qt * 16 + lg * 4 + r;
    if (q < 197) {
#pragma unroll
      for (int kt = 0; kt < 13; ++kt)
        pb[(size_t)q * 224 + kt * 16 + lr] = f2bf(c[kt][r] * sr_[r]);
      pb[(size_t)q * 224 + 208 + lr] = 0;  // pad cols 208..223
    }
  }
}

// o[b][q][h*64+d] = sum_k P[bh][q][k](bf16) * V[b][k][h][d]; V via LDS
__global__ __launch_bounds__(256) void pv_k(const u16* __restrict__ qkv,
                                            const u16* __restrict__ P,
                                            u16* __restrict__ o) {
  __shared__ __align__(16) u16 Vs[224 * 64];  // 28 KB
  const int bh = blockIdx.x;
  const int b = bh / 12, hh = bh - b * 12;
  const int tid = threadIdx.x;
  const int lane = tid & 63, ct = tid >> 6;  // wave = 16-col tile of HD
  const int lg = lane >> 4, lr = lane & 15;
  const u16* vhead = qkv + (size_t)b * 197 * 2304 + 1536 + hh * 64;
#pragma unroll
  for (int it = 0; it < 7; ++it) {
    const int c0 = it * 256 + ct * 64;  // wave-uniform chunk base
    const int c = c0 + lane;
    int row = c >> 3;
    if (row > 196) row = 196;
    glds16(vhead + (size_t)row * 2304 + (c & 7) * 8, &Vs[c0 * 8]);
  }
  __syncthreads();
  short8 vf[7];
#pragma unroll
  for (int ks = 0; ks < 7; ++ks) {
    ushort8 t;
#pragma unroll
    for (int j = 0; j < 8; ++j) {
      int kk = ks * 32 + lg * 8 + j;
      t[j] = Vs[kk * 64 + ct * 16 + lr];
    }
    vf[ks] = __builtin_bit_cast(short8, t);
  }
  const u16* pbase = P + (size_t)bh * 197 * 224;
  u16* ob = o + (size_t)b * 197 * 768 + hh * 64 + ct * 16;
  for (int qt = 0; qt < 13; ++qt) {
    int q = qt * 16 + lr;
    if (q > 196) q = 196;
    const u16* pp = pbase + (size_t)q * 224 + lg * 8;
    f32x4 acc = {0.f, 0.f, 0.f, 0.f};
#pragma unroll
    for (int ks = 0; ks < 7; ++ks) {
      short8 af = *(const short8*)(pp + ks * 32);
      acc = __builtin_amdgcn_mfma_f32_16x16x32_bf16(af, vf[ks], acc, 0, 0, 0);
    }
#pragma unroll
    for (int r = 0; r < 4; ++r) {
      int qq = qt * 16 + lg * 4 + r;
      if (qq < 197) ob[(size_t)qq * 768 + lr] = f2bf(acc[r]);
    }
  }
}

// ---------------- layernorm: 4 rows/block, 64 lanes/row, float4 ----------
__global__ __launch_bounds__(256) void ln_k(const float* __restrict__ x,
                                            const float* __restrict__ w,
                                            const float* __restrict__ bb,
                                            u16* __restrict__ y) {
  const int lane = threadIdx.x & 63, wv = threadIdx.x >> 6;
  const int r = blockIdx.x * 4 + wv;
  const float* xr = x + (size_t)r * 768;
  float4 v[3];
  float s = 0.f, q = 0.f;
#pragma unroll
  for (int i = 0; i < 3; ++i) {
    v[i] = *(const float4*)(xr + i * 256 + lane * 4);
    s += v[i].x + v[i].y + v[i].z + v[i].w;
    q += v[i].x * v[i].x + v[i].y * v[i].y + v[i].z * v[i].z +
         v[i].w * v[i].w;
  }
  s = wred_sum(s);
  q = wred_sum(q);
  float mu = s * (1.f / 768.f);
  float var = q * (1.f / 768.f) - mu * mu;
  float rs = rsqrtf(var + 1e-5f);
  u16* yr = y + (size_t)r * 768;
#pragma unroll
  for (int i = 0; i < 3; ++i) {
    float4 wv4 = *(const float4*)(w + i * 256 + lane * 4);
    float4 bv4 = *(const float4*)(bb + i * 256 + lane * 4);
    ushort4 o;
    o.x = f2bf((v[i].x - mu) * rs * wv4.x + bv4.x);
    o.y = f2bf((v[i].y - mu) * rs * wv4.y + bv4.y);
    o.z = f2bf((v[i].z - mu) * rs * wv4.z + bv4.z);
    o.w = f2bf((v[i].w - mu) * rs * wv4.w + bv4.w);
    *(ushort4*)(yr + i * 256 + lane * 4) = o;
  }
}

// ---------------- final LN(cls row) + head ----------------
__global__ __launch_bounds__(256) void head_k(
    const float* __restrict__ h, const float* __restrict__ lnw,
    const float* __restrict__ lnb, const float* __restrict__ hw,
    const float* __restrict__ hb, float* __restrict__ out) {
  const int b = blockIdx.x, tid = threadIdx.x;
  const float* xr = h + (size_t)b * 197 * 768;
  float v0 = xr[tid], v1 = xr[tid + 256], v2 = xr[tid + 512];
  float s = v0 + v1 + v2;
  float q = v0 * v0 + v1 * v1 + v2 * v2;
  s = wred_sum(s);
  q = wred_sum(q);
  __shared__ float ss[4], qs[4];
  int lane = tid & 63, wid = tid >> 6;
  if (lane == 0) { ss[wid] = s; qs[wid] = q; }
  __syncthreads();
  float S = ss[0] + ss[1] + ss[2] + ss[3];
  float Q = qs[0] + qs[1] + qs[2] + qs[3];
  float mu = S * (1.f / 768.f);
  float var = Q * (1.f / 768.f) - mu * mu;
  float rs = rsqrtf(var + 1e-5f);
  __shared__ float yb[768];
  yb[tid] = (v0 - mu) * rs * lnw[tid] + lnb[tid];
  yb[tid + 256] = (v1 - mu) * rs * lnw[tid + 256] + lnb[tid + 256];
  yb[tid + 512] = (v2 - mu) * rs * lnw[tid + 512] + lnb[tid + 512];
  __syncthreads();
  float p[10] = {};
  for (int e = tid; e < 768; e += 256) {
    float yv = yb[e];
#pragma unroll
    for (int n = 0; n < 10; ++n) p[n] += yv * hw[(size_t)e * 10 + n];
  }
#pragma unroll
  for (int n = 0; n < 10; ++n) p[n] = wred_sum(p[n]);
  __shared__ float red[4][10];
  if (lane == 0)
#pragma unroll
    for (int n = 0; n < 10; ++n) red[wid][n] = p[n];
  __syncthreads();
  if (tid < 10)
    out[b * 10 + tid] =
        red[0][tid] + red[1][tid] + red[2][tid] + red[3][tid] + hb[tid];
}

// ---------------- host orchestration ----------------
extern "C" void kernel_launch(void* const* d_in, const int* in_sizes, int n_in,
                              void* d_out, int out_size, void* d_ws,
                              size_t ws_size, hipStream_t stream) {
  const float* x = (const float*)d_in[0];
  const float* conv_w = (const float*)d_in[1];
  const float* conv_b = (const float*)d_in[2];
  const float* cls = (const float*)d_in[3];
  const float* pos = (const float*)d_in[4];
  const float* ln1w = (const float*)d_in[5];
  const float* ln1b = (const float*)d_in[6];
  const float* qkvw = (const float*)d_in[7];
  const float* qkvbias = (const float*)d_in[8];
  const float* projw = (const float*)d_in[9];
  const float* projb = (const float*)d_in[10];
  const float* ln2w = (const float*)d_in[11];
  const float* ln2b = (const float*)d_in[12];
  const float* w1f = (const float*)d_in[13];
  const float* b1 = (const float*)d_in[14];
  const float* w2f = (const float*)d_in[15];
  const float* b2 = (const float*)d_in[16];
  const float* lnfw = (const float*)d_in[17];
  const float* lnfb = (const float*)d_in[18];
  const float* headw = (const float*)d_in[19];
  const float* headb = (const float*)d_in[20];
  float* out = (float*)d_out;

  // workspace layout; A-side buffers padded to 6400 rows (tiles read past
  // M=6304; garbage rows are finite, never reach guarded outputs)
  char* p = (char*)d_ws;
  auto take = [&](size_t bytes) {
    char* q = p;
    p += (bytes + 255) & ~(size_t)255;
    return q;
  };
  u16* wq = (u16*)take(12ull * 768 * 2304 * 2);   // [N=2304][K=768] per layer
  u16* wpj = (u16*)take(12ull * 768 * 768 * 2);   // [768][768]
  u16* w1 = (u16*)take(12ull * 768 * 3072 * 2);   // [3072][768]
  u16* w2 = (u16*)take(12ull * 3072 * 768 * 2);   // [768][3072]
  u16* wc = (u16*)take(768ull * 768 * 2);         // conv_w already [N][K]
  float* h = (float*)take(6304ull * 768 * 4);
  u16* y = (u16*)take(6400ull * 768 * 2);
  u16* qkv = (u16*)take(6400ull * 2304 * 2);
  u16* ob = (u16*)take(6400ull * 768 * 2);
  u16* mlpb = (u16*)take(6400ull * 3072 * 2);  // also holds patches at start
  u16* P = (u16*)take(384ull * 197 * 224 * 2);
  float* skP = (float*)take(3ull * 6304 * 768 * 4);  // 3 split-K planes
  (void)ws_size; (void)in_sizes; (void)n_in; (void)out_size;

  // weight conversion fp32 -> bf16, transposed to [N][K]
  tpose_k<<<dim3(72, 24, 12), 256, 0, stream>>>(qkvw, wq, 768, 2304);
  tpose_k<<<dim3(24, 24, 12), 256, 0, stream>>>(projw, wpj, 768, 768);
  tpose_k<<<dim3(96, 24, 12), 256, 0, stream>>>(w1f, w1, 768, 3072);
  tpose_k<<<dim3(24, 96, 12), 256, 0, stream>>>(w2f, w2, 3072, 768);
  cvt4_k<<<576, 256, 0, stream>>>(conv_w, wc, 768 * 768 / 4);

  // patch embed
  patch_k<<<6272 * 768 / 256, 256, 0, stream>>>(x, mlpb);
  gemmP<3, 64><<<dim3(6, 98), 256, 0, stream>>>(mlpb, 768, wc, 768, conv_b,
                                                nullptr, 0, h, pos, 6272, 768,
                                                768);
  clspos_k<<<32 * 768 / 256, 256, 0, stream>>>(cls, pos, h);

  // layer 0's ln1 standalone; thereafter fused into redln
  ln_k<<<1576, 256, 0, stream>>>(h, ln1w, ln1b, y);
  for (int i = 0; i < 12; ++i) {
    gemmW2<0><<<dim3(9, 50), 512, 0, stream>>>(
        y, 768, wq + (size_t)i * 768 * 2304, 768, qkvbias + i * 2304, qkv,
        2304, nullptr, 6304, 768);
    qksm_k<<<dim3(384, 13), 64, 0, stream>>>(qkv, P);
    pv_k<<<384, 256, 0, stream>>>(qkv, P, ob);
    gemmP<2, 64><<<dim3(6, 99), 256, 0, stream>>>(
        ob, 768, wpj + (size_t)i * 768 * 768, 768, projb + i * 768, nullptr,
        768, h, nullptr, 6304, 768, 768);
    ln_k<<<1576, 256, 0, stream>>>(h, ln2w + i * 768, ln2b + i * 768, y);
    gemmK64<1><<<dim3(24, 50), 512, 0, stream>>>(
        y, 768, w1 + (size_t)i * 768 * 3072, 768, b1 + i * 3072, mlpb, 3072,
        nullptr, nullptr, 6304, 3072, 768);
    // mlp2: split-K x3 (KC=1024) on 128x256 tile -> 450 blocks
    gemmW2<4><<<dim3(3, 50, 3), 512, 0, stream>>>(
        mlpb, 3072, w2 + (size_t)i * 3072 * 768, 3072, nullptr, nullptr, 768,
        skP, 6304, 1024);
    if (i < 11) {
      redln_k<<<1576, 256, 0, stream>>>(skP, b2 + i * 768, h,
                                        ln1w + (i + 1) * 768,
                                        ln1b + (i + 1) * 768, y);
    } else {
      redK<<<4728, 256, 0, stream>>>(skP, b2 + i * 768, h);
    }
  }

  head_k<<<32, 256, 0, stream>>>(h, lnfw, lnfb, headw, headb, out);
}

// Round 16
// 2840.900 us; speedup vs baseline: 1.2518x; 1.0388x over previous
//
#include <hip/hip_runtime.h>

// ViT-B/16 forward, B=32, S=197, E=768, H=12, HD=64, MLP=3072, DEPTH=12.
// Round 16: R15 (best, 2951us) + (1) bf16 split-K partial planes (halves
// gemmSK write + redln plane-read traffic; RNE rounding, unbiased), and
// (2) qksm with LDS-staged K (4 waves/block, chunk-XOR swizzle; kills the
// 13x K re-read per head). All GEMM schedules frozen from R15.

typedef __attribute__((ext_vector_type(8))) short short8;
typedef __attribute__((ext_vector_type(8))) unsigned short ushort8;
typedef __attribute__((ext_vector_type(4))) float f32x4;
typedef unsigned short u16;

#define DEV __device__ __forceinline__

DEV u16 f2bf(float f) {
  unsigned int u = __builtin_bit_cast(unsigned int, f);
  u += 0x7fffu + ((u >> 16) & 1u);
  return (u16)(u >> 16);
}
DEV float bf2f(u16 v) {
  return __builtin_bit_cast(float, (unsigned int)v << 16);
}
DEV float wred_sum(float v) {
  for (int o = 32; o; o >>= 1) v += __shfl_xor(v, o, 64);
  return v;
}
DEV void glds16(const void* gp, void* lp) {
  __builtin_amdgcn_global_load_lds(
      (const __attribute__((address_space(1))) void*)gp,
      (__attribute__((address_space(3))) void*)lp, 16, 0, 0);
}
// m204 bijective XCD swizzle: contiguous wg chunk per XCD
DEV int xcd_swz(int flat, int nwg) {
  int q = nwg >> 3, r = nwg & 7;
  int x = flat & 7, o = flat >> 3;
  return (x < r ? x * (q + 1) : r * (q + 1) + (x - r) * q) + o;
}

// ---------------- weight conversion ----------------
__global__ __launch_bounds__(256) void cvt4_k(const float* __restrict__ s,
                                              u16* __restrict__ d, long n4) {
  long i = (long)blockIdx.x * 256 + threadIdx.x;
  if (i >= n4) return;
  float4 v = ((const float4*)s)[i];
  ushort4 o;
  o.x = f2bf(v.x); o.y = f2bf(v.y); o.z = f2bf(v.z); o.w = f2bf(v.w);
  ((ushort4*)d)[i] = o;
}

// fp32 [K][N] (blockIdx.z selects layer) -> bf16 [N][K], tiled 32x32
__global__ __launch_bounds__(256) void tpose_k(const float* __restrict__ s,
                                               u16* __restrict__ d, int K,
                                               int N) {
  __shared__ float t[32][33];
  const int bx = blockIdx.x;  // n tile
  const int by = blockIdx.y;  // k tile
  const size_t base = (size_t)blockIdx.z * K * N;
  const int c = threadIdx.x & 31, r0 = threadIdx.x >> 5;
#pragma unroll
  for (int i = 0; i < 4; ++i) {
    int r = r0 + i * 8;
    t[r][c] = s[base + (size_t)(by * 32 + r) * N + bx * 32 + c];
  }
  __syncthreads();
#pragma unroll
  for (int i = 0; i < 4; ++i) {
    int r = r0 + i * 8;
    d[base + (size_t)(bx * 32 + r) * K + by * 32 + c] = f2bf(t[c][r]);
  }
}

// patches[b][p][d] <- x[b][c][gy*16+py][gx*16+px], bf16
__global__ __launch_bounds__(256) void patch_k(const float* __restrict__ x,
                                               u16* __restrict__ pt) {
  int i = blockIdx.x * 256 + threadIdx.x;  // 6272*768 exactly
  int d = i % 768;
  int bp = i / 768;
  int p = bp % 196, b = bp / 196;
  int c = d >> 8, pd = d & 255;
  int py = pd >> 4, px = pd & 15;
  int gy = p / 14, gx = p - gy * 14;
  size_t src = ((size_t)(b * 3 + c) * 224 + gy * 16 + py) * 224 + gx * 16 + px;
  pt[i] = f2bf(x[src]);
}

// h[b][0][:] = cls + pos[0]
__global__ __launch_bounds__(256) void clspos_k(const float* __restrict__ cls,
                                                const float* __restrict__ pos,
                                                float* __restrict__ h) {
  int i = blockIdx.x * 256 + threadIdx.x;  // 32*768
  int b = i / 768, e = i - b * 768;
  h[(size_t)b * 197 * 768 + e] = cls[e] + pos[e];
}

// ---------------- epilogue helper ----------------
template <int EPI>
DEV void epi_store(float v, int grow, int gcol, u16* outb, int ldo,
                   float* outf, const float* pos) {
  if constexpr (EPI == 0) {
    outb[(size_t)grow * ldo + gcol] = f2bf(v);
  } else if constexpr (EPI == 1) {
    // gelu(x) ~= x * sigmoid(1.5957691(x + 0.044715 x^3))
    float u = __expf(-1.5957691216f * (v + 0.044715f * v * v * v));
    outb[(size_t)grow * ldo + gcol] = f2bf(v / (1.f + u));
  } else if constexpr (EPI == 2) {
    outf[(size_t)grow * ldo + gcol] += v;
  } else {
    int b = grow / 196, p = grow - b * 196;
    outf[(size_t)(grow + b + 1) * 768 + gcol] =
        v + pos[(size_t)(p + 1) * 768 + gcol];
  }
}

// -------- gemmK64: C[M,N] = A[M,K] @ Bt[N,K], 128x128 tile, BK=64 ---------
// 8 waves (2m x 4n), 2-phase double-buffer, global_load_lds(16B), both-sides
// chunk-XOR swizzle, tm-major flat + XCD block swizzle. (mlp1)
template <int EPI>
__global__ __launch_bounds__(512) void gemmK64(
    const u16* __restrict__ A, int lda, const u16* __restrict__ Bt, int ldb,
    const float* __restrict__ bias, u16* __restrict__ outb, int ldo,
    float* __restrict__ outf, const float* __restrict__ pos, int M, int N,
    int K) {
  __shared__ __align__(16) u16 Ak[2][128 * 64];
  __shared__ __align__(16) u16 Bk[2][128 * 64];
  const int tid = threadIdx.x;
  const int lane = tid & 63, wid = tid >> 6;
  const int wm = wid >> 2, wn = wid & 3;
  const int lg = lane >> 4, lr = lane & 15;
  const int nwg = gridDim.x * gridDim.y;
  const int wg = xcd_swz(blockIdx.y * gridDim.x + blockIdx.x, nwg);
  const int tn = wg % gridDim.x, tm = wg / gridDim.x;

  const int r8 = lane >> 3, c8 = lane & 7;
  const int swc = (c8 ^ r8) << 3;  // source chunk pre-swizzled (rule #21)
  const u16* aS = A + (size_t)(tm * 128 + wid * 16 + r8) * lda + swc;
  const u16* bS = Bt + (size_t)(tn * 128 + wid * 16 + r8) * ldb + swc;

  auto stage = [&](int buf, int kt) {  // 4 glds16/wave
    const u16* ak = aS + kt * 64;
    const u16* bk = bS + kt * 64;
    u16* ad = &Ak[buf][wid * 1024];
    u16* bd = &Bk[buf][wid * 1024];
    glds16(ak, ad);
    glds16(ak + (size_t)8 * lda, ad + 512);
    glds16(bk, bd);
    glds16(bk + (size_t)8 * ldb, bd + 512);
  };

  f32x4 acc[4][2] = {};
  auto compute = [&](int buf) {
#pragma unroll
    for (int ks = 0; ks < 2; ++ks) {
      const int pc = (ks << 2) | lg;
      const int po = ((pc ^ (lr & 7)) << 3);  // read-side un-swizzle
      short8 af[4], bf2[2];
#pragma unroll
      for (int i = 0; i < 4; ++i)
        af[i] = *(const short8*)(&Ak[buf][(wm * 64 + i * 16 + lr) * 64 + po]);
#pragma unroll
      for (int i = 0; i < 2; ++i)
        bf2[i] = *(const short8*)(&Bk[buf][(wn * 32 + i * 16 + lr) * 64 + po]);
#pragma unroll
      for (int mi = 0; mi < 4; ++mi)
#pragma unroll
        for (int ni = 0; ni < 2; ++ni)
          acc[mi][ni] = __builtin_amdgcn_mfma_f32_16x16x32_bf16(
              af[mi], bf2[ni], acc[mi][ni], 0, 0, 0);
    }
  };

  const int nk = K >> 6;
  int cur = 0;
  stage(0, 0);
  __syncthreads();
  for (int kt = 0; kt < nk - 1; ++kt) {
    stage(cur ^ 1, kt + 1);  // next K-tile in flight under compute
    compute(cur);
    __syncthreads();
    cur ^= 1;
  }
  compute(cur);

#pragma unroll
  for (int mi = 0; mi < 4; ++mi)
#pragma unroll
    for (int ni = 0; ni < 2; ++ni)
#pragma unroll
      for (int r = 0; r < 4; ++r) {
        int grow = tm * 128 + wm * 64 + mi * 16 + lg * 4 + r;
        int gcol = tn * 128 + wn * 32 + ni * 16 + lr;
        if (grow < M)
          epi_store<EPI>(acc[mi][ni][r] + bias[gcol], grow, gcol, outb, ldo,
                         outf, pos);
      }
}

// -------- gemmW2: C[M,N] = A[M,K] @ Bt[N,K], 128(M) x 256(N), BK=32 -------
// 8 waves (2m x 4n, wave tile 64x64), 2-phase double-buffer, 48KB LDS ->
// 3 blocks/CU. (qkv direct; mlp2 split-K via EPI 4: bf16 partial planes.)
template <int EPI>
__global__ __launch_bounds__(512) void gemmW2(
    const u16* __restrict__ A, int lda, const u16* __restrict__ Bt, int ldb,
    const float* __restrict__ bias, u16* __restrict__ outb, int ldo,
    float* __restrict__ outf, int M, int K) {
  __shared__ __align__(16) u16 Ak[2][128 * 32];  // 16 KB
  __shared__ __align__(16) u16 Bk[2][256 * 32];  // 32 KB
  const int tid = threadIdx.x;
  const int lane = tid & 63, wid = tid >> 6;
  const int wm = wid >> 2, wn = wid & 3;
  const int lg = lane >> 4, lr = lane & 15;
  const int nwg = gridDim.x * gridDim.y;
  const int wg = xcd_swz(blockIdx.y * gridDim.x + blockIdx.x, nwg);
  const int tn = wg % gridDim.x, tm = wg / gridDim.x;
  const size_t koff = (EPI == 4) ? (size_t)blockIdx.z * K : 0;

  const int sr = lane >> 2;
  const int sc4 = (((lane & 3) ^ ((lane >> 3) & 3)) << 3);
  const u16* aSrc = A + (size_t)(tm * 128 + wid * 16 + sr) * lda + koff + sc4;
  const u16* bSrc = Bt + (size_t)(tn * 256 + wid * 32 + sr) * ldb + koff + sc4;
  const size_t bRow16 = (size_t)16 * ldb;

  auto stage = [&](int buf, int kt) {  // 3 glds16/wave
    const u16* ak = aSrc + kt * 32;
    const u16* bk = bSrc + kt * 32;
    glds16(ak, &Ak[buf][wid * 16 * 32]);
    u16* bd = &Bk[buf][wid * 32 * 32];
    glds16(bk, bd);
    glds16(bk + bRow16, bd + 512);
  };

  const int rp = (lg ^ ((lr >> 1) & 3)) << 3;  // read-side un-swizzle
  f32x4 acc[4][4] = {};
  auto compute = [&](int buf) {
    short8 af[4], bf[4];
#pragma unroll
    for (int i = 0; i < 4; ++i)
      af[i] = *(const short8*)(&Ak[buf][(wm * 64 + i * 16 + lr) * 32 + rp]);
#pragma unroll
    for (int i = 0; i < 4; ++i)
      bf[i] = *(const short8*)(&Bk[buf][(wn * 64 + i * 16 + lr) * 32 + rp]);
#pragma unroll
    for (int mi = 0; mi < 4; ++mi)
#pragma unroll
      for (int ni = 0; ni < 4; ++ni)
        acc[mi][ni] = __builtin_amdgcn_mfma_f32_16x16x32_bf16(
            af[mi], bf[ni], acc[mi][ni], 0, 0, 0);
  };

  const int nk = K >> 5;
  int cur = 0;
  stage(0, 0);
  __syncthreads();
  for (int kt = 0; kt < nk - 1; ++kt) {
    stage(cur ^ 1, kt + 1);  // next K-tile in flight under compute
    compute(cur);
    __syncthreads();
    cur ^= 1;
  }
  compute(cur);

#pragma unroll
  for (int mi = 0; mi < 4; ++mi)
#pragma unroll
    for (int ni = 0; ni < 4; ++ni)
#pragma unroll
      for (int r = 0; r < 4; ++r) {
        int grow = tm * 128 + wm * 64 + mi * 16 + lg * 4 + r;
        int gcol = tn * 256 + wn * 64 + ni * 16 + lr;
        if (grow < M) {
          if constexpr (EPI == 4) {
            // bf16 split-K partial plane (RNE)
            outb[(size_t)blockIdx.z * M * ldo + (size_t)grow * ldo + gcol] =
                f2bf(acc[mi][ni][r]);
          } else {
            epi_store<EPI>(acc[mi][ni][r] + bias[gcol], grow, gcol, outb, ldo,
                           outf, nullptr);
          }
        }
      }
}

// redK: h += bias + Cp[0..2]  (bf16 planes; last-layer reduce)
__global__ __launch_bounds__(256) void redK(const u16* __restrict__ Cp,
                                            const float* __restrict__ bias,
                                            float* __restrict__ h) {
  size_t i = ((size_t)blockIdx.x * 256 + threadIdx.x) * 4;  // < 6304*768
  ushort4 q0 = *(const ushort4*)(Cp + i);
  ushort4 q1 = *(const ushort4*)(Cp + 6304ull * 768 + i);
  ushort4 q2 = *(const ushort4*)(Cp + 2ull * 6304 * 768 + i);
  float4 hv = *(const float4*)(h + i);
  float4 bv = *(const float4*)(bias + (int)(i % 768));
  hv.x += bf2f(q0.x) + bf2f(q1.x) + bf2f(q2.x) + bv.x;
  hv.y += bf2f(q0.y) + bf2f(q1.y) + bf2f(q2.y) + bv.y;
  hv.z += bf2f(q0.z) + bf2f(q1.z) + bf2f(q2.z) + bv.z;
  hv.w += bf2f(q0.w) + bf2f(q1.w) + bf2f(q2.w) + bv.w;
  *(float4*)(h + i) = hv;
}

// redln: h' = h + bias + Cp[0..2] (bf16 planes); h = h'; y = ln(h') bf16.
__global__ __launch_bounds__(256) void redln_k(
    const u16* __restrict__ Cp, const float* __restrict__ bias,
    float* __restrict__ h, const float* __restrict__ lnw,
    const float* __restrict__ lnb, u16* __restrict__ y) {
  const int lane = threadIdx.x & 63, wv = threadIdx.x >> 6;
  const int r = blockIdx.x * 4 + wv;
  const size_t base = (size_t)r * 768;
  float4 a[3];
  float s = 0.f, q = 0.f;
#pragma unroll
  for (int i = 0; i < 3; ++i) {
    const int off = i * 256 + lane * 4;
    float4 hv = *(const float4*)(h + base + off);
    ushort4 q0 = *(const ushort4*)(Cp + base + off);
    ushort4 q1 = *(const ushort4*)(Cp + 6304ull * 768 + base + off);
    ushort4 q2 = *(const ushort4*)(Cp + 2ull * 6304 * 768 + base + off);
    float4 bv = *(const float4*)(bias + off);
    a[i].x = hv.x + bf2f(q0.x) + bf2f(q1.x) + bf2f(q2.x) + bv.x;
    a[i].y = hv.y + bf2f(q0.y) + bf2f(q1.y) + bf2f(q2.y) + bv.y;
    a[i].z = hv.z + bf2f(q0.z) + bf2f(q1.z) + bf2f(q2.z) + bv.z;
    a[i].w = hv.w + bf2f(q0.w) + bf2f(q1.w) + bf2f(q2.w) + bv.w;
    s += a[i].x + a[i].y + a[i].z + a[i].w;
    q += a[i].x * a[i].x + a[i].y * a[i].y + a[i].z * a[i].z +
         a[i].w * a[i].w;
  }
  s = wred_sum(s);
  q = wred_sum(q);
  float mu = s * (1.f / 768.f);
  float var = q * (1.f / 768.f) - mu * mu;
  float rs = rsqrtf(var + 1e-5f);
#pragma unroll
  for (int i = 0; i < 3; ++i) {
    const int off = i * 256 + lane * 4;
    *(float4*)(h + base + off) = a[i];
    float4 wv4 = *(const float4*)(lnw + off);
    float4 bv4 = *(const float4*)(lnb + off);
    ushort4 o;
    o.x = f2bf((a[i].x - mu) * rs * wv4.x + bv4.x);
    o.y = f2bf((a[i].y - mu) * rs * wv4.y + bv4.y);
    o.z = f2bf((a[i].z - mu) * rs * wv4.z + bv4.z);
    o.w = f2bf((a[i].w - mu) * rs * wv4.w + bv4.w);
    *(ushort4*)(y + base + off) = o;
  }
}

// -------- gemmP: BMx128 tile, BK=32, 4 waves, 2-phase (patch + proj) ------
template <int EPI, int BM>
__global__ __launch_bounds__(256) void gemmP(
    const u16* __restrict__ A, int lda, const u16* __restrict__ Bt, int ldb,
    const float* __restrict__ bias, u16* __restrict__ outb, int ldo,
    float* __restrict__ outf, const float* __restrict__ pos, int M, int N,
    int K) {
  constexpr int MI = BM / 32;  // acc rows per wave (2 or 4)
  __shared__ __align__(16) u16 Ak[2][BM * 32];
  __shared__ __align__(16) u16 Bk[2][128 * 32];
  const int tid = threadIdx.x;
  const int lane = tid & 63, wid = tid >> 6;
  const int wm = wid >> 1, wn = wid & 1;
  const int lg = lane >> 4, lr = lane & 15;
  const int nwg = gridDim.x * gridDim.y;
  const int wg = xcd_swz(blockIdx.y * gridDim.x + blockIdx.x, nwg);
  const int tn = wg % gridDim.x, tm = wg / gridDim.x;

  const int sr = lane >> 2;
  const int sc4 = (((lane & 3) ^ ((lane >> 3) & 3)) << 3);
  const u16* aSrc = A + (size_t)(tm * BM + wid * (BM / 4) + sr) * lda + sc4;
  const u16* bSrc = Bt + (size_t)(tn * 128 + wid * 32 + sr) * ldb + sc4;
  const size_t aRow16 = (size_t)16 * lda, bRow16 = (size_t)16 * ldb;

  auto stage = [&](int buf, int kt) {
    const u16* ak = aSrc + kt * 32;
    const u16* bk = bSrc + kt * 32;
    u16* ad = &Ak[buf][wid * (BM / 4) * 32];
    u16* bd = &Bk[buf][wid * 1024];
    glds16(ak, ad);
    if constexpr (BM == 128) glds16(ak + aRow16, ad + 512);
    glds16(bk, bd);
    glds16(bk + bRow16, bd + 512);
  };

  const int rp = (lg ^ ((lr >> 1) & 3)) << 3;
  f32x4 acc[MI][4] = {};
  auto compute = [&](int buf) {
    short8 af[MI], bfr[4];
#pragma unroll
    for (int i = 0; i < MI; ++i)
      af[i] =
          *(const short8*)(&Ak[buf][(wm * (BM / 2) + i * 16 + lr) * 32 + rp]);
#pragma unroll
    for (int i = 0; i < 4; ++i)
      bfr[i] = *(const short8*)(&Bk[buf][(wn * 64 + i * 16 + lr) * 32 + rp]);
#pragma unroll
    for (int mi = 0; mi < MI; ++mi)
#pragma unroll
      for (int ni = 0; ni < 4; ++ni)
        acc[mi][ni] = __builtin_amdgcn_mfma_f32_16x16x32_bf16(
            af[mi], bfr[ni], acc[mi][ni], 0, 0, 0);
  };

  const int nk = K >> 5;
  int cur = 0;
  stage(0, 0);
  __syncthreads();
  for (int kt = 0; kt < nk - 1; ++kt) {
    stage(cur ^ 1, kt + 1);
    compute(cur);
    __syncthreads();
    cur ^= 1;
  }
  compute(cur);

#pragma unroll
  for (int mi = 0; mi < MI; ++mi)
#pragma unroll
    for (int ni = 0; ni < 4; ++ni)
#pragma unroll
      for (int r = 0; r < 4; ++r) {
        int grow = tm * BM + wm * (BM / 2) + mi * 16 + lg * 4 + r;
        int gcol = tn * 128 + wn * 64 + ni * 16 + lr;
        if (grow < M)
          epi_store<EPI>(acc[mi][ni][r] + bias[gcol], grow, gcol, outb, ldo,
                         outf, pos);
      }
}

// ---------------- attention ----------------
// fused QK^T + softmax with LDS-staged K (chunk-XOR swizzled). 4 waves per
// (b,h); wave w handles q-tiles w, w+4, w+8, w+12. P bf16, stride 224,
// cols 197..223 zeroed.
__global__ __launch_bounds__(256) void qksm_k(const u16* __restrict__ qkv,
                                              u16* __restrict__ P) {
  __shared__ __align__(16) u16 Ks[224 * 64];  // 28 KB
  const int bh = blockIdx.x;  // b*12+h
  const int tid = threadIdx.x;
  const int lane = tid & 63, w = tid >> 6;
  const int lg = lane >> 4, lr = lane & 15;
  const int b = bh / 12, hh = bh - b * 12;
  const u16* kbase = qkv + (size_t)b * 197 * 2304 + 768 + hh * 64;
  // stage K rows 0..223 (chunk c -> dest row c>>3, chunk c&7; source chunk
  // pre-swizzled by dest row, rule #21)
#pragma unroll
  for (int it = 0; it < 7; ++it) {
    const int c0 = it * 256 + w * 64;  // wave-uniform
    const int c = c0 + lane;
    const int rd = c >> 3, c8 = c & 7;
    const int rc = rd > 196 ? 196 : rd;
    glds16(kbase + (size_t)rc * 2304 + ((c8 ^ (rd & 7)) << 3), &Ks[c0 * 8]);
  }
  __syncthreads();

  const u16* base = qkv + (size_t)b * 197 * 2304 + hh * 64;
  const bool kval12 = (12 * 16 + lr) <= 196;
  for (int qt = w; qt < 13; qt += 4) {
    int qrow = qt * 16 + lr;
    if (qrow > 196) qrow = 196;
    const u16* qp = base + (size_t)qrow * 2304 + lg * 8;
    short8 a0 = *(const short8*)(qp);
    short8 a1 = *(const short8*)(qp + 32);
    f32x4 c[13];
#pragma unroll
    for (int kt = 0; kt < 13; ++kt) {
      const int krow = kt * 16 + lr;  // <= 207 < 224
      short8 b0 =
          *(const short8*)(&Ks[krow * 64 + ((lg ^ (krow & 7)) << 3)]);
      short8 b1 =
          *(const short8*)(&Ks[krow * 64 + (((4 + lg) ^ (krow & 7)) << 3)]);
      f32x4 t = {0.f, 0.f, 0.f, 0.f};
      t = __builtin_amdgcn_mfma_f32_16x16x32_bf16(a0, b0, t, 0, 0, 0);
      c[kt] = __builtin_amdgcn_mfma_f32_16x16x32_bf16(a1, b1, t, 0, 0, 0);
    }
    float mr[4], sr_[4];
#pragma unroll
    for (int r = 0; r < 4; ++r) {
      float mm = -3.4e38f;
#pragma unroll
      for (int kt = 0; kt < 13; ++kt)
        if (kt < 12 || kval12) mm = fmaxf(mm, c[kt][r] * 0.125f);
#pragma unroll
      for (int o = 1; o < 16; o <<= 1) mm = fmaxf(mm, __shfl_xor(mm, o, 64));
      mr[r] = mm;
    }
#pragma unroll
    for (int r = 0; r < 4; ++r) {
      float s = 0.f;
#pragma unroll
      for (int kt = 0; kt < 13; ++kt) {
        float e =
            (kt < 12 || kval12) ? __expf(c[kt][r] * 0.125f - mr[r]) : 0.f;
        c[kt][r] = e;
        s += e;
      }
#pragma unroll
      for (int o = 1; o < 16; o <<= 1) s += __shfl_xor(s, o, 64);
      sr_[r] = 1.0f / s;
    }
    u16* pb = P + (size_t)bh * 197 * 224;
#pragma unroll
    for (int r = 0; r < 4; ++r) {
      int q = qt * 16 + lg * 4 + r;
      if (q < 197) {
#pragma unroll
        for (int kt = 0; kt < 13; ++kt)
          pb[(size_t)q * 224 + kt * 16 + lr] = f2bf(c[kt][r] * sr_[r]);
        pb[(size_t)q * 224 + 208 + lr] = 0;  // pad cols 208..223
      }
    }
  }
}

// o[b][q][h*64+d] = sum_k P[bh][q][k](bf16) * V[b][k][h][d]; V via LDS
__global__ __launch_bounds__(256) void pv_k(const u16* __restrict__ qkv,
                                            const u16* __restrict__ P,
                                            u16* __restrict__ o) {
  __shared__ __align__(16) u16 Vs[224 * 64];  // 28 KB
  const int bh = blockIdx.x;
  const int b = bh / 12, hh = bh - b * 12;
  const int tid = threadIdx.x;
  const int lane = tid & 63, ct = tid >> 6;  // wave = 16-col tile of HD
  const int lg = lane >> 4, lr = lane & 15;
  const u16* vhead = qkv + (size_t)b * 197 * 2304 + 1536 + hh * 64;
#pragma unroll
  for (int it = 0; it < 7; ++it) {
    const int c0 = it * 256 + ct * 64;  // wave-uniform chunk base
    const int c = c0 + lane;
    int row = c >> 3;
    if (row > 196) row = 196;
    glds16(vhead + (size_t)row * 2304 + (c & 7) * 8, &Vs[c0 * 8]);
  }
  __syncthreads();
  short8 vf[7];
#pragma unroll
  for (int ks = 0; ks < 7; ++ks) {
    ushort8 t;
#pragma unroll
    for (int j = 0; j < 8; ++j) {
      int kk = ks * 32 + lg * 8 + j;
      t[j] = Vs[kk * 64 + ct * 16 + lr];
    }
    vf[ks] = __builtin_bit_cast(short8, t);
  }
  const u16* pbase = P + (size_t)bh * 197 * 224;
  u16* ob = o + (size_t)b * 197 * 768 + hh * 64 + ct * 16;
  for (int qt = 0; qt < 13; ++qt) {
    int q = qt * 16 + lr;
    if (q > 196) q = 196;
    const u16* pp = pbase + (size_t)q * 224 + lg * 8;
    f32x4 acc = {0.f, 0.f, 0.f, 0.f};
#pragma unroll
    for (int ks = 0; ks < 7; ++ks) {
      short8 af = *(const short8*)(pp + ks * 32);
      acc = __builtin_amdgcn_mfma_f32_16x16x32_bf16(af, vf[ks], acc, 0, 0, 0);
    }
#pragma unroll
    for (int r = 0; r < 4; ++r) {
      int qq = qt * 16 + lg * 4 + r;
      if (qq < 197) ob[(size_t)qq * 768 + lr] = f2bf(acc[r]);
    }
  }
}

// ---------------- layernorm: 4 rows/block, 64 lanes/row, float4 ----------
__global__ __launch_bounds__(256) void ln_k(const float* __restrict__ x,
                                            const float* __restrict__ w,
                                            const float* __restrict__ bb,
                                            u16* __restrict__ y) {
  const int lane = threadIdx.x & 63, wv = threadIdx.x >> 6;
  const int r = blockIdx.x * 4 + wv;
  const float* xr = x + (size_t)r * 768;
  float4 v[3];
  float s = 0.f, q = 0.f;
#pragma unroll
  for (int i = 0; i < 3; ++i) {
    v[i] = *(const float4*)(xr + i * 256 + lane * 4);
    s += v[i].x + v[i].y + v[i].z + v[i].w;
    q += v[i].x * v[i].x + v[i].y * v[i].y + v[i].z * v[i].z +
         v[i].w * v[i].w;
  }
  s = wred_sum(s);
  q = wred_sum(q);
  float mu = s * (1.f / 768.f);
  float var = q * (1.f / 768.f) - mu * mu;
  float rs = rsqrtf(var + 1e-5f);
  u16* yr = y + (size_t)r * 768;
#pragma unroll
  for (int i = 0; i < 3; ++i) {
    float4 wv4 = *(const float4*)(w + i * 256 + lane * 4);
    float4 bv4 = *(const float4*)(bb + i * 256 + lane * 4);
    ushort4 o;
    o.x = f2bf((v[i].x - mu) * rs * wv4.x + bv4.x);
    o.y = f2bf((v[i].y - mu) * rs * wv4.y + bv4.y);
    o.z = f2bf((v[i].z - mu) * rs * wv4.z + bv4.z);
    o.w = f2bf((v[i].w - mu) * rs * wv4.w + bv4.w);
    *(ushort4*)(yr + i * 256 + lane * 4) = o;
  }
}

// ---------------- final LN(cls row) + head ----------------
__global__ __launch_bounds__(256) void head_k(
    const float* __restrict__ h, const float* __restrict__ lnw,
    const float* __restrict__ lnb, const float* __restrict__ hw,
    const float* __restrict__ hb, float* __restrict__ out) {
  const int b = blockIdx.x, tid = threadIdx.x;
  const float* xr = h + (size_t)b * 197 * 768;
  float v0 = xr[tid], v1 = xr[tid + 256], v2 = xr[tid + 512];
  float s = v0 + v1 + v2;
  float q = v0 * v0 + v1 * v1 + v2 * v2;
  s = wred_sum(s);
  q = wred_sum(q);
  __shared__ float ss[4], qs[4];
  int lane = tid & 63, wid = tid >> 6;
  if (lane == 0) { ss[wid] = s; qs[wid] = q; }
  __syncthreads();
  float S = ss[0] + ss[1] + ss[2] + ss[3];
  float Q = qs[0] + qs[1] + qs[2] + qs[3];
  float mu = S * (1.f / 768.f);
  float var = Q * (1.f / 768.f) - mu * mu;
  float rs = rsqrtf(var + 1e-5f);
  __shared__ float yb[768];
  yb[tid] = (v0 - mu) * rs * lnw[tid] + lnb[tid];
  yb[tid + 256] = (v1 - mu) * rs * lnw[tid + 256] + lnb[tid + 256];
  yb[tid + 512] = (v2 - mu) * rs * lnw[tid + 512] + lnb[tid + 512];
  __syncthreads();
  float p[10] = {};
  for (int e = tid; e < 768; e += 256) {
    float yv = yb[e];
#pragma unroll
    for (int n = 0; n < 10; ++n) p[n] += yv * hw[(size_t)e * 10 + n];
  }
#pragma unroll
  for (int n = 0; n < 10; ++n) p[n] = wred_sum(p[n]);
  __shared__ float red[4][10];
  if (lane == 0)
#pragma unroll
    for (int n = 0; n < 10; ++n) red[wid][n] = p[n];
  __syncthreads();
  if (tid < 10)
    out[b * 10 + tid] =
        red[0][tid] + red[1][tid] + red[2][tid] + red[3][tid] + hb[tid];
}

// ---------------- host orchestration ----------------
extern "C" void kernel_launch(void* const* d_in, const int* in_sizes, int n_in,
                              void* d_out, int out_size, void* d_ws,
                              size_t ws_size, hipStream_t stream) {
  const float* x = (const float*)d_in[0];
  const float* conv_w = (const float*)d_in[1];
  const float* conv_b = (const float*)d_in[2];
  const float* cls = (const float*)d_in[3];
  const float* pos = (const float*)d_in[4];
  const float* ln1w = (const float*)d_in[5];
  const float* ln1b = (const float*)d_in[6];
  const float* qkvw = (const float*)d_in[7];
  const float* qkvbias = (const float*)d_in[8];
  const float* projw = (const float*)d_in[9];
  const float* projb = (const float*)d_in[10];
  const float* ln2w = (const float*)d_in[11];
  const float* ln2b = (const float*)d_in[12];
  const float* w1f = (const float*)d_in[13];
  const float* b1 = (const float*)d_in[14];
  const float* w2f = (const float*)d_in[15];
  const float* b2 = (const float*)d_in[16];
  const float* lnfw = (const float*)d_in[17];
  const float* lnfb = (const float*)d_in[18];
  const float* headw = (const float*)d_in[19];
  const float* headb = (const float*)d_in[20];
  float* out = (float*)d_out;

  // workspace layout; A-side buffers padded to 6400 rows (tiles read past
  // M=6304; garbage rows are finite, never reach guarded outputs)
  char* p = (char*)d_ws;
  auto take = [&](size_t bytes) {
    char* q = p;
    p += (bytes + 255) & ~(size_t)255;
    return q;
  };
  u16* wq = (u16*)take(12ull * 768 * 2304 * 2);   // [N=2304][K=768] per layer
  u16* wpj = (u16*)take(12ull * 768 * 768 * 2);   // [768][768]
  u16* w1 = (u16*)take(12ull * 768 * 3072 * 2);   // [3072][768]
  u16* w2 = (u16*)take(12ull * 3072 * 768 * 2);   // [768][3072]
  u16* wc = (u16*)take(768ull * 768 * 2);         // conv_w already [N][K]
  float* h = (float*)take(6304ull * 768 * 4);
  u16* y = (u16*)take(6400ull * 768 * 2);
  u16* qkv = (u16*)take(6400ull * 2304 * 2);
  u16* ob = (u16*)take(6400ull * 768 * 2);
  u16* mlpb = (u16*)take(6400ull * 3072 * 2);  // also holds patches at start
  u16* P = (u16*)take(384ull * 197 * 224 * 2);
  u16* skPb = (u16*)take(3ull * 6304 * 768 * 2);  // 3 bf16 split-K planes
  (void)ws_size; (void)in_sizes; (void)n_in; (void)out_size;

  // weight conversion fp32 -> bf16, transposed to [N][K]
  tpose_k<<<dim3(72, 24, 12), 256, 0, stream>>>(qkvw, wq, 768, 2304);
  tpose_k<<<dim3(24, 24, 12), 256, 0, stream>>>(projw, wpj, 768, 768);
  tpose_k<<<dim3(96, 24, 12), 256, 0, stream>>>(w1f, w1, 768, 3072);
  tpose_k<<<dim3(24, 96, 12), 256, 0, stream>>>(w2f, w2, 3072, 768);
  cvt4_k<<<576, 256, 0, stream>>>(conv_w, wc, 768 * 768 / 4);

  // patch embed
  patch_k<<<6272 * 768 / 256, 256, 0, stream>>>(x, mlpb);
  gemmP<3, 64><<<dim3(6, 98), 256, 0, stream>>>(mlpb, 768, wc, 768, conv_b,
                                                nullptr, 0, h, pos, 6272, 768,
                                                768);
  clspos_k<<<32 * 768 / 256, 256, 0, stream>>>(cls, pos, h);

  // layer 0's ln1 standalone; thereafter fused into redln
  ln_k<<<1576, 256, 0, stream>>>(h, ln1w, ln1b, y);
  for (int i = 0; i < 12; ++i) {
    gemmW2<0><<<dim3(9, 50), 512, 0, stream>>>(
        y, 768, wq + (size_t)i * 768 * 2304, 768, qkvbias + i * 2304, qkv,
        2304, nullptr, 6304, 768);
    qksm_k<<<384, 256, 0, stream>>>(qkv, P);
    pv_k<<<384, 256, 0, stream>>>(qkv, P, ob);
    gemmP<2, 64><<<dim3(6, 99), 256, 0, stream>>>(
        ob, 768, wpj + (size_t)i * 768 * 768, 768, projb + i * 768, nullptr,
        768, h, nullptr, 6304, 768, 768);
    ln_k<<<1576, 256, 0, stream>>>(h, ln2w + i * 768, ln2b + i * 768, y);
    gemmK64<1><<<dim3(24, 50), 512, 0, stream>>>(
        y, 768, w1 + (size_t)i * 768 * 3072, 768, b1 + i * 3072, mlpb, 3072,
        nullptr, nullptr, 6304, 3072, 768);
    // mlp2: split-K x3 (KC=1024) on 128x256 tile -> 450 blocks, bf16 planes
    gemmW2<4><<<dim3(3, 50, 3), 512, 0, stream>>>(
        mlpb, 3072, w2 + (size_t)i * 3072 * 768, 3072, nullptr, skPb, 768,
        nullptr, 6304, 1024);
    if (i < 11) {
      redln_k<<<1576, 256, 0, stream>>>(skPb, b2 + i * 768, h,
                                        ln1w + (i + 1) * 768,
                                        ln1b + (i + 1) * 768, y);
    } else {
      redK<<<4728, 256, 0, stream>>>(skPb, b2 + i * 768, h);
    }
  }

  head_k<<<32, 256, 0, stream>>>(h, lnfw, lnfb, headw, headb, out);
}

// Round 17
// 2788.221 us; speedup vs baseline: 1.2755x; 1.0189x over previous
//
#include <hip/hip_runtime.h>

// ViT-B/16 forward, B=32, S=197, E=768, H=12, HD=64, MLP=3072, DEPTH=12.
// Round 17: R16 (best, 2841us) + fully fused attention: attn_k replaces
// qksm_k+pv_k. K (208 rows, swizzled) + V (224 rows) staged once; 4 waves
// each run QK^T -> softmax -> P to wave-private LDS scratch -> PV with no
// inter-wave sync after the stage barrier. LDS exactly 80KB (2 blocks/CU).
// P never touches global (-68 MB/layer L2 traffic). GEMMs/LN frozen.

typedef __attribute__((ext_vector_type(8))) short short8;
typedef __attribute__((ext_vector_type(8))) unsigned short ushort8;
typedef __attribute__((ext_vector_type(4))) float f32x4;
typedef unsigned short u16;

#define DEV __device__ __forceinline__

DEV u16 f2bf(float f) {
  unsigned int u = __builtin_bit_cast(unsigned int, f);
  u += 0x7fffu + ((u >> 16) & 1u);
  return (u16)(u >> 16);
}
DEV float bf2f(u16 v) {
  return __builtin_bit_cast(float, (unsigned int)v << 16);
}
DEV float wred_sum(float v) {
  for (int o = 32; o; o >>= 1) v += __shfl_xor(v, o, 64);
  return v;
}
DEV void glds16(const void* gp, void* lp) {
  __builtin_amdgcn_global_load_lds(
      (const __attribute__((address_space(1))) void*)gp,
      (__attribute__((address_space(3))) void*)lp, 16, 0, 0);
}
// m204 bijective XCD swizzle: contiguous wg chunk per XCD
DEV int xcd_swz(int flat, int nwg) {
  int q = nwg >> 3, r = nwg & 7;
  int x = flat & 7, o = flat >> 3;
  return (x < r ? x * (q + 1) : r * (q + 1) + (x - r) * q) + o;
}

// ---------------- weight conversion ----------------
__global__ __launch_bounds__(256) void cvt4_k(const float* __restrict__ s,
                                              u16* __restrict__ d, long n4) {
  long i = (long)blockIdx.x * 256 + threadIdx.x;
  if (i >= n4) return;
  float4 v = ((const float4*)s)[i];
  ushort4 o;
  o.x = f2bf(v.x); o.y = f2bf(v.y); o.z = f2bf(v.z); o.w = f2bf(v.w);
  ((ushort4*)d)[i] = o;
}

// fp32 [K][N] (blockIdx.z selects layer) -> bf16 [N][K], tiled 32x32
__global__ __launch_bounds__(256) void tpose_k(const float* __restrict__ s,
                                               u16* __restrict__ d, int K,
                                               int N) {
  __shared__ float t[32][33];
  const int bx = blockIdx.x;  // n tile
  const int by = blockIdx.y;  // k tile
  const size_t base = (size_t)blockIdx.z * K * N;
  const int c = threadIdx.x & 31, r0 = threadIdx.x >> 5;
#pragma unroll
  for (int i = 0; i < 4; ++i) {
    int r = r0 + i * 8;
    t[r][c] = s[base + (size_t)(by * 32 + r) * N + bx * 32 + c];
  }
  __syncthreads();
#pragma unroll
  for (int i = 0; i < 4; ++i) {
    int r = r0 + i * 8;
    d[base + (size_t)(bx * 32 + r) * K + by * 32 + c] = f2bf(t[c][r]);
  }
}

// patches[b][p][d] <- x[b][c][gy*16+py][gx*16+px], bf16
__global__ __launch_bounds__(256) void patch_k(const float* __restrict__ x,
                                               u16* __restrict__ pt) {
  int i = blockIdx.x * 256 + threadIdx.x;  // 6272*768 exactly
  int d = i % 768;
  int bp = i / 768;
  int p = bp % 196, b = bp / 196;
  int c = d >> 8, pd = d & 255;
  int py = pd >> 4, px = pd & 15;
  int gy = p / 14, gx = p - gy * 14;
  size_t src = ((size_t)(b * 3 + c) * 224 + gy * 16 + py) * 224 + gx * 16 + px;
  pt[i] = f2bf(x[src]);
}

// h[b][0][:] = cls + pos[0]
__global__ __launch_bounds__(256) void clspos_k(const float* __restrict__ cls,
                                                const float* __restrict__ pos,
                                                float* __restrict__ h) {
  int i = blockIdx.x * 256 + threadIdx.x;  // 32*768
  int b = i / 768, e = i - b * 768;
  h[(size_t)b * 197 * 768 + e] = cls[e] + pos[e];
}

// ---------------- epilogue helper ----------------
template <int EPI>
DEV void epi_store(float v, int grow, int gcol, u16* outb, int ldo,
                   float* outf, const float* pos) {
  if constexpr (EPI == 0) {
    outb[(size_t)grow * ldo + gcol] = f2bf(v);
  } else if constexpr (EPI == 1) {
    // gelu(x) ~= x * sigmoid(1.5957691(x + 0.044715 x^3))
    float u = __expf(-1.5957691216f * (v + 0.044715f * v * v * v));
    outb[(size_t)grow * ldo + gcol] = f2bf(v / (1.f + u));
  } else if constexpr (EPI == 2) {
    outf[(size_t)grow * ldo + gcol] += v;
  } else {
    int b = grow / 196, p = grow - b * 196;
    outf[(size_t)(grow + b + 1) * 768 + gcol] =
        v + pos[(size_t)(p + 1) * 768 + gcol];
  }
}

// -------- gemmK64: C[M,N] = A[M,K] @ Bt[N,K], 128x128 tile, BK=64 ---------
// 8 waves (2m x 4n), 2-phase double-buffer, global_load_lds(16B), both-sides
// chunk-XOR swizzle, tm-major flat + XCD block swizzle. (mlp1)
template <int EPI>
__global__ __launch_bounds__(512) void gemmK64(
    const u16* __restrict__ A, int lda, const u16* __restrict__ Bt, int ldb,
    const float* __restrict__ bias, u16* __restrict__ outb, int ldo,
    float* __restrict__ outf, const float* __restrict__ pos, int M, int N,
    int K) {
  __shared__ __align__(16) u16 Ak[2][128 * 64];
  __shared__ __align__(16) u16 Bk[2][128 * 64];
  const int tid = threadIdx.x;
  const int lane = tid & 63, wid = tid >> 6;
  const int wm = wid >> 2, wn = wid & 3;
  const int lg = lane >> 4, lr = lane & 15;
  const int nwg = gridDim.x * gridDim.y;
  const int wg = xcd_swz(blockIdx.y * gridDim.x + blockIdx.x, nwg);
  const int tn = wg % gridDim.x, tm = wg / gridDim.x;

  const int r8 = lane >> 3, c8 = lane & 7;
  const int swc = (c8 ^ r8) << 3;  // source chunk pre-swizzled (rule #21)
  const u16* aS = A + (size_t)(tm * 128 + wid * 16 + r8) * lda + swc;
  const u16* bS = Bt + (size_t)(tn * 128 + wid * 16 + r8) * ldb + swc;

  auto stage = [&](int buf, int kt) {  // 4 glds16/wave
    const u16* ak = aS + kt * 64;
    const u16* bk = bS + kt * 64;
    u16* ad = &Ak[buf][wid * 1024];
    u16* bd = &Bk[buf][wid * 1024];
    glds16(ak, ad);
    glds16(ak + (size_t)8 * lda, ad + 512);
    glds16(bk, bd);
    glds16(bk + (size_t)8 * ldb, bd + 512);
  };

  f32x4 acc[4][2] = {};
  auto compute = [&](int buf) {
#pragma unroll
    for (int ks = 0; ks < 2; ++ks) {
      const int pc = (ks << 2) | lg;
      const int po = ((pc ^ (lr & 7)) << 3);  // read-side un-swizzle
      short8 af[4], bf2[2];
#pragma unroll
      for (int i = 0; i < 4; ++i)
        af[i] = *(const short8*)(&Ak[buf][(wm * 64 + i * 16 + lr) * 64 + po]);
#pragma unroll
      for (int i = 0; i < 2; ++i)
        bf2[i] = *(const short8*)(&Bk[buf][(wn * 32 + i * 16 + lr) * 64 + po]);
#pragma unroll
      for (int mi = 0; mi < 4; ++mi)
#pragma unroll
        for (int ni = 0; ni < 2; ++ni)
          acc[mi][ni] = __builtin_amdgcn_mfma_f32_16x16x32_bf16(
              af[mi], bf2[ni], acc[mi][ni], 0, 0, 0);
    }
  };

  const int nk = K >> 6;
  int cur = 0;
  stage(0, 0);
  __syncthreads();
  for (int kt = 0; kt < nk - 1; ++kt) {
    stage(cur ^ 1, kt + 1);  // next K-tile in flight under compute
    compute(cur);
    __syncthreads();
    cur ^= 1;
  }
  compute(cur);

#pragma unroll
  for (int mi = 0; mi < 4; ++mi)
#pragma unroll
    for (int ni = 0; ni < 2; ++ni)
#pragma unroll
      for (int r = 0; r < 4; ++r) {
        int grow = tm * 128 + wm * 64 + mi * 16 + lg * 4 + r;
        int gcol = tn * 128 + wn * 32 + ni * 16 + lr;
        if (grow < M)
          epi_store<EPI>(acc[mi][ni][r] + bias[gcol], grow, gcol, outb, ldo,
                         outf, pos);
      }
}

// -------- gemmW2: C[M,N] = A[M,K] @ Bt[N,K], 128(M) x 256(N), BK=32 -------
// 8 waves (2m x 4n, wave tile 64x64), 2-phase double-buffer, 48KB LDS ->
// 3 blocks/CU. (qkv direct; mlp2 split-K via EPI 4: bf16 partial planes.)
template <int EPI>
__global__ __launch_bounds__(512) void gemmW2(
    const u16* __restrict__ A, int lda, const u16* __restrict__ Bt, int ldb,
    const float* __restrict__ bias, u16* __restrict__ outb, int ldo,
    float* __restrict__ outf, int M, int K) {
  __shared__ __align__(16) u16 Ak[2][128 * 32];  // 16 KB
  __shared__ __align__(16) u16 Bk[2][256 * 32];  // 32 KB
  const int tid = threadIdx.x;
  const int lane = tid & 63, wid = tid >> 6;
  const int wm = wid >> 2, wn = wid & 3;
  const int lg = lane >> 4, lr = lane & 15;
  const int nwg = gridDim.x * gridDim.y;
  const int wg = xcd_swz(blockIdx.y * gridDim.x + blockIdx.x, nwg);
  const int tn = wg % gridDim.x, tm = wg / gridDim.x;
  const size_t koff = (EPI == 4) ? (size_t)blockIdx.z * K : 0;

  const int sr = lane >> 2;
  const int sc4 = (((lane & 3) ^ ((lane >> 3) & 3)) << 3);
  const u16* aSrc = A + (size_t)(tm * 128 + wid * 16 + sr) * lda + koff + sc4;
  const u16* bSrc = Bt + (size_t)(tn * 256 + wid * 32 + sr) * ldb + koff + sc4;
  const size_t bRow16 = (size_t)16 * ldb;

  auto stage = [&](int buf, int kt) {  // 3 glds16/wave
    const u16* ak = aSrc + kt * 32;
    const u16* bk = bSrc + kt * 32;
    glds16(ak, &Ak[buf][wid * 16 * 32]);
    u16* bd = &Bk[buf][wid * 32 * 32];
    glds16(bk, bd);
    glds16(bk + bRow16, bd + 512);
  };

  const int rp = (lg ^ ((lr >> 1) & 3)) << 3;  // read-side un-swizzle
  f32x4 acc[4][4] = {};
  auto compute = [&](int buf) {
    short8 af[4], bf[4];
#pragma unroll
    for (int i = 0; i < 4; ++i)
      af[i] = *(const short8*)(&Ak[buf][(wm * 64 + i * 16 + lr) * 32 + rp]);
#pragma unroll
    for (int i = 0; i < 4; ++i)
      bf[i] = *(const short8*)(&Bk[buf][(wn * 64 + i * 16 + lr) * 32 + rp]);
#pragma unroll
    for (int mi = 0; mi < 4; ++mi)
#pragma unroll
      for (int ni = 0; ni < 4; ++ni)
        acc[mi][ni] = __builtin_amdgcn_mfma_f32_16x16x32_bf16(
            af[mi], bf[ni], acc[mi][ni], 0, 0, 0);
  };

  const int nk = K >> 5;
  int cur = 0;
  stage(0, 0);
  __syncthreads();
  for (int kt = 0; kt < nk - 1; ++kt) {
    stage(cur ^ 1, kt + 1);  // next K-tile in flight under compute
    compute(cur);
    __syncthreads();
    cur ^= 1;
  }
  compute(cur);

#pragma unroll
  for (int mi = 0; mi < 4; ++mi)
#pragma unroll
    for (int ni = 0; ni < 4; ++ni)
#pragma unroll
      for (int r = 0; r < 4; ++r) {
        int grow = tm * 128 + wm * 64 + mi * 16 + lg * 4 + r;
        int gcol = tn * 256 + wn * 64 + ni * 16 + lr;
        if (grow < M) {
          if constexpr (EPI == 4) {
            // bf16 split-K partial plane (RNE)
            outb[(size_t)blockIdx.z * M * ldo + (size_t)grow * ldo + gcol] =
                f2bf(acc[mi][ni][r]);
          } else {
            epi_store<EPI>(acc[mi][ni][r] + bias[gcol], grow, gcol, outb, ldo,
                           outf, nullptr);
          }
        }
      }
}

// redK: h += bias + Cp[0..2]  (bf16 planes; last-layer reduce)
__global__ __launch_bounds__(256) void redK(const u16* __restrict__ Cp,
                                            const float* __restrict__ bias,
                                            float* __restrict__ h) {
  size_t i = ((size_t)blockIdx.x * 256 + threadIdx.x) * 4;  // < 6304*768
  ushort4 q0 = *(const ushort4*)(Cp + i);
  ushort4 q1 = *(const ushort4*)(Cp + 6304ull * 768 + i);
  ushort4 q2 = *(const ushort4*)(Cp + 2ull * 6304 * 768 + i);
  float4 hv = *(const float4*)(h + i);
  float4 bv = *(const float4*)(bias + (int)(i % 768));
  hv.x += bf2f(q0.x) + bf2f(q1.x) + bf2f(q2.x) + bv.x;
  hv.y += bf2f(q0.y) + bf2f(q1.y) + bf2f(q2.y) + bv.y;
  hv.z += bf2f(q0.z) + bf2f(q1.z) + bf2f(q2.z) + bv.z;
  hv.w += bf2f(q0.w) + bf2f(q1.w) + bf2f(q2.w) + bv.w;
  *(float4*)(h + i) = hv;
}

// redln: h' = h + bias + Cp[0..2] (bf16 planes); h = h'; y = ln(h') bf16.
__global__ __launch_bounds__(256) void redln_k(
    const u16* __restrict__ Cp, const float* __restrict__ bias,
    float* __restrict__ h, const float* __restrict__ lnw,
    const float* __restrict__ lnb, u16* __restrict__ y) {
  const int lane = threadIdx.x & 63, wv = threadIdx.x >> 6;
  const int r = blockIdx.x * 4 + wv;
  const size_t base = (size_t)r * 768;
  float4 a[3];
  float s = 0.f, q = 0.f;
#pragma unroll
  for (int i = 0; i < 3; ++i) {
    const int off = i * 256 + lane * 4;
    float4 hv = *(const float4*)(h + base + off);
    ushort4 q0 = *(const ushort4*)(Cp + base + off);
    ushort4 q1 = *(const ushort4*)(Cp + 6304ull * 768 + base + off);
    ushort4 q2 = *(const ushort4*)(Cp + 2ull * 6304 * 768 + base + off);
    float4 bv = *(const float4*)(bias + off);
    a[i].x = hv.x + bf2f(q0.x) + bf2f(q1.x) + bf2f(q2.x) + bv.x;
    a[i].y = hv.y + bf2f(q0.y) + bf2f(q1.y) + bf2f(q2.y) + bv.y;
    a[i].z = hv.z + bf2f(q0.z) + bf2f(q1.z) + bf2f(q2.z) + bv.z;
    a[i].w = hv.w + bf2f(q0.w) + bf2f(q1.w) + bf2f(q2.w) + bv.w;
    s += a[i].x + a[i].y + a[i].z + a[i].w;
    q += a[i].x * a[i].x + a[i].y * a[i].y + a[i].z * a[i].z +
         a[i].w * a[i].w;
  }
  s = wred_sum(s);
  q = wred_sum(q);
  float mu = s * (1.f / 768.f);
  float var = q * (1.f / 768.f) - mu * mu;
  float rs = rsqrtf(var + 1e-5f);
#pragma unroll
  for (int i = 0; i < 3; ++i) {
    const int off = i * 256 + lane * 4;
    *(float4*)(h + base + off) = a[i];
    float4 wv4 = *(const float4*)(lnw + off);
    float4 bv4 = *(const float4*)(lnb + off);
    ushort4 o;
    o.x = f2bf((a[i].x - mu) * rs * wv4.x + bv4.x);
    o.y = f2bf((a[i].y - mu) * rs * wv4.y + bv4.y);
    o.z = f2bf((a[i].z - mu) * rs * wv4.z + bv4.z);
    o.w = f2bf((a[i].w - mu) * rs * wv4.w + bv4.w);
    *(ushort4*)(y + base + off) = o;
  }
}

// -------- gemmP: BMx128 tile, BK=32, 4 waves, 2-phase (patch + proj) ------
template <int EPI, int BM>
__global__ __launch_bounds__(256) void gemmP(
    const u16* __restrict__ A, int lda, const u16* __restrict__ Bt, int ldb,
    const float* __restrict__ bias, u16* __restrict__ outb, int ldo,
    float* __restrict__ outf, const float* __restrict__ pos, int M, int N,
    int K) {
  constexpr int MI = BM / 32;  // acc rows per wave (2 or 4)
  __shared__ __align__(16) u16 Ak[2][BM * 32];
  __shared__ __align__(16) u16 Bk[2][128 * 32];
  const int tid = threadIdx.x;
  const int lane = tid & 63, wid = tid >> 6;
  const int wm = wid >> 1, wn = wid & 1;
  const int lg = lane >> 4, lr = lane & 15;
  const int nwg = gridDim.x * gridDim.y;
  const int wg = xcd_swz(blockIdx.y * gridDim.x + blockIdx.x, nwg);
  const int tn = wg % gridDim.x, tm = wg / gridDim.x;

  const int sr = lane >> 2;
  const int sc4 = (((lane & 3) ^ ((lane >> 3) & 3)) << 3);
  const u16* aSrc = A + (size_t)(tm * BM + wid * (BM / 4) + sr) * lda + sc4;
  const u16* bSrc = Bt + (size_t)(tn * 128 + wid * 32 + sr) * ldb + sc4;
  const size_t aRow16 = (size_t)16 * lda, bRow16 = (size_t)16 * ldb;

  auto stage = [&](int buf, int kt) {
    const u16* ak = aSrc + kt * 32;
    const u16* bk = bSrc + kt * 32;
    u16* ad = &Ak[buf][wid * (BM / 4) * 32];
    u16* bd = &Bk[buf][wid * 1024];
    glds16(ak, ad);
    if constexpr (BM == 128) glds16(ak + aRow16, ad + 512);
    glds16(bk, bd);
    glds16(bk + bRow16, bd + 512);
  };

  const int rp = (lg ^ ((lr >> 1) & 3)) << 3;
  f32x4 acc[MI][4] = {};
  auto compute = [&](int buf) {
    short8 af[MI], bfr[4];
#pragma unroll
    for (int i = 0; i < MI; ++i)
      af[i] =
          *(const short8*)(&Ak[buf][(wm * (BM / 2) + i * 16 + lr) * 32 + rp]);
#pragma unroll
    for (int i = 0; i < 4; ++i)
      bfr[i] = *(const short8*)(&Bk[buf][(wn * 64 + i * 16 + lr) * 32 + rp]);
#pragma unroll
    for (int mi = 0; mi < MI; ++mi)
#pragma unroll
      for (int ni = 0; ni < 4; ++ni)
        acc[mi][ni] = __builtin_amdgcn_mfma_f32_16x16x32_bf16(
            af[mi], bfr[ni], acc[mi][ni], 0, 0, 0);
  };

  const int nk = K >> 5;
  int cur = 0;
  stage(0, 0);
  __syncthreads();
  for (int kt = 0; kt < nk - 1; ++kt) {
    stage(cur ^ 1, kt + 1);
    compute(cur);
    __syncthreads();
    cur ^= 1;
  }
  compute(cur);

#pragma unroll
  for (int mi = 0; mi < MI; ++mi)
#pragma unroll
    for (int ni = 0; ni < 4; ++ni)
#pragma unroll
      for (int r = 0; r < 4; ++r) {
        int grow = tm * BM + wm * (BM / 2) + mi * 16 + lg * 4 + r;
        int gcol = tn * 128 + wn * 64 + ni * 16 + lr;
        if (grow < M)
          epi_store<EPI>(acc[mi][ni][r] + bias[gcol], grow, gcol, outb, ldo,
                         outf, pos);
      }
}

// ---------------- fused attention: QK^T + softmax + PV ----------------
// One block per (b,h), 4 waves. K rows 0..207 staged swizzled (26KB);
// V rows 0..223 staged linear (28KB); P lives in wave-private LDS scratch
// (16x208 bf16 per wave, 26KB). Total LDS 80KB -> 2 blocks/CU. Wave w
// handles q-tiles w, w+4, w+8, w+12; no inter-wave sync after stage.
__global__ __launch_bounds__(256) void attn_k(const u16* __restrict__ qkv,
                                              u16* __restrict__ o) {
  __shared__ __align__(16) u16 Ks[208 * 64];      // 26 KB
  __shared__ __align__(16) u16 Vs[224 * 64];      // 28 KB
  __shared__ __align__(16) u16 Ps[4][16 * 208];   // 26 KB (wave-private)
  const int bh = blockIdx.x;
  const int tid = threadIdx.x;
  const int lane = tid & 63, w = tid >> 6;
  const int lg = lane >> 4, lr = lane & 15;
  const int b = bh / 12, hh = bh - b * 12;
  const u16* kbase = qkv + (size_t)b * 197 * 2304 + 768 + hh * 64;
  const u16* vbase = kbase + 768;
  // stage K rows 0..207 (1664 chunks), source chunk pre-swizzled (rule #21)
#pragma unroll
  for (int it = 0; it < 7; ++it) {
    const int c0 = it * 256 + w * 64;  // wave-uniform
    if (c0 < 1664) {
      const int c = c0 + lane;
      const int rd = c >> 3, c8 = c & 7;
      const int rc = rd > 196 ? 196 : rd;
      glds16(kbase + (size_t)rc * 2304 + ((c8 ^ (rd & 7)) << 3), &Ks[c0 * 8]);
    }
  }
  // stage V rows 0..223 (1792 chunks), linear
#pragma unroll
  for (int it = 0; it < 7; ++it) {
    const int c0 = it * 256 + w * 64;
    const int c = c0 + lane;
    int row = c >> 3;
    if (row > 196) row = 196;
    glds16(vbase + (size_t)row * 2304 + (c & 7) * 8, &Vs[c0 * 8]);
  }
  __syncthreads();

  // prebuild V fragments for all 4 HD col-tiles (reused across q-tiles)
  short8 vf[7][4];
#pragma unroll
  for (int ks = 0; ks < 7; ++ks)
#pragma unroll
    for (int ct = 0; ct < 4; ++ct) {
      ushort8 t;
#pragma unroll
      for (int j = 0; j < 8; ++j)
        t[j] = Vs[(ks * 32 + lg * 8 + j) * 64 + ct * 16 + lr];
      vf[ks][ct] = __builtin_bit_cast(short8, t);
    }

  const u16* qb = qkv + (size_t)b * 197 * 2304 + hh * 64;
  u16* ob = o + (size_t)b * 197 * 768 + hh * 64;
  u16* Pw = &Ps[w][0];
  const bool kval12 = (192 + lr) <= 196;
  const short8 zf = {};
  for (int qt = w; qt < 13; qt += 4) {
    int qrow = qt * 16 + lr;
    if (qrow > 196) qrow = 196;
    const u16* qp = qb + (size_t)qrow * 2304 + lg * 8;
    short8 a0 = *(const short8*)(qp);
    short8 a1 = *(const short8*)(qp + 32);
    f32x4 c[13];
#pragma unroll
    for (int kt = 0; kt < 13; ++kt) {
      const int krow = kt * 16 + lr;  // <= 207
      short8 b0 = *(const short8*)(&Ks[krow * 64 + ((lg ^ (krow & 7)) << 3)]);
      short8 b1 =
          *(const short8*)(&Ks[krow * 64 + (((4 + lg) ^ (krow & 7)) << 3)]);
      f32x4 t = {0.f, 0.f, 0.f, 0.f};
      t = __builtin_amdgcn_mfma_f32_16x16x32_bf16(a0, b0, t, 0, 0, 0);
      c[kt] = __builtin_amdgcn_mfma_f32_16x16x32_bf16(a1, b1, t, 0, 0, 0);
    }
    float mr[4], sr_[4];
#pragma unroll
    for (int r = 0; r < 4; ++r) {
      float mm = -3.4e38f;
#pragma unroll
      for (int kt = 0; kt < 13; ++kt)
        if (kt < 12 || kval12) mm = fmaxf(mm, c[kt][r] * 0.125f);
#pragma unroll
      for (int oo = 1; oo < 16; oo <<= 1)
        mm = fmaxf(mm, __shfl_xor(mm, oo, 64));
      mr[r] = mm;
    }
#pragma unroll
    for (int r = 0; r < 4; ++r) {
      float s = 0.f;
#pragma unroll
      for (int kt = 0; kt < 13; ++kt) {
        float e =
            (kt < 12 || kval12) ? __expf(c[kt][r] * 0.125f - mr[r]) : 0.f;
        c[kt][r] = e;
        s += e;
      }
#pragma unroll
      for (int oo = 1; oo < 16; oo <<= 1) s += __shfl_xor(s, oo, 64);
      sr_[r] = 1.0f / s;
    }
    // write P tile to wave-private scratch: row q-local, col k
#pragma unroll
    for (int r = 0; r < 4; ++r)
#pragma unroll
      for (int kt = 0; kt < 13; ++kt)
        Pw[(lg * 4 + r) * 208 + kt * 16 + lr] = f2bf(c[kt][r] * sr_[r]);
    asm volatile("s_waitcnt lgkmcnt(0)" ::: "memory");
    __builtin_amdgcn_sched_barrier(0);
    // PV: af from scratch (rows lr), vf prebuilt; k>=208 -> P==0, skip
    f32x4 acc[4] = {};
#pragma unroll
    for (int ks = 0; ks < 7; ++ks) {
      short8 af;
      if (ks == 6 && lg >= 2) {
        af = zf;
      } else {
        af = *(const short8*)(Pw + lr * 208 + ks * 32 + lg * 8);
      }
#pragma unroll
      for (int ct = 0; ct < 4; ++ct)
        acc[ct] =
            __builtin_amdgcn_mfma_f32_16x16x32_bf16(af, vf[ks][ct], acc[ct],
                                                    0, 0, 0);
    }
#pragma unroll
    for (int ct = 0; ct < 4; ++ct)
#pragma unroll
      for (int r = 0; r < 4; ++r) {
        int qq = qt * 16 + lg * 4 + r;
        if (qq < 197) ob[(size_t)qq * 768 + ct * 16 + lr] = f2bf(acc[ct][r]);
      }
  }
}

// ---------------- layernorm: 4 rows/block, 64 lanes/row, float4 ----------
__global__ __launch_bounds__(256) void ln_k(const float* __restrict__ x,
                                            const float* __restrict__ w,
                                            const float* __restrict__ bb,
                                            u16* __restrict__ y) {
  const int lane = threadIdx.x & 63, wv = threadIdx.x >> 6;
  const int r = blockIdx.x * 4 + wv;
  const float* xr = x + (size_t)r * 768;
  float4 v[3];
  float s = 0.f, q = 0.f;
#pragma unroll
  for (int i = 0; i < 3; ++i) {
    v[i] = *(const float4*)(xr + i * 256 + lane * 4);
    s += v[i].x + v[i].y + v[i].z + v[i].w;
    q += v[i].x * v[i].x + v[i].y * v[i].y + v[i].z * v[i].z +
         v[i].w * v[i].w;
  }
  s = wred_sum(s);
  q = wred_sum(q);
  float mu = s * (1.f / 768.f);
  float var = q * (1.f / 768.f) - mu * mu;
  float rs = rsqrtf(var + 1e-5f);
  u16* yr = y + (size_t)r * 768;
#pragma unroll
  for (int i = 0; i < 3; ++i) {
    float4 wv4 = *(const float4*)(w + i * 256 + lane * 4);
    float4 bv4 = *(const float4*)(bb + i * 256 + lane * 4);
    ushort4 o;
    o.x = f2bf((v[i].x - mu) * rs * wv4.x + bv4.x);
    o.y = f2bf((v[i].y - mu) * rs * wv4.y + bv4.y);
    o.z = f2bf((v[i].z - mu) * rs * wv4.z + bv4.z);
    o.w = f2bf((v[i].w - mu) * rs * wv4.w + bv4.w);
    *(ushort4*)(yr + i * 256 + lane * 4) = o;
  }
}

// ---------------- final LN(cls row) + head ----------------
__global__ __launch_bounds__(256) void head_k(
    const float* __restrict__ h, const float* __restrict__ lnw,
    const float* __restrict__ lnb, const float* __restrict__ hw,
    const float* __restrict__ hb, float* __restrict__ out) {
  const int b = blockIdx.x, tid = threadIdx.x;
  const float* xr = h + (size_t)b * 197 * 768;
  float v0 = xr[tid], v1 = xr[tid + 256], v2 = xr[tid + 512];
  float s = v0 + v1 + v2;
  float q = v0 * v0 + v1 * v1 + v2 * v2;
  s = wred_sum(s);
  q = wred_sum(q);
  __shared__ float ss[4], qs[4];
  int lane = tid & 63, wid = tid >> 6;
  if (lane == 0) { ss[wid] = s; qs[wid] = q; }
  __syncthreads();
  float S = ss[0] + ss[1] + ss[2] + ss[3];
  float Q = qs[0] + qs[1] + qs[2] + qs[3];
  float mu = S * (1.f / 768.f);
  float var = Q * (1.f / 768.f) - mu * mu;
  float rs = rsqrtf(var + 1e-5f);
  __shared__ float yb[768];
  yb[tid] = (v0 - mu) * rs * lnw[tid] + lnb[tid];
  yb[tid + 256] = (v1 - mu) * rs * lnw[tid + 256] + lnb[tid + 256];
  yb[tid + 512] = (v2 - mu) * rs * lnw[tid + 512] + lnb[tid + 512];
  __syncthreads();
  float p[10] = {};
  for (int e = tid; e < 768; e += 256) {
    float yv = yb[e];
#pragma unroll
    for (int n = 0; n < 10; ++n) p[n] += yv * hw[(size_t)e * 10 + n];
  }
#pragma unroll
  for (int n = 0; n < 10; ++n) p[n] = wred_sum(p[n]);
  __shared__ float red[4][10];
  if (lane == 0)
#pragma unroll
    for (int n = 0; n < 10; ++n) red[wid][n] = p[n];
  __syncthreads();
  if (tid < 10)
    out[b * 10 + tid] =
        red[0][tid] + red[1][tid] + red[2][tid] + red[3][tid] + hb[tid];
}

// ---------------- host orchestration ----------------
extern "C" void kernel_launch(void* const* d_in, const int* in_sizes, int n_in,
                              void* d_out, int out_size, void* d_ws,
                              size_t ws_size, hipStream_t stream) {
  const float* x = (const float*)d_in[0];
  const float* conv_w = (const float*)d_in[1];
  const float* conv_b = (const float*)d_in[2];
  const float* cls = (const float*)d_in[3];
  const float* pos = (const float*)d_in[4];
  const float* ln1w = (const float*)d_in[5];
  const float* ln1b = (const float*)d_in[6];
  const float* qkvw = (const float*)d_in[7];
  const float* qkvbias = (const float*)d_in[8];
  const float* projw = (const float*)d_in[9];
  const float* projb = (const float*)d_in[10];
  const float* ln2w = (const float*)d_in[11];
  const float* ln2b = (const float*)d_in[12];
  const float* w1f = (const float*)d_in[13];
  const float* b1 = (const float*)d_in[14];
  const float* w2f = (const float*)d_in[15];
  const float* b2 = (const float*)d_in[16];
  const float* lnfw = (const float*)d_in[17];
  const float* lnfb = (const float*)d_in[18];
  const float* headw = (const float*)d_in[19];
  const float* headb = (const float*)d_in[20];
  float* out = (float*)d_out;

  // workspace layout; A-side buffers padded to 6400 rows (tiles read past
  // M=6304; garbage rows are finite, never reach guarded outputs)
  char* p = (char*)d_ws;
  auto take = [&](size_t bytes) {
    char* q = p;
    p += (bytes + 255) & ~(size_t)255;
    return q;
  };
  u16* wq = (u16*)take(12ull * 768 * 2304 * 2);   // [N=2304][K=768] per layer
  u16* wpj = (u16*)take(12ull * 768 * 768 * 2);   // [768][768]
  u16* w1 = (u16*)take(12ull * 768 * 3072 * 2);   // [3072][768]
  u16* w2 = (u16*)take(12ull * 3072 * 768 * 2);   // [768][3072]
  u16* wc = (u16*)take(768ull * 768 * 2);         // conv_w already [N][K]
  float* h = (float*)take(6304ull * 768 * 4);
  u16* y = (u16*)take(6400ull * 768 * 2);
  u16* qkv = (u16*)take(6400ull * 2304 * 2);
  u16* ob = (u16*)take(6400ull * 768 * 2);
  u16* mlpb = (u16*)take(6400ull * 3072 * 2);  // also holds patches at start
  u16* skPb = (u16*)take(3ull * 6304 * 768 * 2);  // 3 bf16 split-K planes
  (void)ws_size; (void)in_sizes; (void)n_in; (void)out_size;

  // weight conversion fp32 -> bf16, transposed to [N][K]
  tpose_k<<<dim3(72, 24, 12), 256, 0, stream>>>(qkvw, wq, 768, 2304);
  tpose_k<<<dim3(24, 24, 12), 256, 0, stream>>>(projw, wpj, 768, 768);
  tpose_k<<<dim3(96, 24, 12), 256, 0, stream>>>(w1f, w1, 768, 3072);
  tpose_k<<<dim3(24, 96, 12), 256, 0, stream>>>(w2f, w2, 3072, 768);
  cvt4_k<<<576, 256, 0, stream>>>(conv_w, wc, 768 * 768 / 4);

  // patch embed
  patch_k<<<6272 * 768 / 256, 256, 0, stream>>>(x, mlpb);
  gemmP<3, 64><<<dim3(6, 98), 256, 0, stream>>>(mlpb, 768, wc, 768, conv_b,
                                                nullptr, 0, h, pos, 6272, 768,
                                                768);
  clspos_k<<<32 * 768 / 256, 256, 0, stream>>>(cls, pos, h);

  // layer 0's ln1 standalone; thereafter fused into redln
  ln_k<<<1576, 256, 0, stream>>>(h, ln1w, ln1b, y);
  for (int i = 0; i < 12; ++i) {
    gemmW2<0><<<dim3(9, 50), 512, 0, stream>>>(
        y, 768, wq + (size_t)i * 768 * 2304, 768, qkvbias + i * 2304, qkv,
        2304, nullptr, 6304, 768);
    attn_k<<<384, 256, 0, stream>>>(qkv, ob);
    gemmP<2, 64><<<dim3(6, 99), 256, 0, stream>>>(
        ob, 768, wpj + (size_t)i * 768 * 768, 768, projb + i * 768, nullptr,
        768, h, nullptr, 6304, 768, 768);
    ln_k<<<1576, 256, 0, stream>>>(h, ln2w + i * 768, ln2b + i * 768, y);
    gemmK64<1><<<dim3(24, 50), 512, 0, stream>>>(
        y, 768, w1 + (size_t)i * 768 * 3072, 768, b1 + i * 3072, mlpb, 3072,
        nullptr, nullptr, 6304, 3072, 768);
    // mlp2: split-K x3 (KC=1024) on 128x256 tile -> 450 blocks, bf16 planes
    gemmW2<4><<<dim3(3, 50, 3), 512, 0, stream>>>(
        mlpb, 3072, w2 + (size_t)i * 3072 * 768, 3072, nullptr, skPb, 768,
        nullptr, 6304, 1024);
    if (i < 11) {
      redln_k<<<1576, 256, 0, stream>>>(skPb, b2 + i * 768, h,
                                        ln1w + (i + 1) * 768,
                                        ln1b + (i + 1) * 768, y);
    } else {
      redK<<<4728, 256, 0, stream>>>(skPb, b2 + i * 768, h);
    }
  }

  head_k<<<32, 256, 0, stream>>>(h, lnfw, lnfb, headw, headb, out);
}

// Round 18
// 2751.762 us; speedup vs baseline: 1.2924x; 1.0132x over previous
//
#include <hip/hip_runtime.h>

// ViT-B/16 forward, B=32, S=197, E=768, H=12, HD=64, MLP=3072, DEPTH=12.
// Round 18: R17 (best, 2788us) + proj via split-K x3 (gemmW2<4>, KC=256 ->
// 8 steps/chunk, 450 blocks) + redln_k reused for {proj-reduce + ln2}:
// h' = h + projb + sum(planes); y = ln2(h'). Standalone ln2 kernel gone.
// All other kernels frozen from R17.

typedef __attribute__((ext_vector_type(8))) short short8;
typedef __attribute__((ext_vector_type(8))) unsigned short ushort8;
typedef __attribute__((ext_vector_type(4))) float f32x4;
typedef unsigned short u16;

#define DEV __device__ __forceinline__

DEV u16 f2bf(float f) {
  unsigned int u = __builtin_bit_cast(unsigned int, f);
  u += 0x7fffu + ((u >> 16) & 1u);
  return (u16)(u >> 16);
}
DEV float bf2f(u16 v) {
  return __builtin_bit_cast(float, (unsigned int)v << 16);
}
DEV float wred_sum(float v) {
  for (int o = 32; o; o >>= 1) v += __shfl_xor(v, o, 64);
  return v;
}
DEV void glds16(const void* gp, void* lp) {
  __builtin_amdgcn_global_load_lds(
      (const __attribute__((address_space(1))) void*)gp,
      (__attribute__((address_space(3))) void*)lp, 16, 0, 0);
}
// m204 bijective XCD swizzle: contiguous wg chunk per XCD
DEV int xcd_swz(int flat, int nwg) {
  int q = nwg >> 3, r = nwg & 7;
  int x = flat & 7, o = flat >> 3;
  return (x < r ? x * (q + 1) : r * (q + 1) + (x - r) * q) + o;
}

// ---------------- weight conversion ----------------
__global__ __launch_bounds__(256) void cvt4_k(const float* __restrict__ s,
                                              u16* __restrict__ d, long n4) {
  long i = (long)blockIdx.x * 256 + threadIdx.x;
  if (i >= n4) return;
  float4 v = ((const float4*)s)[i];
  ushort4 o;
  o.x = f2bf(v.x); o.y = f2bf(v.y); o.z = f2bf(v.z); o.w = f2bf(v.w);
  ((ushort4*)d)[i] = o;
}

// fp32 [K][N] (blockIdx.z selects layer) -> bf16 [N][K], tiled 32x32
__global__ __launch_bounds__(256) void tpose_k(const float* __restrict__ s,
                                               u16* __restrict__ d, int K,
                                               int N) {
  __shared__ float t[32][33];
  const int bx = blockIdx.x;  // n tile
  const int by = blockIdx.y;  // k tile
  const size_t base = (size_t)blockIdx.z * K * N;
  const int c = threadIdx.x & 31, r0 = threadIdx.x >> 5;
#pragma unroll
  for (int i = 0; i < 4; ++i) {
    int r = r0 + i * 8;
    t[r][c] = s[base + (size_t)(by * 32 + r) * N + bx * 32 + c];
  }
  __syncthreads();
#pragma unroll
  for (int i = 0; i < 4; ++i) {
    int r = r0 + i * 8;
    d[base + (size_t)(bx * 32 + r) * K + by * 32 + c] = f2bf(t[c][r]);
  }
}

// patches[b][p][d] <- x[b][c][gy*16+py][gx*16+px], bf16
__global__ __launch_bounds__(256) void patch_k(const float* __restrict__ x,
                                               u16* __restrict__ pt) {
  int i = blockIdx.x * 256 + threadIdx.x;  // 6272*768 exactly
  int d = i % 768;
  int bp = i / 768;
  int p = bp % 196, b = bp / 196;
  int c = d >> 8, pd = d & 255;
  int py = pd >> 4, px = pd & 15;
  int gy = p / 14, gx = p - gy * 14;
  size_t src = ((size_t)(b * 3 + c) * 224 + gy * 16 + py) * 224 + gx * 16 + px;
  pt[i] = f2bf(x[src]);
}

// h[b][0][:] = cls + pos[0]
__global__ __launch_bounds__(256) void clspos_k(const float* __restrict__ cls,
                                                const float* __restrict__ pos,
                                                float* __restrict__ h) {
  int i = blockIdx.x * 256 + threadIdx.x;  // 32*768
  int b = i / 768, e = i - b * 768;
  h[(size_t)b * 197 * 768 + e] = cls[e] + pos[e];
}

// ---------------- epilogue helper ----------------
template <int EPI>
DEV void epi_store(float v, int grow, int gcol, u16* outb, int ldo,
                   float* outf, const float* pos) {
  if constexpr (EPI == 0) {
    outb[(size_t)grow * ldo + gcol] = f2bf(v);
  } else if constexpr (EPI == 1) {
    // gelu(x) ~= x * sigmoid(1.5957691(x + 0.044715 x^3))
    float u = __expf(-1.5957691216f * (v + 0.044715f * v * v * v));
    outb[(size_t)grow * ldo + gcol] = f2bf(v / (1.f + u));
  } else if constexpr (EPI == 2) {
    outf[(size_t)grow * ldo + gcol] += v;
  } else {
    int b = grow / 196, p = grow - b * 196;
    outf[(size_t)(grow + b + 1) * 768 + gcol] =
        v + pos[(size_t)(p + 1) * 768 + gcol];
  }
}

// -------- gemmK64: C[M,N] = A[M,K] @ Bt[N,K], 128x128 tile, BK=64 ---------
// 8 waves (2m x 4n), 2-phase double-buffer, global_load_lds(16B), both-sides
// chunk-XOR swizzle, tm-major flat + XCD block swizzle. (mlp1)
template <int EPI>
__global__ __launch_bounds__(512) void gemmK64(
    const u16* __restrict__ A, int lda, const u16* __restrict__ Bt, int ldb,
    const float* __restrict__ bias, u16* __restrict__ outb, int ldo,
    float* __restrict__ outf, const float* __restrict__ pos, int M, int N,
    int K) {
  __shared__ __align__(16) u16 Ak[2][128 * 64];
  __shared__ __align__(16) u16 Bk[2][128 * 64];
  const int tid = threadIdx.x;
  const int lane = tid & 63, wid = tid >> 6;
  const int wm = wid >> 2, wn = wid & 3;
  const int lg = lane >> 4, lr = lane & 15;
  const int nwg = gridDim.x * gridDim.y;
  const int wg = xcd_swz(blockIdx.y * gridDim.x + blockIdx.x, nwg);
  const int tn = wg % gridDim.x, tm = wg / gridDim.x;

  const int r8 = lane >> 3, c8 = lane & 7;
  const int swc = (c8 ^ r8) << 3;  // source chunk pre-swizzled (rule #21)
  const u16* aS = A + (size_t)(tm * 128 + wid * 16 + r8) * lda + swc;
  const u16* bS = Bt + (size_t)(tn * 128 + wid * 16 + r8) * ldb + swc;

  auto stage = [&](int buf, int kt) {  // 4 glds16/wave
    const u16* ak = aS + kt * 64;
    const u16* bk = bS + kt * 64;
    u16* ad = &Ak[buf][wid * 1024];
    u16* bd = &Bk[buf][wid * 1024];
    glds16(ak, ad);
    glds16(ak + (size_t)8 * lda, ad + 512);
    glds16(bk, bd);
    glds16(bk + (size_t)8 * ldb, bd + 512);
  };

  f32x4 acc[4][2] = {};
  auto compute = [&](int buf) {
#pragma unroll
    for (int ks = 0; ks < 2; ++ks) {
      const int pc = (ks << 2) | lg;
      const int po = ((pc ^ (lr & 7)) << 3);  // read-side un-swizzle
      short8 af[4], bf2[2];
#pragma unroll
      for (int i = 0; i < 4; ++i)
        af[i] = *(const short8*)(&Ak[buf][(wm * 64 + i * 16 + lr) * 64 + po]);
#pragma unroll
      for (int i = 0; i < 2; ++i)
        bf2[i] = *(const short8*)(&Bk[buf][(wn * 32 + i * 16 + lr) * 64 + po]);
#pragma unroll
      for (int mi = 0; mi < 4; ++mi)
#pragma unroll
        for (int ni = 0; ni < 2; ++ni)
          acc[mi][ni] = __builtin_amdgcn_mfma_f32_16x16x32_bf16(
              af[mi], bf2[ni], acc[mi][ni], 0, 0, 0);
    }
  };

  const int nk = K >> 6;
  int cur = 0;
  stage(0, 0);
  __syncthreads();
  for (int kt = 0; kt < nk - 1; ++kt) {
    stage(cur ^ 1, kt + 1);  // next K-tile in flight under compute
    compute(cur);
    __syncthreads();
    cur ^= 1;
  }
  compute(cur);

#pragma unroll
  for (int mi = 0; mi < 4; ++mi)
#pragma unroll
    for (int ni = 0; ni < 2; ++ni)
#pragma unroll
      for (int r = 0; r < 4; ++r) {
        int grow = tm * 128 + wm * 64 + mi * 16 + lg * 4 + r;
        int gcol = tn * 128 + wn * 32 + ni * 16 + lr;
        if (grow < M)
          epi_store<EPI>(acc[mi][ni][r] + bias[gcol], grow, gcol, outb, ldo,
                         outf, pos);
      }
}

// -------- gemmW2: C[M,N] = A[M,K] @ Bt[N,K], 128(M) x 256(N), BK=32 -------
// 8 waves (2m x 4n, wave tile 64x64), 2-phase double-buffer, 48KB LDS ->
// 3 blocks/CU. (qkv direct; proj/mlp2 split-K via EPI 4: bf16 planes.)
template <int EPI>
__global__ __launch_bounds__(512) void gemmW2(
    const u16* __restrict__ A, int lda, const u16* __restrict__ Bt, int ldb,
    const float* __restrict__ bias, u16* __restrict__ outb, int ldo,
    float* __restrict__ outf, int M, int K) {
  __shared__ __align__(16) u16 Ak[2][128 * 32];  // 16 KB
  __shared__ __align__(16) u16 Bk[2][256 * 32];  // 32 KB
  const int tid = threadIdx.x;
  const int lane = tid & 63, wid = tid >> 6;
  const int wm = wid >> 2, wn = wid & 3;
  const int lg = lane >> 4, lr = lane & 15;
  const int nwg = gridDim.x * gridDim.y;
  const int wg = xcd_swz(blockIdx.y * gridDim.x + blockIdx.x, nwg);
  const int tn = wg % gridDim.x, tm = wg / gridDim.x;
  const size_t koff = (EPI == 4) ? (size_t)blockIdx.z * K : 0;

  const int sr = lane >> 2;
  const int sc4 = (((lane & 3) ^ ((lane >> 3) & 3)) << 3);
  const u16* aSrc = A + (size_t)(tm * 128 + wid * 16 + sr) * lda + koff + sc4;
  const u16* bSrc = Bt + (size_t)(tn * 256 + wid * 32 + sr) * ldb + koff + sc4;
  const size_t bRow16 = (size_t)16 * ldb;

  auto stage = [&](int buf, int kt) {  // 3 glds16/wave
    const u16* ak = aSrc + kt * 32;
    const u16* bk = bSrc + kt * 32;
    glds16(ak, &Ak[buf][wid * 16 * 32]);
    u16* bd = &Bk[buf][wid * 32 * 32];
    glds16(bk, bd);
    glds16(bk + bRow16, bd + 512);
  };

  const int rp = (lg ^ ((lr >> 1) & 3)) << 3;  // read-side un-swizzle
  f32x4 acc[4][4] = {};
  auto compute = [&](int buf) {
    short8 af[4], bf[4];
#pragma unroll
    for (int i = 0; i < 4; ++i)
      af[i] = *(const short8*)(&Ak[buf][(wm * 64 + i * 16 + lr) * 32 + rp]);
#pragma unroll
    for (int i = 0; i < 4; ++i)
      bf[i] = *(const short8*)(&Bk[buf][(wn * 64 + i * 16 + lr) * 32 + rp]);
#pragma unroll
    for (int mi = 0; mi < 4; ++mi)
#pragma unroll
      for (int ni = 0; ni < 4; ++ni)
        acc[mi][ni] = __builtin_amdgcn_mfma_f32_16x16x32_bf16(
            af[mi], bf[ni], acc[mi][ni], 0, 0, 0);
  };

  const int nk = K >> 5;
  int cur = 0;
  stage(0, 0);
  __syncthreads();
  for (int kt = 0; kt < nk - 1; ++kt) {
    stage(cur ^ 1, kt + 1);  // next K-tile in flight under compute
    compute(cur);
    __syncthreads();
    cur ^= 1;
  }
  compute(cur);

#pragma unroll
  for (int mi = 0; mi < 4; ++mi)
#pragma unroll
    for (int ni = 0; ni < 4; ++ni)
#pragma unroll
      for (int r = 0; r < 4; ++r) {
        int grow = tm * 128 + wm * 64 + mi * 16 + lg * 4 + r;
        int gcol = tn * 256 + wn * 64 + ni * 16 + lr;
        if (grow < M) {
          if constexpr (EPI == 4) {
            // bf16 split-K partial plane (RNE)
            outb[(size_t)blockIdx.z * M * ldo + (size_t)grow * ldo + gcol] =
                f2bf(acc[mi][ni][r]);
          } else {
            epi_store<EPI>(acc[mi][ni][r] + bias[gcol], grow, gcol, outb, ldo,
                           outf, nullptr);
          }
        }
      }
}

// redK: h += bias + Cp[0..2]  (bf16 planes; last-layer reduce)
__global__ __launch_bounds__(256) void redK(const u16* __restrict__ Cp,
                                            const float* __restrict__ bias,
                                            float* __restrict__ h) {
  size_t i = ((size_t)blockIdx.x * 256 + threadIdx.x) * 4;  // < 6304*768
  ushort4 q0 = *(const ushort4*)(Cp + i);
  ushort4 q1 = *(const ushort4*)(Cp + 6304ull * 768 + i);
  ushort4 q2 = *(const ushort4*)(Cp + 2ull * 6304 * 768 + i);
  float4 hv = *(const float4*)(h + i);
  float4 bv = *(const float4*)(bias + (int)(i % 768));
  hv.x += bf2f(q0.x) + bf2f(q1.x) + bf2f(q2.x) + bv.x;
  hv.y += bf2f(q0.y) + bf2f(q1.y) + bf2f(q2.y) + bv.y;
  hv.z += bf2f(q0.z) + bf2f(q1.z) + bf2f(q2.z) + bv.z;
  hv.w += bf2f(q0.w) + bf2f(q1.w) + bf2f(q2.w) + bv.w;
  *(float4*)(h + i) = hv;
}

// redln: h' = h + bias + Cp[0..2] (bf16 planes); h = h'; y = ln(h') bf16.
// Used for BOTH {proj-reduce + ln2} and {mlp2-reduce + next ln1}.
__global__ __launch_bounds__(256) void redln_k(
    const u16* __restrict__ Cp, const float* __restrict__ bias,
    float* __restrict__ h, const float* __restrict__ lnw,
    const float* __restrict__ lnb, u16* __restrict__ y) {
  const int lane = threadIdx.x & 63, wv = threadIdx.x >> 6;
  const int r = blockIdx.x * 4 + wv;
  const size_t base = (size_t)r * 768;
  float4 a[3];
  float s = 0.f, q = 0.f;
#pragma unroll
  for (int i = 0; i < 3; ++i) {
    const int off = i * 256 + lane * 4;
    float4 hv = *(const float4*)(h + base + off);
    ushort4 q0 = *(const ushort4*)(Cp + base + off);
    ushort4 q1 = *(const ushort4*)(Cp + 6304ull * 768 + base + off);
    ushort4 q2 = *(const ushort4*)(Cp + 2ull * 6304 * 768 + base + off);
    float4 bv = *(const float4*)(bias + off);
    a[i].x = hv.x + bf2f(q0.x) + bf2f(q1.x) + bf2f(q2.x) + bv.x;
    a[i].y = hv.y + bf2f(q0.y) + bf2f(q1.y) + bf2f(q2.y) + bv.y;
    a[i].z = hv.z + bf2f(q0.z) + bf2f(q1.z) + bf2f(q2.z) + bv.z;
    a[i].w = hv.w + bf2f(q0.w) + bf2f(q1.w) + bf2f(q2.w) + bv.w;
    s += a[i].x + a[i].y + a[i].z + a[i].w;
    q += a[i].x * a[i].x + a[i].y * a[i].y + a[i].z * a[i].z +
         a[i].w * a[i].w;
  }
  s = wred_sum(s);
  q = wred_sum(q);
  float mu = s * (1.f / 768.f);
  float var = q * (1.f / 768.f) - mu * mu;
  float rs = rsqrtf(var + 1e-5f);
#pragma unroll
  for (int i = 0; i < 3; ++i) {
    const int off = i * 256 + lane * 4;
    *(float4*)(h + base + off) = a[i];
    float4 wv4 = *(const float4*)(lnw + off);
    float4 bv4 = *(const float4*)(lnb + off);
    ushort4 o;
    o.x = f2bf((a[i].x - mu) * rs * wv4.x + bv4.x);
    o.y = f2bf((a[i].y - mu) * rs * wv4.y + bv4.y);
    o.z = f2bf((a[i].z - mu) * rs * wv4.z + bv4.z);
    o.w = f2bf((a[i].w - mu) * rs * wv4.w + bv4.w);
    *(ushort4*)(y + base + off) = o;
  }
}

// -------- gemmP: BMx128 tile, BK=32, 4 waves, 2-phase (patch embed) -------
template <int EPI, int BM>
__global__ __launch_bounds__(256) void gemmP(
    const u16* __restrict__ A, int lda, const u16* __restrict__ Bt, int ldb,
    const float* __restrict__ bias, u16* __restrict__ outb, int ldo,
    float* __restrict__ outf, const float* __restrict__ pos, int M, int N,
    int K) {
  constexpr int MI = BM / 32;  // acc rows per wave (2 or 4)
  __shared__ __align__(16) u16 Ak[2][BM * 32];
  __shared__ __align__(16) u16 Bk[2][128 * 32];
  const int tid = threadIdx.x;
  const int lane = tid & 63, wid = tid >> 6;
  const int wm = wid >> 1, wn = wid & 1;
  const int lg = lane >> 4, lr = lane & 15;
  const int nwg = gridDim.x * gridDim.y;
  const int wg = xcd_swz(blockIdx.y * gridDim.x + blockIdx.x, nwg);
  const int tn = wg % gridDim.x, tm = wg / gridDim.x;

  const int sr = lane >> 2;
  const int sc4 = (((lane & 3) ^ ((lane >> 3) & 3)) << 3);
  const u16* aSrc = A + (size_t)(tm * BM + wid * (BM / 4) + sr) * lda + sc4;
  const u16* bSrc = Bt + (size_t)(tn * 128 + wid * 32 + sr) * ldb + sc4;
  const size_t aRow16 = (size_t)16 * lda, bRow16 = (size_t)16 * ldb;

  auto stage = [&](int buf, int kt) {
    const u16* ak = aSrc + kt * 32;
    const u16* bk = bSrc + kt * 32;
    u16* ad = &Ak[buf][wid * (BM / 4) * 32];
    u16* bd = &Bk[buf][wid * 1024];
    glds16(ak, ad);
    if constexpr (BM == 128) glds16(ak + aRow16, ad + 512);
    glds16(bk, bd);
    glds16(bk + bRow16, bd + 512);
  };

  const int rp = (lg ^ ((lr >> 1) & 3)) << 3;
  f32x4 acc[MI][4] = {};
  auto compute = [&](int buf) {
    short8 af[MI], bfr[4];
#pragma unroll
    for (int i = 0; i < MI; ++i)
      af[i] =
          *(const short8*)(&Ak[buf][(wm * (BM / 2) + i * 16 + lr) * 32 + rp]);
#pragma unroll
    for (int i = 0; i < 4; ++i)
      bfr[i] = *(const short8*)(&Bk[buf][(wn * 64 + i * 16 + lr) * 32 + rp]);
#pragma unroll
    for (int mi = 0; mi < MI; ++mi)
#pragma unroll
      for (int ni = 0; ni < 4; ++ni)
        acc[mi][ni] = __builtin_amdgcn_mfma_f32_16x16x32_bf16(
            af[mi], bfr[ni], acc[mi][ni], 0, 0, 0);
  };

  const int nk = K >> 5;
  int cur = 0;
  stage(0, 0);
  __syncthreads();
  for (int kt = 0; kt < nk - 1; ++kt) {
    stage(cur ^ 1, kt + 1);
    compute(cur);
    __syncthreads();
    cur ^= 1;
  }
  compute(cur);

#pragma unroll
  for (int mi = 0; mi < MI; ++mi)
#pragma unroll
    for (int ni = 0; ni < 4; ++ni)
#pragma unroll
      for (int r = 0; r < 4; ++r) {
        int grow = tm * BM + wm * (BM / 2) + mi * 16 + lg * 4 + r;
        int gcol = tn * 128 + wn * 64 + ni * 16 + lr;
        if (grow < M)
          epi_store<EPI>(acc[mi][ni][r] + bias[gcol], grow, gcol, outb, ldo,
                         outf, pos);
      }
}

// ---------------- fused attention: QK^T + softmax + PV ----------------
// One block per (b,h), 4 waves. K rows 0..207 staged swizzled (26KB);
// V rows 0..223 staged linear (28KB); P in wave-private LDS scratch.
__global__ __launch_bounds__(256) void attn_k(const u16* __restrict__ qkv,
                                              u16* __restrict__ o) {
  __shared__ __align__(16) u16 Ks[208 * 64];      // 26 KB
  __shared__ __align__(16) u16 Vs[224 * 64];      // 28 KB
  __shared__ __align__(16) u16 Ps[4][16 * 208];   // 26 KB (wave-private)
  const int bh = blockIdx.x;
  const int tid = threadIdx.x;
  const int lane = tid & 63, w = tid >> 6;
  const int lg = lane >> 4, lr = lane & 15;
  const int b = bh / 12, hh = bh - b * 12;
  const u16* kbase = qkv + (size_t)b * 197 * 2304 + 768 + hh * 64;
  const u16* vbase = kbase + 768;
#pragma unroll
  for (int it = 0; it < 7; ++it) {
    const int c0 = it * 256 + w * 64;  // wave-uniform
    if (c0 < 1664) {
      const int c = c0 + lane;
      const int rd = c >> 3, c8 = c & 7;
      const int rc = rd > 196 ? 196 : rd;
      glds16(kbase + (size_t)rc * 2304 + ((c8 ^ (rd & 7)) << 3), &Ks[c0 * 8]);
    }
  }
#pragma unroll
  for (int it = 0; it < 7; ++it) {
    const int c0 = it * 256 + w * 64;
    const int c = c0 + lane;
    int row = c >> 3;
    if (row > 196) row = 196;
    glds16(vbase + (size_t)row * 2304 + (c & 7) * 8, &Vs[c0 * 8]);
  }
  __syncthreads();

  short8 vf[7][4];
#pragma unroll
  for (int ks = 0; ks < 7; ++ks)
#pragma unroll
    for (int ct = 0; ct < 4; ++ct) {
      ushort8 t;
#pragma unroll
      for (int j = 0; j < 8; ++j)
        t[j] = Vs[(ks * 32 + lg * 8 + j) * 64 + ct * 16 + lr];
      vf[ks][ct] = __builtin_bit_cast(short8, t);
    }

  const u16* qb = qkv + (size_t)b * 197 * 2304 + hh * 64;
  u16* ob = o + (size_t)b * 197 * 768 + hh * 64;
  u16* Pw = &Ps[w][0];
  const bool kval12 = (192 + lr) <= 196;
  const short8 zf = {};
  for (int qt = w; qt < 13; qt += 4) {
    int qrow = qt * 16 + lr;
    if (qrow > 196) qrow = 196;
    const u16* qp = qb + (size_t)qrow * 2304 + lg * 8;
    short8 a0 = *(const short8*)(qp);
    short8 a1 = *(const short8*)(qp + 32);
    f32x4 c[13];
#pragma unroll
    for (int kt = 0; kt < 13; ++kt) {
      const int krow = kt * 16 + lr;  // <= 207
      short8 b0 = *(const short8*)(&Ks[krow * 64 + ((lg ^ (krow & 7)) << 3)]);
      short8 b1 =
          *(const short8*)(&Ks[krow * 64 + (((4 + lg) ^ (krow & 7)) << 3)]);
      f32x4 t = {0.f, 0.f, 0.f, 0.f};
      t = __builtin_amdgcn_mfma_f32_16x16x32_bf16(a0, b0, t, 0, 0, 0);
      c[kt] = __builtin_amdgcn_mfma_f32_16x16x32_bf16(a1, b1, t, 0, 0, 0);
    }
    float mr[4], sr_[4];
#pragma unroll
    for (int r = 0; r < 4; ++r) {
      float mm = -3.4e38f;
#pragma unroll
      for (int kt = 0; kt < 13; ++kt)
        if (kt < 12 || kval12) mm = fmaxf(mm, c[kt][r] * 0.125f);
#pragma unroll
      for (int oo = 1; oo < 16; oo <<= 1)
        mm = fmaxf(mm, __shfl_xor(mm, oo, 64));
      mr[r] = mm;
    }
#pragma unroll
    for (int r = 0; r < 4; ++r) {
      float s = 0.f;
#pragma unroll
      for (int kt = 0; kt < 13; ++kt) {
        float e =
            (kt < 12 || kval12) ? __expf(c[kt][r] * 0.125f - mr[r]) : 0.f;
        c[kt][r] = e;
        s += e;
      }
#pragma unroll
      for (int oo = 1; oo < 16; oo <<= 1) s += __shfl_xor(s, oo, 64);
      sr_[r] = 1.0f / s;
    }
#pragma unroll
    for (int r = 0; r < 4; ++r)
#pragma unroll
      for (int kt = 0; kt < 13; ++kt)
        Pw[(lg * 4 + r) * 208 + kt * 16 + lr] = f2bf(c[kt][r] * sr_[r]);
    asm volatile("s_waitcnt lgkmcnt(0)" ::: "memory");
    __builtin_amdgcn_sched_barrier(0);
    f32x4 acc[4] = {};
#pragma unroll
    for (int ks = 0; ks < 7; ++ks) {
      short8 af;
      if (ks == 6 && lg >= 2) {
        af = zf;
      } else {
        af = *(const short8*)(Pw + lr * 208 + ks * 32 + lg * 8);
      }
#pragma unroll
      for (int ct = 0; ct < 4; ++ct)
        acc[ct] =
            __builtin_amdgcn_mfma_f32_16x16x32_bf16(af, vf[ks][ct], acc[ct],
                                                    0, 0, 0);
    }
#pragma unroll
    for (int ct = 0; ct < 4; ++ct)
#pragma unroll
      for (int r = 0; r < 4; ++r) {
        int qq = qt * 16 + lg * 4 + r;
        if (qq < 197) ob[(size_t)qq * 768 + ct * 16 + lr] = f2bf(acc[ct][r]);
      }
  }
}

// ---------------- layernorm: 4 rows/block, 64 lanes/row, float4 ----------
__global__ __launch_bounds__(256) void ln_k(const float* __restrict__ x,
                                            const float* __restrict__ w,
                                            const float* __restrict__ bb,
                                            u16* __restrict__ y) {
  const int lane = threadIdx.x & 63, wv = threadIdx.x >> 6;
  const int r = blockIdx.x * 4 + wv;
  const float* xr = x + (size_t)r * 768;
  float4 v[3];
  float s = 0.f, q = 0.f;
#pragma unroll
  for (int i = 0; i < 3; ++i) {
    v[i] = *(const float4*)(xr + i * 256 + lane * 4);
    s += v[i].x + v[i].y + v[i].z + v[i].w;
    q += v[i].x * v[i].x + v[i].y * v[i].y + v[i].z * v[i].z +
         v[i].w * v[i].w;
  }
  s = wred_sum(s);
  q = wred_sum(q);
  float mu = s * (1.f / 768.f);
  float var = q * (1.f / 768.f) - mu * mu;
  float rs = rsqrtf(var + 1e-5f);
  u16* yr = y + (size_t)r * 768;
#pragma unroll
  for (int i = 0; i < 3; ++i) {
    float4 wv4 = *(const float4*)(w + i * 256 + lane * 4);
    float4 bv4 = *(const float4*)(bb + i * 256 + lane * 4);
    ushort4 o;
    o.x = f2bf((v[i].x - mu) * rs * wv4.x + bv4.x);
    o.y = f2bf((v[i].y - mu) * rs * wv4.y + bv4.y);
    o.z = f2bf((v[i].z - mu) * rs * wv4.z + bv4.z);
    o.w = f2bf((v[i].w - mu) * rs * wv4.w + bv4.w);
    *(ushort4*)(yr + i * 256 + lane * 4) = o;
  }
}

// ---------------- final LN(cls row) + head ----------------
__global__ __launch_bounds__(256) void head_k(
    const float* __restrict__ h, const float* __restrict__ lnw,
    const float* __restrict__ lnb, const float* __restrict__ hw,
    const float* __restrict__ hb, float* __restrict__ out) {
  const int b = blockIdx.x, tid = threadIdx.x;
  const float* xr = h + (size_t)b * 197 * 768;
  float v0 = xr[tid], v1 = xr[tid + 256], v2 = xr[tid + 512];
  float s = v0 + v1 + v2;
  float q = v0 * v0 + v1 * v1 + v2 * v2;
  s = wred_sum(s);
  q = wred_sum(q);
  __shared__ float ss[4], qs[4];
  int lane = tid & 63, wid = tid >> 6;
  if (lane == 0) { ss[wid] = s; qs[wid] = q; }
  __syncthreads();
  float S = ss[0] + ss[1] + ss[2] + ss[3];
  float Q = qs[0] + qs[1] + qs[2] + qs[3];
  float mu = S * (1.f / 768.f);
  float var = Q * (1.f / 768.f) - mu * mu;
  float rs = rsqrtf(var + 1e-5f);
  __shared__ float yb[768];
  yb[tid] = (v0 - mu) * rs * lnw[tid] + lnb[tid];
  yb[tid + 256] = (v1 - mu) * rs * lnw[tid + 256] + lnb[tid + 256];
  yb[tid + 512] = (v2 - mu) * rs * lnw[tid + 512] + lnb[tid + 512];
  __syncthreads();
  float p[10] = {};
  for (int e = tid; e < 768; e += 256) {
    float yv = yb[e];
#pragma unroll
    for (int n = 0; n < 10; ++n) p[n] += yv * hw[(size_t)e * 10 + n];
  }
#pragma unroll
  for (int n = 0; n < 10; ++n) p[n] = wred_sum(p[n]);
  __shared__ float red[4][10];
  if (lane == 0)
#pragma unroll
    for (int n = 0; n < 10; ++n) red[wid][n] = p[n];
  __syncthreads();
  if (tid < 10)
    out[b * 10 + tid] =
        red[0][tid] + red[1][tid] + red[2][tid] + red[3][tid] + hb[tid];
}

// ---------------- host orchestration ----------------
extern "C" void kernel_launch(void* const* d_in, const int* in_sizes, int n_in,
                              void* d_out, int out_size, void* d_ws,
                              size_t ws_size, hipStream_t stream) {
  const float* x = (const float*)d_in[0];
  const float* conv_w = (const float*)d_in[1];
  const float* conv_b = (const float*)d_in[2];
  const float* cls = (const float*)d_in[3];
  const float* pos = (const float*)d_in[4];
  const float* ln1w = (const float*)d_in[5];
  const float* ln1b = (const float*)d_in[6];
  const float* qkvw = (const float*)d_in[7];
  const float* qkvbias = (const float*)d_in[8];
  const float* projw = (const float*)d_in[9];
  const float* projb = (const float*)d_in[10];
  const float* ln2w = (const float*)d_in[11];
  const float* ln2b = (const float*)d_in[12];
  const float* w1f = (const float*)d_in[13];
  const float* b1 = (const float*)d_in[14];
  const float* w2f = (const float*)d_in[15];
  const float* b2 = (const float*)d_in[16];
  const float* lnfw = (const float*)d_in[17];
  const float* lnfb = (const float*)d_in[18];
  const float* headw = (const float*)d_in[19];
  const float* headb = (const float*)d_in[20];
  float* out = (float*)d_out;

  // workspace layout; A-side buffers padded to 6400 rows (tiles read past
  // M=6304; garbage rows are finite, never reach guarded outputs)
  char* p = (char*)d_ws;
  auto take = [&](size_t bytes) {
    char* q = p;
    p += (bytes + 255) & ~(size_t)255;
    return q;
  };
  u16* wq = (u16*)take(12ull * 768 * 2304 * 2);   // [N=2304][K=768] per layer
  u16* wpj = (u16*)take(12ull * 768 * 768 * 2);   // [768][768]
  u16* w1 = (u16*)take(12ull * 768 * 3072 * 2);   // [3072][768]
  u16* w2 = (u16*)take(12ull * 3072 * 768 * 2);   // [768][3072]
  u16* wc = (u16*)take(768ull * 768 * 2);         // conv_w already [N][K]
  float* h = (float*)take(6304ull * 768 * 4);
  u16* y = (u16*)take(6400ull * 768 * 2);
  u16* qkv = (u16*)take(6400ull * 2304 * 2);
  u16* ob = (u16*)take(6400ull * 768 * 2);
  u16* mlpb = (u16*)take(6400ull * 3072 * 2);  // also holds patches at start
  u16* skPb = (u16*)take(3ull * 6304 * 768 * 2);  // 3 bf16 split-K planes
  (void)ws_size; (void)in_sizes; (void)n_in; (void)out_size;

  // weight conversion fp32 -> bf16, transposed to [N][K]
  tpose_k<<<dim3(72, 24, 12), 256, 0, stream>>>(qkvw, wq, 768, 2304);
  tpose_k<<<dim3(24, 24, 12), 256, 0, stream>>>(projw, wpj, 768, 768);
  tpose_k<<<dim3(96, 24, 12), 256, 0, stream>>>(w1f, w1, 768, 3072);
  tpose_k<<<dim3(24, 96, 12), 256, 0, stream>>>(w2f, w2, 3072, 768);
  cvt4_k<<<576, 256, 0, stream>>>(conv_w, wc, 768 * 768 / 4);

  // patch embed
  patch_k<<<6272 * 768 / 256, 256, 0, stream>>>(x, mlpb);
  gemmP<3, 64><<<dim3(6, 98), 256, 0, stream>>>(mlpb, 768, wc, 768, conv_b,
                                                nullptr, 0, h, pos, 6272, 768,
                                                768);
  clspos_k<<<32 * 768 / 256, 256, 0, stream>>>(cls, pos, h);

  // layer 0's ln1 standalone; thereafter fused into redln
  ln_k<<<1576, 256, 0, stream>>>(h, ln1w, ln1b, y);
  for (int i = 0; i < 12; ++i) {
    gemmW2<0><<<dim3(9, 50), 512, 0, stream>>>(
        y, 768, wq + (size_t)i * 768 * 2304, 768, qkvbias + i * 2304, qkv,
        2304, nullptr, 6304, 768);
    attn_k<<<384, 256, 0, stream>>>(qkv, ob);
    // proj: split-K x3 (KC=256, 8 steps/chunk) -> bf16 planes, then fused
    // {reduce + residual + ln2} via redln_k
    gemmW2<4><<<dim3(3, 50, 3), 512, 0, stream>>>(
        ob, 768, wpj + (size_t)i * 768 * 768, 768, nullptr, skPb, 768,
        nullptr, 6304, 256);
    redln_k<<<1576, 256, 0, stream>>>(skPb, projb + i * 768, h,
                                      ln2w + i * 768, ln2b + i * 768, y);
    gemmK64<1><<<dim3(24, 50), 512, 0, stream>>>(
        y, 768, w1 + (size_t)i * 768 * 3072, 768, b1 + i * 3072, mlpb, 3072,
        nullptr, nullptr, 6304, 3072, 768);
    // mlp2: split-K x3 (KC=1024) on 128x256 tile -> 450 blocks, bf16 planes
    gemmW2<4><<<dim3(3, 50, 3), 512, 0, stream>>>(
        mlpb, 3072, w2 + (size_t)i * 3072 * 768, 3072, nullptr, skPb, 768,
        nullptr, 6304, 1024);
    if (i < 11) {
      redln_k<<<1576, 256, 0, stream>>>(skPb, b2 + i * 768, h,
                                        ln1w + (i + 1) * 768,
                                        ln1b + (i + 1) * 768, y);
    } else {
      redK<<<4728, 256, 0, stream>>>(skPb, b2 + i * 768, h);
    }
  }

  head_k<<<32, 256, 0, stream>>>(h, lnfw, lnfb, headw, headb, out);
}